// Round 5
// baseline (851.532 us; speedup 1.0000x reference)
//
#include <hip/hip_runtime.h>
#include <cstddef>
#include <cstdint>

// Problem constants
#define Bb 4
#define Tt 4096
#define Dd 1024
#define Hh 16
#define HDd 64
#define NSs 64
#define SPHh 4
#define HMm 4096
#define MTOK (Bb*Tt)   // 16384

typedef _Float16 f16x8 __attribute__((ext_vector_type(8)));
typedef float f32x4 __attribute__((ext_vector_type(4)));

__device__ __forceinline__ float gelu_f(float x) {
    return 0.5f * x * (1.0f + erff(x * 0.70710678118654752440f));
}

// XCD-chunked bijective block swizzle (requires nwg % 8 == 0; all launches comply)
__device__ __forceinline__ int xcd_swz(int nwg) {
    int orig = blockIdx.y * gridDim.x + blockIdx.x;
    int cpx = nwg >> 3;
    return (orig & 7) * cpx + (orig >> 3);
}

// ---------------- K0: cb[j] = sum_k slot_mean_full[k] * rw1[1024+k, j] ----------------
__global__ __launch_bounds__(128) void cb_kernel(const float* __restrict__ slot_init,
                                                 const float* __restrict__ rw1,
                                                 float* __restrict__ cb) {
    __shared__ float sm[64];
    int tid = threadIdx.x;
    if (tid < 64) {
        float s = 0.f;
        for (int i = 0; i < 64; ++i) s += slot_init[i * 64 + tid];
        sm[tid] = s * (1.0f / 64.0f);
    }
    __syncthreads();
    int j = blockIdx.x * 128 + tid;
    float acc = 0.f;
    for (int k = 0; k < 1024; ++k)
        acc = fmaf(sm[k & 63], rw1[(size_t)(1024 + k) * 1024 + j], acc);
    cb[j] = acc;
}

// ---------------- K1: rw1[:1024] -> transposed split-f16 planes [N=1024][K=1024] ------
__global__ __launch_bounds__(256) void wsplitT_k(const float* __restrict__ rw1,
                                                 _Float16* __restrict__ whiT,
                                                 _Float16* __restrict__ wloT) {
    __shared__ float t[32][33];
    int n0 = blockIdx.x * 32, k0 = blockIdx.y * 32;
    int tx = threadIdx.x & 31, ty = threadIdx.x >> 5;   // 32 x 8
#pragma unroll
    for (int i = 0; i < 32; i += 8)
        t[ty + i][tx] = rw1[(size_t)(k0 + ty + i) * 1024 + n0 + tx];
    __syncthreads();
#pragma unroll
    for (int i = 0; i < 32; i += 8) {
        float v = t[tx][ty + i];
        _Float16 h = (_Float16)v;
        _Float16 l = (_Float16)(v - (float)h);
        whiT[(size_t)(n0 + ty + i) * 1024 + k0 + tx] = h;
        wloT[(size_t)(n0 + ty + i) * 1024 + k0 + tx] = l;
    }
}

// ---------------- K1a: x -> split f16 hi/lo planes (row-major, K-contig) --------------
__global__ __launch_bounds__(256) void xsplit_k(const float* __restrict__ x,
                                                _Float16* __restrict__ xhi,
                                                _Float16* __restrict__ xlo) {
    size_t i = ((size_t)blockIdx.x * 256 + threadIdx.x) * 8;
    float4 a = *(const float4*)(x + i);
    float4 b = *(const float4*)(x + i + 4);
    float v[8] = {a.x, a.y, a.z, a.w, b.x, b.y, b.z, b.w};
    f16x8 h, l;
#pragma unroll
    for (int j = 0; j < 8; ++j) {
        _Float16 hv = (_Float16)v[j];
        h[j] = hv;
        l[j] = (_Float16)(v[j] - (float)hv);
    }
    *(f16x8*)(xhi + i) = h;
    *(f16x8*)(xlo + i) = l;
}

// ---------------- K1b: split-fp16 MFMA routing GEMM (pre-split 4-plane) ---------------
// C[M,N] fp32 = gelu(A @ B^T + bias1 + bias2); A = Ah+Al [M,K] f16, B = Bh+Bl [N,K] f16.
// 3-term Markidis: al*bh + ah*bl + ah*bh with fp32 MFMA accumulation.
// 128x128 tile, BK=32, 4 waves, all planes via global_load_lds (linear LDS).
__global__ __launch_bounds__(256) void hgemm4_k(const _Float16* __restrict__ Ah,
                                                const _Float16* __restrict__ Al,
                                                const _Float16* __restrict__ Bh,
                                                const _Float16* __restrict__ Bl,
                                                const float* __restrict__ bias1,
                                                const float* __restrict__ bias2,
                                                float* __restrict__ C,
                                                int M, int N, int K) {
    __shared__ __align__(16) _Float16 Ahs[128][32];
    __shared__ __align__(16) _Float16 Als[128][32];
    __shared__ __align__(16) _Float16 Bhs[128][32];
    __shared__ __align__(16) _Float16 Bls[128][32];
    const int tid = threadIdx.x;
    const int wid = tid >> 6;
    const int lane = tid & 63;
    const int swz = xcd_swz(gridDim.x * gridDim.y);
    const int brow = (swz / gridDim.x) * 128;
    const int bcol = (swz % gridDim.x) * 128;
    const int wr = (wid >> 1) * 64;
    const int wc = (wid & 1) * 64;

    // staging lane image per issue: 16 rows x 32 f16 (64B rows), lane -> (rb, cbk)
    const int rb = lane >> 2;
    const int cbk = (lane & 3) * 8;
    const int fr = lane & 15;
    const int fk = (lane >> 4) * 8;

    f32x4 acc[4][4];
#pragma unroll
    for (int m = 0; m < 4; ++m)
#pragma unroll
        for (int n = 0; n < 4; ++n)
            acc[m][n] = f32x4{0.f, 0.f, 0.f, 0.f};

    for (int k0 = 0; k0 < K; k0 += 32) {
#pragma unroll
        for (int i = 0; i < 2; ++i) {
            int r0 = wid * 32 + i * 16;
            const _Float16* gah = Ah + (size_t)(brow + r0 + rb) * K + k0 + cbk;
            __builtin_amdgcn_global_load_lds(
                (const __attribute__((address_space(1))) void*)gah,
                (__attribute__((address_space(3))) void*)&Ahs[r0][0], 16, 0, 0);
            const _Float16* gal = Al + (size_t)(brow + r0 + rb) * K + k0 + cbk;
            __builtin_amdgcn_global_load_lds(
                (const __attribute__((address_space(1))) void*)gal,
                (__attribute__((address_space(3))) void*)&Als[r0][0], 16, 0, 0);
            const _Float16* gbh = Bh + (size_t)(bcol + r0 + rb) * K + k0 + cbk;
            __builtin_amdgcn_global_load_lds(
                (const __attribute__((address_space(1))) void*)gbh,
                (__attribute__((address_space(3))) void*)&Bhs[r0][0], 16, 0, 0);
            const _Float16* gbl = Bl + (size_t)(bcol + r0 + rb) * K + k0 + cbk;
            __builtin_amdgcn_global_load_lds(
                (const __attribute__((address_space(1))) void*)gbl,
                (__attribute__((address_space(3))) void*)&Bls[r0][0], 16, 0, 0);
        }
        __syncthreads();   // drains vmcnt (compiler emits waitcnt before barrier)

        f16x8 afh[4], afl[4], bfh[4], bfl[4];
#pragma unroll
        for (int m = 0; m < 4; ++m) {
            afh[m] = *(const f16x8*)&Ahs[wr + m * 16 + fr][fk];
            afl[m] = *(const f16x8*)&Als[wr + m * 16 + fr][fk];
        }
#pragma unroll
        for (int n = 0; n < 4; ++n) {
            bfh[n] = *(const f16x8*)&Bhs[wc + n * 16 + fr][fk];
            bfl[n] = *(const f16x8*)&Bls[wc + n * 16 + fr][fk];
        }
#pragma unroll
        for (int m = 0; m < 4; ++m)
#pragma unroll
            for (int n = 0; n < 4; ++n) {
                acc[m][n] = __builtin_amdgcn_mfma_f32_16x16x32_f16(afl[m], bfh[n], acc[m][n], 0, 0, 0);
                acc[m][n] = __builtin_amdgcn_mfma_f32_16x16x32_f16(afh[m], bfl[n], acc[m][n], 0, 0, 0);
                acc[m][n] = __builtin_amdgcn_mfma_f32_16x16x32_f16(afh[m], bfh[n], acc[m][n], 0, 0, 0);
            }
        __syncthreads();
    }

    // epilogue: C/D layout col=lane&15, row=(lane>>4)*4+reg
    const int crow = (lane >> 4) * 4;
#pragma unroll
    for (int m = 0; m < 4; ++m) {
        int row0 = brow + wr + m * 16 + crow;
#pragma unroll
        for (int n = 0; n < 4; ++n) {
            int col = bcol + wc + n * 16 + fr;
            float bv = bias1[col] + bias2[col];
#pragma unroll
            for (int r = 0; r < 4; ++r) {
                float v = acc[m][n][r] + bv;
                C[(size_t)(row0 + r) * N + col] = gelu_f(v);
            }
        }
    }
}

// ---------------- K2: route logits, N=64 ----------------
__global__ __launch_bounds__(256) void logits_k(const float* __restrict__ A,
                                                const float* __restrict__ Bw,
                                                const float* __restrict__ rb2,
                                                const float* __restrict__ taup,
                                                float* __restrict__ Cl,
                                                int M, int K) {
    __shared__ float As[16][64];
    __shared__ float Bs[16][64];
    const int tid = threadIdx.x;
    const int m0 = blockIdx.x * 64;
    const int tx = (tid & 15) * 4;
    const int ty = (tid >> 4) * 4;
    const int arow = tid >> 2;
    const int acol = (tid & 3) * 4;
    const int brl = tid >> 4;
    const int bcl = (tid & 15) * 4;

    float acc[4][4] = {};

    for (int k0 = 0; k0 < K; k0 += 16) {
        float4 av = *(const float4*)(A + (size_t)(m0 + arow) * K + k0 + acol);
        float4 bv = *(const float4*)(Bw + (size_t)(k0 + brl) * 64 + bcl);
        As[acol + 0][arow] = av.x;
        As[acol + 1][arow] = av.y;
        As[acol + 2][arow] = av.z;
        As[acol + 3][arow] = av.w;
        *(float4*)&Bs[brl][bcl] = bv;
        __syncthreads();
#pragma unroll
        for (int kk = 0; kk < 16; ++kk) {
            float a[4], b[4];
            *(float4*)&a[0] = *(const float4*)&As[kk][ty];
            *(float4*)&b[0] = *(const float4*)&Bs[kk][tx];
#pragma unroll
            for (int i = 0; i < 4; ++i)
#pragma unroll
                for (int j = 0; j < 4; ++j)
                    acc[i][j] = fmaf(a[i], b[j], acc[i][j]);
        }
        __syncthreads();
    }
    float inv = 1.0f / (fabsf(taup[0]) + 0.1f);
#pragma unroll
    for (int i = 0; i < 4; ++i)
#pragma unroll
        for (int j = 0; j < 4; ++j)
            Cl[(size_t)(m0 + ty + i) * 64 + tx + j] = (acc[i][j] + rb2[tx + j]) * inv;
}

// ---------------- K3: top-32-of-64 + softmax -> dense alpha (fp32 + f16 copy) --------
__global__ __launch_bounds__(256) void topk_k(const float* __restrict__ logits,
                                              float* __restrict__ alpha,
                                              _Float16* __restrict__ alpha16) {
    int wave = threadIdx.x >> 6;
    int lane = threadIdx.x & 63;
    int t = blockIdx.x * 4 + wave;
    float li = logits[(size_t)t * 64 + lane];
    float m = li;
#pragma unroll
    for (int off = 32; off; off >>= 1) m = fmaxf(m, __shfl_xor(m, off, 64));
    int cnt = 0;
    for (int off = 1; off < 64; ++off) {
        int j = (lane + off) & 63;
        float lj = __shfl(li, j, 64);
        cnt += (lj > li) || (lj == li && j < lane);
    }
    float e = (cnt < 32) ? expf(li - m) : 0.0f;
    float s = e;
#pragma unroll
    for (int off = 32; off; off >>= 1) s += __shfl_xor(s, off, 64);
    float a = e / s;
    alpha[(size_t)t * 64 + lane] = a;
    alpha16[(size_t)t * 64 + lane] = (_Float16)a;
}

// ---------------- K4: slot pooling (T-split partial sums) ----------------
__global__ __launch_bounds__(256) void pool_part_k(const float* __restrict__ x,
                                                   const float* __restrict__ alpha,
                                                   float* __restrict__ part,
                                                   float* __restrict__ partw) {
    int bh = blockIdx.x;
    int c = blockIdx.y;
    int b = bh >> 4, h = bh & 15;
    int tid = threadIdx.x;
    int s = tid >> 6, d = tid & 63;
    __shared__ float lx[16][64];
    __shared__ float la[16][4];
    float acc = 0.f, wacc = 0.f;
    const int tchunk = Tt / 8;
    const int t0base = c * tchunk;
    for (int t0 = 0; t0 < tchunk; t0 += 16) {
        int ttr = tid >> 4;
        int ddr = (tid & 15) * 4;
        size_t trow = (size_t)b * Tt + t0base + t0 + ttr;
        float4 xv = *(const float4*)(x + trow * Dd + h * 64 + ddr);
        *(float4*)&lx[ttr][ddr] = xv;
        if (tid < 64) {
            int tt2 = tid >> 2, ss = tid & 3;
            la[tt2][ss] = alpha[((size_t)b * Tt + t0base + t0 + tt2) * 64 + h * 4 + ss];
        }
        __syncthreads();
#pragma unroll
        for (int q = 0; q < 16; ++q) {
            float av = la[q][s];
            acc = fmaf(av, lx[q][d], acc);
            wacc += av;
        }
        __syncthreads();
    }
    part[(((size_t)c * 64 + bh) * 4 + s) * 64 + d] = acc;
    if (d == 0) partw[((size_t)c * 64 + bh) * 4 + s] = wacc;
}

__global__ __launch_bounds__(256) void pool_comb_k(const float* __restrict__ part,
                                                   const float* __restrict__ partw,
                                                   float* __restrict__ slot_in) {
    int bh = blockIdx.x;
    int tid = threadIdx.x;
    int s = tid >> 6, d = tid & 63;
    float acc = 0.f, w = 0.f;
    for (int c = 0; c < 8; ++c) {
        acc += part[(((size_t)c * 64 + bh) * 4 + s) * 64 + d];
        w   += partw[((size_t)c * 64 + bh) * 4 + s];
    }
    slot_in[((size_t)bh * 4 + s) * 64 + d] = acc / (w + 1e-8f);
}

// ---------------- K5: GRU + slot MLP, one wave per slot ----------------
__global__ __launch_bounds__(64) void gru_k(const float* __restrict__ slot_in,
                                            const float* __restrict__ slot_init,
                                            const float* __restrict__ gwi,
                                            const float* __restrict__ gwh,
                                            const float* __restrict__ gbi,
                                            const float* __restrict__ gbh,
                                            const float* __restrict__ hpw,
                                            const float* __restrict__ hpb,
                                            const float* __restrict__ ohw,
                                            const float* __restrict__ ohb,
                                            float* __restrict__ S_new) {
    int slot = blockIdx.x;
    int hs = slot & 63;
    int d = threadIdx.x;
    __shared__ float si[64], hp[64], hn[64], g[256];
    si[d] = slot_in[(size_t)slot * 64 + d];
    hp[d] = slot_init[(size_t)hs * 64 + d];
    __syncthreads();
    float gi_r = gbi[d], gi_z = gbi[64 + d], gi_n = gbi[128 + d];
    float gh_r = gbh[d], gh_z = gbh[64 + d], gh_n = gbh[128 + d];
    for (int k = 0; k < 64; ++k) {
        float sv = si[k], hv = hp[k];
        gi_r = fmaf(sv, gwi[(size_t)(d) * 64 + k], gi_r);
        gi_z = fmaf(sv, gwi[(size_t)(64 + d) * 64 + k], gi_z);
        gi_n = fmaf(sv, gwi[(size_t)(128 + d) * 64 + k], gi_n);
        gh_r = fmaf(hv, gwh[(size_t)(d) * 64 + k], gh_r);
        gh_z = fmaf(hv, gwh[(size_t)(64 + d) * 64 + k], gh_z);
        gh_n = fmaf(hv, gwh[(size_t)(128 + d) * 64 + k], gh_n);
    }
    float r = 1.0f / (1.0f + expf(-(gi_r + gh_r)));
    float z = 1.0f / (1.0f + expf(-(gi_z + gh_z)));
    float n = tanhf(gi_n + r * gh_n);
    float hnew = (1.0f - z) * n + z * hp[d];
    hn[d] = hnew;
    __syncthreads();
    float p0 = hpb[d], p1 = hpb[64 + d], p2 = hpb[128 + d], p3 = hpb[192 + d];
    for (int k = 0; k < 64; ++k) {
        float hv = hn[k];
        p0 = fmaf(hv, hpw[(size_t)k * 256 + d], p0);
        p1 = fmaf(hv, hpw[(size_t)k * 256 + 64 + d], p1);
        p2 = fmaf(hv, hpw[(size_t)k * 256 + 128 + d], p2);
        p3 = fmaf(hv, hpw[(size_t)k * 256 + 192 + d], p3);
    }
    g[d] = gelu_f(p0); g[64 + d] = gelu_f(p1); g[128 + d] = gelu_f(p2); g[192 + d] = gelu_f(p3);
    __syncthreads();
    float o = ohb[d];
    for (int j = 0; j < 256; ++j) o = fmaf(g[j], ohw[(size_t)j * 64 + d], o);
    S_new[(size_t)slot * 64 + d] = o;
}

// ---------------- K6: P^T[b][j][hs] = sum_d S_new[b,hs,d] * vpw[h*64+d, j]  (f16) ----
__global__ __launch_bounds__(256) void pmat_k(const float* __restrict__ Snew,
                                              const float* __restrict__ vpw,
                                              _Float16* __restrict__ PT) {
    int tid = threadIdx.x;
    int j = blockIdx.x * 64 + (tid & 63);
    int bq = tid >> 6;                       // batch 0..3 (one per wave)
    for (int hb = 0; hb < 8; ++hb) {
        float acc[8] = {};
        int h0 = hb * 2;
        for (int d = 0; d < 64; ++d) {
            float w0 = vpw[(size_t)(h0 * 64 + d) * HMm + j];
            float w1 = vpw[(size_t)((h0 + 1) * 64 + d) * HMm + j];
#pragma unroll
            for (int s = 0; s < 4; ++s) {
                acc[s]     = fmaf(Snew[((size_t)bq * 64 + h0 * 4 + s) * 64 + d], w0, acc[s]);
                acc[4 + s] = fmaf(Snew[((size_t)bq * 64 + (h0 + 1) * 4 + s) * 64 + d], w1, acc[4 + s]);
            }
        }
        f16x8 o;
#pragma unroll
        for (int i = 0; i < 8; ++i) o[i] = (_Float16)acc[i];
        *(f16x8*)&PT[((size_t)bq * 4096 + j) * 64 + hb * 8] = o;
    }
}

// ---------------- K7: transpose + fp32->fp16 convert: out[N,K] = (f16) in[K,N]^T -----
__global__ __launch_bounds__(256) void transp_f16_k(const float* __restrict__ in,
                                                    _Float16* __restrict__ out,
                                                    int K, int N) {
    __shared__ float t[32][33];
    int n0 = blockIdx.x * 32, k0 = blockIdx.y * 32;
    int tx = threadIdx.x & 31, ty = threadIdx.x >> 5;   // 32 x 8
#pragma unroll
    for (int i = 0; i < 32; i += 8)
        t[ty + i][tx] = in[(size_t)(k0 + ty + i) * N + n0 + tx];
    __syncthreads();
#pragma unroll
    for (int i = 0; i < 32; i += 8)
        out[(size_t)(n0 + ty + i) * K + k0 + tx] = (_Float16)t[tx][ty + i];
}

// ---------------- K8: fp16 MFMA GEMM: C = act(A[M,K] @ Bt[N,K]^T + bias) --------------
// 128x128 tile, BK=64, 4 waves, m97 structure + XCD swizzle.
template <int DO_GELU, int OUT_F16>
__global__ __launch_bounds__(256) void hgemm_k(const _Float16* __restrict__ A,
                                               const _Float16* __restrict__ Bt,
                                               const float* __restrict__ bias,
                                               void* __restrict__ Cv,
                                               int M, int N, int K) {
    __shared__ __align__(16) _Float16 As[128][64];
    __shared__ __align__(16) _Float16 Bs[128][64];
    const int tid = threadIdx.x;
    const int wid = tid >> 6;
    const int lane = tid & 63;
    const int swz = xcd_swz(gridDim.x * gridDim.y);
    const int brow = (swz / gridDim.x) * 128;
    const int bcol = (swz % gridDim.x) * 128;
    const int wr = (wid >> 1) * 64;
    const int wc = (wid & 1) * 64;

    f32x4 acc[4][4];
#pragma unroll
    for (int m = 0; m < 4; ++m)
#pragma unroll
        for (int n = 0; n < 4; ++n)
            acc[m][n] = f32x4{0.f, 0.f, 0.f, 0.f};

    const int lrow = lane >> 3;          // 0..7
    const int lcol = (lane & 7) * 8;     // f16 elements

    const int fr = lane & 15;
    const int fk = (lane >> 4) * 8;

    for (int k0 = 0; k0 < K; k0 += 64) {
#pragma unroll
        for (int i = 0; i < 4; ++i) {
            int seg = wid * 4 + i;
            const _Float16* g = A + (size_t)(brow + seg * 8 + lrow) * K + k0 + lcol;
            __builtin_amdgcn_global_load_lds(
                (const __attribute__((address_space(1))) void*)g,
                (__attribute__((address_space(3))) void*)&As[seg * 8][0], 16, 0, 0);
        }
#pragma unroll
        for (int i = 0; i < 4; ++i) {
            int seg = wid * 4 + i;
            const _Float16* g = Bt + (size_t)(bcol + seg * 8 + lrow) * K + k0 + lcol;
            __builtin_amdgcn_global_load_lds(
                (const __attribute__((address_space(1))) void*)g,
                (__attribute__((address_space(3))) void*)&Bs[seg * 8][0], 16, 0, 0);
        }
        __syncthreads();
#pragma unroll
        for (int kb = 0; kb < 2; ++kb) {
            f16x8 af[4], bf[4];
#pragma unroll
            for (int m = 0; m < 4; ++m)
                af[m] = *(const f16x8*)&As[wr + m * 16 + fr][kb * 32 + fk];
#pragma unroll
            for (int n = 0; n < 4; ++n)
                bf[n] = *(const f16x8*)&Bs[wc + n * 16 + fr][kb * 32 + fk];
#pragma unroll
            for (int m = 0; m < 4; ++m)
#pragma unroll
                for (int n = 0; n < 4; ++n)
                    acc[m][n] = __builtin_amdgcn_mfma_f32_16x16x32_f16(af[m], bf[n], acc[m][n], 0, 0, 0);
        }
        __syncthreads();
    }

    const int crow = (lane >> 4) * 4;
#pragma unroll
    for (int m = 0; m < 4; ++m) {
        int row0 = brow + wr + m * 16 + crow;
#pragma unroll
        for (int n = 0; n < 4; ++n) {
            int col = bcol + wc + n * 16 + fr;
            float bv = bias ? bias[col] : 0.f;
#pragma unroll
            for (int r = 0; r < 4; ++r) {
                float v = acc[m][n][r] + bv;
                if (DO_GELU) v = gelu_f(v);
                size_t idx = (size_t)(row0 + r) * N + col;
                if (OUT_F16) ((_Float16*)Cv)[idx] = (_Float16)v;
                else ((float*)Cv)[idx] = v;
            }
        }
    }
}

extern "C" void kernel_launch(void* const* d_in, const int* in_sizes, int n_in,
                              void* d_out, int out_size, void* d_ws, size_t ws_size,
                              hipStream_t stream) {
    const float* x         = (const float*)d_in[0];
    const float* slot_init = (const float*)d_in[1];
    const float* rw1       = (const float*)d_in[2];
    const float* rb1       = (const float*)d_in[3];
    const float* rw2       = (const float*)d_in[4];
    const float* rb2       = (const float*)d_in[5];
    const float* gwi       = (const float*)d_in[6];
    const float* gwh       = (const float*)d_in[7];
    const float* gbi       = (const float*)d_in[8];
    const float* gbh       = (const float*)d_in[9];
    const float* hpw       = (const float*)d_in[10];
    const float* hpb       = (const float*)d_in[11];
    const float* ohw       = (const float*)d_in[12];
    const float* ohb       = (const float*)d_in[13];
    const float* vpw       = (const float*)d_in[14];
    const float* vpb       = (const float*)d_in[15];
    const float* vow       = (const float*)d_in[16];
    const float* vob       = (const float*)d_in[17];
    const float* opw       = (const float*)d_in[18];
    const float* opb       = (const float*)d_in[19];
    const float* tau       = (const float*)d_in[20];
    float* out = (float*)d_out;

    float* ws = (float*)d_ws;
    size_t off = 0;
    auto alloc = [&](size_t nfloats) { float* p = ws + off; off += (nfloats + 63) & ~(size_t)63; return p; };

    float* cb     = alloc(1024);
    float* h1     = alloc((size_t)MTOK * 1024);            // fp32; dead after logits:
    _Float16* v1cc = (_Float16*)h1;                         //   reused as v1 row-chunk [8192,4096] f16
    float* logits = alloc((size_t)MTOK * 64);
    float* alpha  = alloc((size_t)MTOK * 64);
    _Float16* alpha16 = (_Float16*)alloc((size_t)MTOK * 64 / 2);
    float* slotin = alloc(256 * 64);
    float* part   = alloc((size_t)8 * 64 * 4 * 64);
    float* partw  = alloc(8 * 64 * 4);
    float* Snew   = alloc(256 * 64);
    _Float16* PT   = (_Float16*)alloc((size_t)Bb * HMm * 64 / 2);  // [4,4096,64] f16
    _Float16* vowT = (_Float16*)alloc((size_t)Dd * HMm / 2);       // [1024,4096] f16
    _Float16* opwT = (_Float16*)alloc((size_t)Dd * Dd / 2);        // [1024,1024] f16
    _Float16* v2f16 = (_Float16*)alloc((size_t)MTOK * Dd / 2);     // [16384,1024] f16
    _Float16* w1hiT = (_Float16*)alloc((size_t)Dd * Dd / 2);       // [1024,1024] f16
    _Float16* w1loT = (_Float16*)alloc((size_t)Dd * Dd / 2);       // [1024,1024] f16

    // x split planes live in d_out (dead until final GEMM overwrites it): 32MB + 32MB
    _Float16* xhi = (_Float16*)d_out;
    _Float16* xlo = xhi + (size_t)MTOK * Dd;

    // ---- routing: pre-split x + 4-plane split-fp16 MFMA GEMM + fp32 logits ----
    cb_kernel<<<8, 128, 0, stream>>>(slot_init, rw1, cb);
    wsplitT_k<<<dim3(Dd / 32, Dd / 32), 256, 0, stream>>>(rw1, w1hiT, w1loT);
    xsplit_k<<<(MTOK * Dd) / (256 * 8), 256, 0, stream>>>(x, xhi, xlo);
    hgemm4_k<<<dim3(Dd / 128, MTOK / 128), 256, 0, stream>>>(
        xhi, xlo, w1hiT, w1loT, rb1, cb, h1, MTOK, Dd, Dd);
    logits_k<<<MTOK / 64, 256, 0, stream>>>(h1, rw2, rb2, tau, logits, MTOK, 1024);
    topk_k<<<MTOK / 4, 256, 0, stream>>>(logits, alpha, alpha16);

    // ---- weight transposes (fp32 -> fp16 [N,K]) ----
    transp_f16_k<<<dim3(Dd / 32, HMm / 32), 256, 0, stream>>>(vow, vowT, HMm, Dd);
    transp_f16_k<<<dim3(Dd / 32, Dd / 32), 256, 0, stream>>>(opw, opwT, Dd, Dd);

    // ---- slot pooling + GRU + slot MLP ----
    pool_part_k<<<dim3(64, 8), 256, 0, stream>>>(x, alpha, part, partw);
    pool_comb_k<<<64, 256, 0, stream>>>(part, partw, slotin);
    gru_k<<<256, 64, 0, stream>>>(slotin, slot_init, gwi, gwh, gbi, gbh,
                                  hpw, hpb, ohw, ohb, Snew);

    // ---- P^T[b] = (S_emb[b] @ vpw)^T : rank-64 structure kills GEMM1 ----
    pmat_k<<<HMm / 64, 256, 0, stream>>>(Snew, vpw, PT);

    // ---- value MLP: v1 = gelu(alpha @ P[b] + vpb) via K=64 MFMA GEMM, then GEMM2 ----
    for (int c = 0; c < 2; ++c) {
        for (int q = 0; q < 2; ++q) {
            int b = c * 2 + q;
            hgemm_k<1, 1><<<dim3(HMm / 128, Tt / 128), 256, 0, stream>>>(
                alpha16 + (size_t)b * Tt * 64, PT + (size_t)b * HMm * 64, vpb,
                v1cc + (size_t)q * Tt * HMm, Tt, HMm, 64);
        }
        hgemm_k<0, 1><<<dim3(Dd / 128, 8192 / 128), 256, 0, stream>>>(
            v1cc, vowT, vob, v2f16 + (size_t)c * 8192 * Dd, 8192, Dd, HMm);
    }
    // ---- final projection (fp32 out; overwrites the xhi/xlo scratch) ----
    hgemm_k<0, 0><<<dim3(Dd / 128, MTOK / 128), 256, 0, stream>>>(
        v2f16, opwT, opb, out, MTOK, Dd, Dd);

    (void)in_sizes; (void)n_in; (void)out_size; (void)ws_size;
}

// Round 6
// 672.062 us; speedup vs baseline: 1.2670x; 1.2670x over previous
//
#include <hip/hip_runtime.h>
#include <cstddef>
#include <cstdint>

// Problem constants
#define Bb 4
#define Tt 4096
#define Dd 1024
#define Hh 16
#define HDd 64
#define NSs 64
#define SPHh 4
#define HMm 4096
#define MTOK (Bb*Tt)   // 16384

typedef _Float16 f16x8 __attribute__((ext_vector_type(8)));
typedef _Float16 f16x4 __attribute__((ext_vector_type(4)));
typedef float f32x4 __attribute__((ext_vector_type(4)));

__device__ __forceinline__ float gelu_f(float x) {
    return 0.5f * x * (1.0f + erff(x * 0.70710678118654752440f));
}

// XCD-chunked bijective block swizzle (requires nwg % 8 == 0; all launches comply)
__device__ __forceinline__ int xcd_swz(int nwg) {
    int orig = blockIdx.y * gridDim.x + blockIdx.x;
    int cpx = nwg >> 3;
    return (orig & 7) * cpx + (orig >> 3);
}

// ---------------- K0: cb partials: cbp[kc][j] = sum_{k in kc} sm[k&63]*rw1[1024+k, j] --
__global__ __launch_bounds__(256) void cb_part_k(const float* __restrict__ slot_init,
                                                 const float* __restrict__ rw1,
                                                 float* __restrict__ cbp) {
    __shared__ float sm[64];
    int tid = threadIdx.x;
    if (tid < 64) {
        float s = 0.f;
        for (int i = 0; i < 64; ++i) s += slot_init[i * 64 + tid];
        sm[tid] = s * (1.0f / 64.0f);
    }
    __syncthreads();
    int j = blockIdx.x * 256 + tid;
    int k0 = blockIdx.y * 64;
    float acc = 0.f;
#pragma unroll 8
    for (int k = 0; k < 64; ++k)
        acc = fmaf(sm[k], rw1[(size_t)(1024 + k0 + k) * 1024 + j], acc);
    cbp[(size_t)blockIdx.y * 1024 + j] = acc;
}

__global__ __launch_bounds__(256) void cb_comb_k(const float* __restrict__ cbp,
                                                 float* __restrict__ cb) {
    int j = blockIdx.x * 256 + threadIdx.x;
    float acc = 0.f;
#pragma unroll
    for (int c = 0; c < 16; ++c) acc += cbp[(size_t)c * 1024 + j];
    cb[j] = acc;
}

// ---------------- K1: rw1[:1024] -> transposed split-f16 planes [N=1024][K=1024] ------
__global__ __launch_bounds__(256) void wsplitT_k(const float* __restrict__ rw1,
                                                 _Float16* __restrict__ whiT,
                                                 _Float16* __restrict__ wloT) {
    __shared__ float t[32][33];
    int n0 = blockIdx.x * 32, k0 = blockIdx.y * 32;
    int tx = threadIdx.x & 31, ty = threadIdx.x >> 5;   // 32 x 8
#pragma unroll
    for (int i = 0; i < 32; i += 8)
        t[ty + i][tx] = rw1[(size_t)(k0 + ty + i) * 1024 + n0 + tx];
    __syncthreads();
#pragma unroll
    for (int i = 0; i < 32; i += 8) {
        float v = t[tx][ty + i];
        _Float16 h = (_Float16)v;
        _Float16 l = (_Float16)(v - (float)h);
        whiT[(size_t)(n0 + ty + i) * 1024 + k0 + tx] = h;
        wloT[(size_t)(n0 + ty + i) * 1024 + k0 + tx] = l;
    }
}

// ---------------- K1a: x -> split f16 hi/lo planes (row-major, K-contig) --------------
__global__ __launch_bounds__(256) void xsplit_k(const float* __restrict__ x,
                                                _Float16* __restrict__ xhi,
                                                _Float16* __restrict__ xlo) {
    size_t i = ((size_t)blockIdx.x * 256 + threadIdx.x) * 8;
    float4 a = *(const float4*)(x + i);
    float4 b = *(const float4*)(x + i + 4);
    float v[8] = {a.x, a.y, a.z, a.w, b.x, b.y, b.z, b.w};
    f16x8 h, l;
#pragma unroll
    for (int j = 0; j < 8; ++j) {
        _Float16 hv = (_Float16)v[j];
        h[j] = hv;
        l[j] = (_Float16)(v[j] - (float)hv);
    }
    *(f16x8*)(xhi + i) = h;
    *(f16x8*)(xlo + i) = l;
}

// ---------------- K1b: split-fp16 MFMA routing GEMM (pre-split 4-plane) ---------------
// C[M,N] fp32 = gelu(A @ B^T + bias1 + bias2); A = Ah+Al [M,K] f16, B = Bh+Bl [N,K] f16.
// 3-term Markidis: al*bh + ah*bl + ah*bh with fp32 MFMA accumulation.
__global__ __launch_bounds__(256) void hgemm4_k(const _Float16* __restrict__ Ah,
                                                const _Float16* __restrict__ Al,
                                                const _Float16* __restrict__ Bh,
                                                const _Float16* __restrict__ Bl,
                                                const float* __restrict__ bias1,
                                                const float* __restrict__ bias2,
                                                float* __restrict__ C,
                                                int M, int N, int K) {
    __shared__ __align__(16) _Float16 Ahs[128][32];
    __shared__ __align__(16) _Float16 Als[128][32];
    __shared__ __align__(16) _Float16 Bhs[128][32];
    __shared__ __align__(16) _Float16 Bls[128][32];
    const int tid = threadIdx.x;
    const int wid = tid >> 6;
    const int lane = tid & 63;
    const int swz = xcd_swz(gridDim.x * gridDim.y);
    const int brow = (swz / gridDim.x) * 128;
    const int bcol = (swz % gridDim.x) * 128;
    const int wr = (wid >> 1) * 64;
    const int wc = (wid & 1) * 64;

    const int rb = lane >> 2;
    const int cbk = (lane & 3) * 8;
    const int fr = lane & 15;
    const int fk = (lane >> 4) * 8;

    f32x4 acc[4][4];
#pragma unroll
    for (int m = 0; m < 4; ++m)
#pragma unroll
        for (int n = 0; n < 4; ++n)
            acc[m][n] = f32x4{0.f, 0.f, 0.f, 0.f};

    for (int k0 = 0; k0 < K; k0 += 32) {
#pragma unroll
        for (int i = 0; i < 2; ++i) {
            int r0 = wid * 32 + i * 16;
            const _Float16* gah = Ah + (size_t)(brow + r0 + rb) * K + k0 + cbk;
            __builtin_amdgcn_global_load_lds(
                (const __attribute__((address_space(1))) void*)gah,
                (__attribute__((address_space(3))) void*)&Ahs[r0][0], 16, 0, 0);
            const _Float16* gal = Al + (size_t)(brow + r0 + rb) * K + k0 + cbk;
            __builtin_amdgcn_global_load_lds(
                (const __attribute__((address_space(1))) void*)gal,
                (__attribute__((address_space(3))) void*)&Als[r0][0], 16, 0, 0);
            const _Float16* gbh = Bh + (size_t)(bcol + r0 + rb) * K + k0 + cbk;
            __builtin_amdgcn_global_load_lds(
                (const __attribute__((address_space(1))) void*)gbh,
                (__attribute__((address_space(3))) void*)&Bhs[r0][0], 16, 0, 0);
            const _Float16* gbl = Bl + (size_t)(bcol + r0 + rb) * K + k0 + cbk;
            __builtin_amdgcn_global_load_lds(
                (const __attribute__((address_space(1))) void*)gbl,
                (__attribute__((address_space(3))) void*)&Bls[r0][0], 16, 0, 0);
        }
        __syncthreads();

        f16x8 afh[4], afl[4], bfh[4], bfl[4];
#pragma unroll
        for (int m = 0; m < 4; ++m) {
            afh[m] = *(const f16x8*)&Ahs[wr + m * 16 + fr][fk];
            afl[m] = *(const f16x8*)&Als[wr + m * 16 + fr][fk];
        }
#pragma unroll
        for (int n = 0; n < 4; ++n) {
            bfh[n] = *(const f16x8*)&Bhs[wc + n * 16 + fr][fk];
            bfl[n] = *(const f16x8*)&Bls[wc + n * 16 + fr][fk];
        }
#pragma unroll
        for (int m = 0; m < 4; ++m)
#pragma unroll
            for (int n = 0; n < 4; ++n) {
                acc[m][n] = __builtin_amdgcn_mfma_f32_16x16x32_f16(afl[m], bfh[n], acc[m][n], 0, 0, 0);
                acc[m][n] = __builtin_amdgcn_mfma_f32_16x16x32_f16(afh[m], bfl[n], acc[m][n], 0, 0, 0);
                acc[m][n] = __builtin_amdgcn_mfma_f32_16x16x32_f16(afh[m], bfh[n], acc[m][n], 0, 0, 0);
            }
        __syncthreads();
    }

    const int crow = (lane >> 4) * 4;
#pragma unroll
    for (int m = 0; m < 4; ++m) {
        int row0 = brow + wr + m * 16 + crow;
#pragma unroll
        for (int n = 0; n < 4; ++n) {
            int col = bcol + wc + n * 16 + fr;
            float bv = bias1[col] + bias2[col];
#pragma unroll
            for (int r = 0; r < 4; ++r) {
                float v = acc[m][n][r] + bv;
                C[(size_t)(row0 + r) * N + col] = gelu_f(v);
            }
        }
    }
}

// ---------------- K2: route logits, N=64 ----------------
__global__ __launch_bounds__(256) void logits_k(const float* __restrict__ A,
                                                const float* __restrict__ Bw,
                                                const float* __restrict__ rb2,
                                                const float* __restrict__ taup,
                                                float* __restrict__ Cl,
                                                int M, int K) {
    __shared__ float As[16][64];
    __shared__ float Bs[16][64];
    const int tid = threadIdx.x;
    const int m0 = blockIdx.x * 64;
    const int tx = (tid & 15) * 4;
    const int ty = (tid >> 4) * 4;
    const int arow = tid >> 2;
    const int acol = (tid & 3) * 4;
    const int brl = tid >> 4;
    const int bcl = (tid & 15) * 4;

    float acc[4][4] = {};

    for (int k0 = 0; k0 < K; k0 += 16) {
        float4 av = *(const float4*)(A + (size_t)(m0 + arow) * K + k0 + acol);
        float4 bv = *(const float4*)(Bw + (size_t)(k0 + brl) * 64 + bcl);
        As[acol + 0][arow] = av.x;
        As[acol + 1][arow] = av.y;
        As[acol + 2][arow] = av.z;
        As[acol + 3][arow] = av.w;
        *(float4*)&Bs[brl][bcl] = bv;
        __syncthreads();
#pragma unroll
        for (int kk = 0; kk < 16; ++kk) {
            float a[4], b[4];
            *(float4*)&a[0] = *(const float4*)&As[kk][ty];
            *(float4*)&b[0] = *(const float4*)&Bs[kk][tx];
#pragma unroll
            for (int i = 0; i < 4; ++i)
#pragma unroll
                for (int j = 0; j < 4; ++j)
                    acc[i][j] = fmaf(a[i], b[j], acc[i][j]);
        }
        __syncthreads();
    }
    float inv = 1.0f / (fabsf(taup[0]) + 0.1f);
#pragma unroll
    for (int i = 0; i < 4; ++i)
#pragma unroll
        for (int j = 0; j < 4; ++j)
            Cl[(size_t)(m0 + ty + i) * 64 + tx + j] = (acc[i][j] + rb2[tx + j]) * inv;
}

// ---------------- K3: top-32-of-64 + softmax -> dense alpha (fp32 + f16 copy) --------
__global__ __launch_bounds__(256) void topk_k(const float* __restrict__ logits,
                                              float* __restrict__ alpha,
                                              _Float16* __restrict__ alpha16) {
    int wave = threadIdx.x >> 6;
    int lane = threadIdx.x & 63;
    int t = blockIdx.x * 4 + wave;
    float li = logits[(size_t)t * 64 + lane];
    float m = li;
#pragma unroll
    for (int off = 32; off; off >>= 1) m = fmaxf(m, __shfl_xor(m, off, 64));
    int cnt = 0;
    for (int off = 1; off < 64; ++off) {
        int j = (lane + off) & 63;
        float lj = __shfl(li, j, 64);
        cnt += (lj > li) || (lj == li && j < lane);
    }
    float e = (cnt < 32) ? expf(li - m) : 0.0f;
    float s = e;
#pragma unroll
    for (int off = 32; off; off >>= 1) s += __shfl_xor(s, off, 64);
    float a = e / s;
    alpha[(size_t)t * 64 + lane] = a;
    alpha16[(size_t)t * 64 + lane] = (_Float16)a;
}

// ---------------- K4: slot pooling (T-split partial sums) ----------------
__global__ __launch_bounds__(256) void pool_part_k(const float* __restrict__ x,
                                                   const float* __restrict__ alpha,
                                                   float* __restrict__ part,
                                                   float* __restrict__ partw) {
    int bh = blockIdx.x;
    int c = blockIdx.y;
    int b = bh >> 4, h = bh & 15;
    int tid = threadIdx.x;
    int s = tid >> 6, d = tid & 63;
    __shared__ float lx[16][64];
    __shared__ float la[16][4];
    float acc = 0.f, wacc = 0.f;
    const int tchunk = Tt / 8;
    const int t0base = c * tchunk;
    for (int t0 = 0; t0 < tchunk; t0 += 16) {
        int ttr = tid >> 4;
        int ddr = (tid & 15) * 4;
        size_t trow = (size_t)b * Tt + t0base + t0 + ttr;
        float4 xv = *(const float4*)(x + trow * Dd + h * 64 + ddr);
        *(float4*)&lx[ttr][ddr] = xv;
        if (tid < 64) {
            int tt2 = tid >> 2, ss = tid & 3;
            la[tt2][ss] = alpha[((size_t)b * Tt + t0base + t0 + tt2) * 64 + h * 4 + ss];
        }
        __syncthreads();
#pragma unroll
        for (int q = 0; q < 16; ++q) {
            float av = la[q][s];
            acc = fmaf(av, lx[q][d], acc);
            wacc += av;
        }
        __syncthreads();
    }
    part[(((size_t)c * 64 + bh) * 4 + s) * 64 + d] = acc;
    if (d == 0) partw[((size_t)c * 64 + bh) * 4 + s] = wacc;
}

__global__ __launch_bounds__(256) void pool_comb_k(const float* __restrict__ part,
                                                   const float* __restrict__ partw,
                                                   float* __restrict__ slot_in) {
    int bh = blockIdx.x;
    int tid = threadIdx.x;
    int s = tid >> 6, d = tid & 63;
    float acc = 0.f, w = 0.f;
    for (int c = 0; c < 8; ++c) {
        acc += part[(((size_t)c * 64 + bh) * 4 + s) * 64 + d];
        w   += partw[((size_t)c * 64 + bh) * 4 + s];
    }
    slot_in[((size_t)bh * 4 + s) * 64 + d] = acc / (w + 1e-8f);
}

// ---------------- K5: GRU + slot MLP, one wave per slot ----------------
__global__ __launch_bounds__(64) void gru_k(const float* __restrict__ slot_in,
                                            const float* __restrict__ slot_init,
                                            const float* __restrict__ gwi,
                                            const float* __restrict__ gwh,
                                            const float* __restrict__ gbi,
                                            const float* __restrict__ gbh,
                                            const float* __restrict__ hpw,
                                            const float* __restrict__ hpb,
                                            const float* __restrict__ ohw,
                                            const float* __restrict__ ohb,
                                            float* __restrict__ S_new) {
    int slot = blockIdx.x;
    int hs = slot & 63;
    int d = threadIdx.x;
    __shared__ float si[64], hp[64], hn[64], g[256];
    si[d] = slot_in[(size_t)slot * 64 + d];
    hp[d] = slot_init[(size_t)hs * 64 + d];
    __syncthreads();
    float gi_r = gbi[d], gi_z = gbi[64 + d], gi_n = gbi[128 + d];
    float gh_r = gbh[d], gh_z = gbh[64 + d], gh_n = gbh[128 + d];
    for (int k = 0; k < 64; ++k) {
        float sv = si[k], hv = hp[k];
        gi_r = fmaf(sv, gwi[(size_t)(d) * 64 + k], gi_r);
        gi_z = fmaf(sv, gwi[(size_t)(64 + d) * 64 + k], gi_z);
        gi_n = fmaf(sv, gwi[(size_t)(128 + d) * 64 + k], gi_n);
        gh_r = fmaf(hv, gwh[(size_t)(d) * 64 + k], gh_r);
        gh_z = fmaf(hv, gwh[(size_t)(64 + d) * 64 + k], gh_z);
        gh_n = fmaf(hv, gwh[(size_t)(128 + d) * 64 + k], gh_n);
    }
    float r = 1.0f / (1.0f + expf(-(gi_r + gh_r)));
    float z = 1.0f / (1.0f + expf(-(gi_z + gh_z)));
    float n = tanhf(gi_n + r * gh_n);
    float hnew = (1.0f - z) * n + z * hp[d];
    hn[d] = hnew;
    __syncthreads();
    float p0 = hpb[d], p1 = hpb[64 + d], p2 = hpb[128 + d], p3 = hpb[192 + d];
    for (int k = 0; k < 64; ++k) {
        float hv = hn[k];
        p0 = fmaf(hv, hpw[(size_t)k * 256 + d], p0);
        p1 = fmaf(hv, hpw[(size_t)k * 256 + 64 + d], p1);
        p2 = fmaf(hv, hpw[(size_t)k * 256 + 128 + d], p2);
        p3 = fmaf(hv, hpw[(size_t)k * 256 + 192 + d], p3);
    }
    g[d] = gelu_f(p0); g[64 + d] = gelu_f(p1); g[128 + d] = gelu_f(p2); g[192 + d] = gelu_f(p3);
    __syncthreads();
    float o = ohb[d];
    for (int j = 0; j < 256; ++j) o = fmaf(g[j], ohw[(size_t)j * 64 + d], o);
    S_new[(size_t)slot * 64 + d] = o;
}

// ---------------- K6: PT[b][j][hs] = sum_d Snew[b,hs,d] * vpw[h*64+d, j]  (f16) -------
// grid (HM/256, H); one thread per j, 16 accumulators (4 b x 4 s); coalesced vpw reads.
__global__ __launch_bounds__(256) void pmat_k(const float* __restrict__ Snew,
                                              const float* __restrict__ vpw,
                                              _Float16* __restrict__ PT) {
    const int h = blockIdx.y;
    const int tid = threadIdx.x;
    const int j = blockIdx.x * 256 + tid;
    __shared__ float S[16][64];          // [(b*4+s)][d] for this head
    for (int i = tid; i < 1024; i += 256) {
        int row = i >> 6, d = i & 63;
        int b = row >> 2, s = row & 3;
        S[row][d] = Snew[((size_t)b * 64 + h * 4 + s) * 64 + d];
    }
    __syncthreads();
    float acc[16];
#pragma unroll
    for (int r = 0; r < 16; ++r) acc[r] = 0.f;
    const float* wp = vpw + (size_t)h * 64 * HMm + j;
#pragma unroll 4
    for (int d = 0; d < 64; ++d) {
        float w = wp[(size_t)d * HMm];
#pragma unroll
        for (int r = 0; r < 16; ++r) acc[r] = fmaf(S[r][d], w, acc[r]);
    }
#pragma unroll
    for (int b = 0; b < 4; ++b) {
        f16x4 o;
#pragma unroll
        for (int s = 0; s < 4; ++s) o[s] = (_Float16)acc[b * 4 + s];
        *(f16x4*)&PT[((size_t)b * HMm + j) * 64 + h * 4] = o;
    }
}

// ---------------- K7: transpose + fp32->fp16 convert: out[N,K] = (f16) in[K,N]^T -----
__global__ __launch_bounds__(256) void transp_f16_k(const float* __restrict__ in,
                                                    _Float16* __restrict__ out,
                                                    int K, int N) {
    __shared__ float t[32][33];
    int n0 = blockIdx.x * 32, k0 = blockIdx.y * 32;
    int tx = threadIdx.x & 31, ty = threadIdx.x >> 5;   // 32 x 8
#pragma unroll
    for (int i = 0; i < 32; i += 8)
        t[ty + i][tx] = in[(size_t)(k0 + ty + i) * N + n0 + tx];
    __syncthreads();
#pragma unroll
    for (int i = 0; i < 32; i += 8)
        out[(size_t)(n0 + ty + i) * K + k0 + tx] = (_Float16)t[tx][ty + i];
}

// ---------------- K8: fp16 MFMA GEMM: C = act(A[M,K] @ Bt[N,K]^T + bias) --------------
// 128x128 tile, BK=64, 4 waves, m97 structure + XCD swizzle.
template <int DO_GELU, int OUT_F16>
__global__ __launch_bounds__(256) void hgemm_k(const _Float16* __restrict__ A,
                                               const _Float16* __restrict__ Bt,
                                               const float* __restrict__ bias,
                                               void* __restrict__ Cv,
                                               int M, int N, int K) {
    __shared__ __align__(16) _Float16 As[128][64];
    __shared__ __align__(16) _Float16 Bs[128][64];
    const int tid = threadIdx.x;
    const int wid = tid >> 6;
    const int lane = tid & 63;
    const int swz = xcd_swz(gridDim.x * gridDim.y);
    const int brow = (swz / gridDim.x) * 128;
    const int bcol = (swz % gridDim.x) * 128;
    const int wr = (wid >> 1) * 64;
    const int wc = (wid & 1) * 64;

    f32x4 acc[4][4];
#pragma unroll
    for (int m = 0; m < 4; ++m)
#pragma unroll
        for (int n = 0; n < 4; ++n)
            acc[m][n] = f32x4{0.f, 0.f, 0.f, 0.f};

    const int lrow = lane >> 3;
    const int lcol = (lane & 7) * 8;

    const int fr = lane & 15;
    const int fk = (lane >> 4) * 8;

    for (int k0 = 0; k0 < K; k0 += 64) {
#pragma unroll
        for (int i = 0; i < 4; ++i) {
            int seg = wid * 4 + i;
            const _Float16* g = A + (size_t)(brow + seg * 8 + lrow) * K + k0 + lcol;
            __builtin_amdgcn_global_load_lds(
                (const __attribute__((address_space(1))) void*)g,
                (__attribute__((address_space(3))) void*)&As[seg * 8][0], 16, 0, 0);
        }
#pragma unroll
        for (int i = 0; i < 4; ++i) {
            int seg = wid * 4 + i;
            const _Float16* g = Bt + (size_t)(bcol + seg * 8 + lrow) * K + k0 + lcol;
            __builtin_amdgcn_global_load_lds(
                (const __attribute__((address_space(1))) void*)g,
                (__attribute__((address_space(3))) void*)&Bs[seg * 8][0], 16, 0, 0);
        }
        __syncthreads();
#pragma unroll
        for (int kb = 0; kb < 2; ++kb) {
            f16x8 af[4], bf[4];
#pragma unroll
            for (int m = 0; m < 4; ++m)
                af[m] = *(const f16x8*)&As[wr + m * 16 + fr][kb * 32 + fk];
#pragma unroll
            for (int n = 0; n < 4; ++n)
                bf[n] = *(const f16x8*)&Bs[wc + n * 16 + fr][kb * 32 + fk];
#pragma unroll
            for (int m = 0; m < 4; ++m)
#pragma unroll
                for (int n = 0; n < 4; ++n)
                    acc[m][n] = __builtin_amdgcn_mfma_f32_16x16x32_f16(af[m], bf[n], acc[m][n], 0, 0, 0);
        }
        __syncthreads();
    }

    const int crow = (lane >> 4) * 4;
#pragma unroll
    for (int m = 0; m < 4; ++m) {
        int row0 = brow + wr + m * 16 + crow;
#pragma unroll
        for (int n = 0; n < 4; ++n) {
            int col = bcol + wc + n * 16 + fr;
            float bv = bias ? bias[col] : 0.f;
#pragma unroll
            for (int r = 0; r < 4; ++r) {
                float v = acc[m][n][r] + bv;
                if (DO_GELU) v = gelu_f(v);
                size_t idx = (size_t)(row0 + r) * N + col;
                if (OUT_F16) ((_Float16*)Cv)[idx] = (_Float16)v;
                else ((float*)Cv)[idx] = v;
            }
        }
    }
}

extern "C" void kernel_launch(void* const* d_in, const int* in_sizes, int n_in,
                              void* d_out, int out_size, void* d_ws, size_t ws_size,
                              hipStream_t stream) {
    const float* x         = (const float*)d_in[0];
    const float* slot_init = (const float*)d_in[1];
    const float* rw1       = (const float*)d_in[2];
    const float* rb1       = (const float*)d_in[3];
    const float* rw2       = (const float*)d_in[4];
    const float* rb2       = (const float*)d_in[5];
    const float* gwi       = (const float*)d_in[6];
    const float* gwh       = (const float*)d_in[7];
    const float* gbi       = (const float*)d_in[8];
    const float* gbh       = (const float*)d_in[9];
    const float* hpw       = (const float*)d_in[10];
    const float* hpb       = (const float*)d_in[11];
    const float* ohw       = (const float*)d_in[12];
    const float* ohb       = (const float*)d_in[13];
    const float* vpw       = (const float*)d_in[14];
    const float* vpb       = (const float*)d_in[15];
    const float* vow       = (const float*)d_in[16];
    const float* vob       = (const float*)d_in[17];
    const float* opw       = (const float*)d_in[18];
    const float* opb       = (const float*)d_in[19];
    const float* tau       = (const float*)d_in[20];
    float* out = (float*)d_out;

    float* ws = (float*)d_ws;
    size_t off = 0;
    auto alloc = [&](size_t nfloats) { float* p = ws + off; off += (nfloats + 63) & ~(size_t)63; return p; };

    float* cb     = alloc(1024);
    float* cbp    = alloc(16 * 1024);
    float* h1     = alloc((size_t)MTOK * 1024);            // fp32; dead after logits:
    _Float16* v1cc = (_Float16*)h1;                         //   reused as v1 row-chunk [8192,4096] f16
    float* logits = alloc((size_t)MTOK * 64);
    float* alpha  = alloc((size_t)MTOK * 64);
    _Float16* alpha16 = (_Float16*)alloc((size_t)MTOK * 64 / 2);
    float* slotin = alloc(256 * 64);
    float* part   = alloc((size_t)8 * 64 * 4 * 64);
    float* partw  = alloc(8 * 64 * 4);
    float* Snew   = alloc(256 * 64);
    _Float16* PT   = (_Float16*)alloc((size_t)Bb * HMm * 64 / 2);  // [4,4096,64] f16
    _Float16* vowT = (_Float16*)alloc((size_t)Dd * HMm / 2);       // [1024,4096] f16
    _Float16* opwT = (_Float16*)alloc((size_t)Dd * Dd / 2);        // [1024,1024] f16
    _Float16* v2f16 = (_Float16*)alloc((size_t)MTOK * Dd / 2);     // [16384,1024] f16
    _Float16* w1hiT = (_Float16*)alloc((size_t)Dd * Dd / 2);       // [1024,1024] f16
    _Float16* w1loT = (_Float16*)alloc((size_t)Dd * Dd / 2);       // [1024,1024] f16

    // x split planes live in d_out (dead until final GEMM overwrites it): 32MB + 32MB
    _Float16* xhi = (_Float16*)d_out;
    _Float16* xlo = xhi + (size_t)MTOK * Dd;

    // ---- routing: pre-split x + 4-plane split-fp16 MFMA GEMM + fp32 logits ----
    cb_part_k<<<dim3(4, 16), 256, 0, stream>>>(slot_init, rw1, cbp);
    cb_comb_k<<<4, 256, 0, stream>>>(cbp, cb);
    wsplitT_k<<<dim3(Dd / 32, Dd / 32), 256, 0, stream>>>(rw1, w1hiT, w1loT);
    xsplit_k<<<(MTOK * Dd) / (256 * 8), 256, 0, stream>>>(x, xhi, xlo);
    hgemm4_k<<<dim3(Dd / 128, MTOK / 128), 256, 0, stream>>>(
        xhi, xlo, w1hiT, w1loT, rb1, cb, h1, MTOK, Dd, Dd);
    logits_k<<<MTOK / 64, 256, 0, stream>>>(h1, rw2, rb2, tau, logits, MTOK, 1024);
    topk_k<<<MTOK / 4, 256, 0, stream>>>(logits, alpha, alpha16);

    // ---- weight transposes (fp32 -> fp16 [N,K]) ----
    transp_f16_k<<<dim3(Dd / 32, HMm / 32), 256, 0, stream>>>(vow, vowT, HMm, Dd);
    transp_f16_k<<<dim3(Dd / 32, Dd / 32), 256, 0, stream>>>(opw, opwT, Dd, Dd);

    // ---- slot pooling + GRU + slot MLP ----
    pool_part_k<<<dim3(64, 8), 256, 0, stream>>>(x, alpha, part, partw);
    pool_comb_k<<<64, 256, 0, stream>>>(part, partw, slotin);
    gru_k<<<256, 64, 0, stream>>>(slotin, slot_init, gwi, gwh, gbi, gbh,
                                  hpw, hpb, ohw, ohb, Snew);

    // ---- P[b] = S_emb[b] @ vpw (stored transposed f16 [b][j][hs]) ----
    pmat_k<<<dim3(HMm / 256, Hh), 256, 0, stream>>>(Snew, vpw, PT);

    // ---- value MLP: v1 = gelu(alpha @ P[b] + vpb) via K=64 MFMA GEMM, then GEMM2 ----
    for (int c = 0; c < 2; ++c) {
        for (int q = 0; q < 2; ++q) {
            int b = c * 2 + q;
            hgemm_k<1, 1><<<dim3(HMm / 128, Tt / 128), 256, 0, stream>>>(
                alpha16 + (size_t)b * Tt * 64, PT + (size_t)b * HMm * 64, vpb,
                v1cc + (size_t)q * Tt * HMm, Tt, HMm, 64);
        }
        hgemm_k<0, 1><<<dim3(Dd / 128, 8192 / 128), 256, 0, stream>>>(
            v1cc, vowT, vob, v2f16 + (size_t)c * 8192 * Dd, 8192, Dd, HMm);
    }
    // ---- final projection (fp32 out; overwrites the xhi/xlo scratch) ----
    hgemm_k<0, 0><<<dim3(Dd / 128, MTOK / 128), 256, 0, stream>>>(
        v2f16, opwT, opb, out, MTOK, Dd, Dd);

    (void)in_sizes; (void)n_in; (void)out_size; (void)ws_size;
}

// Round 7
// 620.764 us; speedup vs baseline: 1.3717x; 1.0826x over previous
//
#include <hip/hip_runtime.h>
#include <cstddef>
#include <cstdint>

// Problem constants
#define Bb 4
#define Tt 4096
#define Dd 1024
#define Hh 16
#define HDd 64
#define NSs 64
#define SPHh 4
#define HMm 4096
#define MTOK (Bb*Tt)   // 16384

typedef _Float16 f16x8 __attribute__((ext_vector_type(8)));
typedef _Float16 f16x4 __attribute__((ext_vector_type(4)));
typedef float f32x4 __attribute__((ext_vector_type(4)));

__device__ __forceinline__ float gelu_f(float x) {
    return 0.5f * x * (1.0f + erff(x * 0.70710678118654752440f));
}

// XCD-chunked bijective block swizzle (requires nwg % 8 == 0; all launches comply)
__device__ __forceinline__ int xcd_swz(int nwg) {
    int orig = blockIdx.y * gridDim.x + blockIdx.x;
    int cpx = nwg >> 3;
    return (orig & 7) * cpx + (orig >> 3);
}

// ---------------- K0: cb partials ----------------
__global__ __launch_bounds__(256) void cb_part_k(const float* __restrict__ slot_init,
                                                 const float* __restrict__ rw1,
                                                 float* __restrict__ cbp) {
    __shared__ float sm[64];
    int tid = threadIdx.x;
    if (tid < 64) {
        float s = 0.f;
        for (int i = 0; i < 64; ++i) s += slot_init[i * 64 + tid];
        sm[tid] = s * (1.0f / 64.0f);
    }
    __syncthreads();
    int j = blockIdx.x * 256 + tid;
    int k0 = blockIdx.y * 64;
    float acc = 0.f;
#pragma unroll 8
    for (int k = 0; k < 64; ++k)
        acc = fmaf(sm[k], rw1[(size_t)(1024 + k0 + k) * 1024 + j], acc);
    cbp[(size_t)blockIdx.y * 1024 + j] = acc;
}

__global__ __launch_bounds__(256) void cb_comb_k(const float* __restrict__ cbp,
                                                 float* __restrict__ cb) {
    int j = blockIdx.x * 256 + threadIdx.x;
    float acc = 0.f;
#pragma unroll
    for (int c = 0; c < 16; ++c) acc += cbp[(size_t)c * 1024 + j];
    cb[j] = acc;
}

// ---------------- K1: rw1[:1024] -> transposed split-f16 planes ----------------
__global__ __launch_bounds__(256) void wsplitT_k(const float* __restrict__ rw1,
                                                 _Float16* __restrict__ whiT,
                                                 _Float16* __restrict__ wloT) {
    __shared__ float t[32][33];
    int n0 = blockIdx.x * 32, k0 = blockIdx.y * 32;
    int tx = threadIdx.x & 31, ty = threadIdx.x >> 5;
#pragma unroll
    for (int i = 0; i < 32; i += 8)
        t[ty + i][tx] = rw1[(size_t)(k0 + ty + i) * 1024 + n0 + tx];
    __syncthreads();
#pragma unroll
    for (int i = 0; i < 32; i += 8) {
        float v = t[tx][ty + i];
        _Float16 h = (_Float16)v;
        _Float16 l = (_Float16)(v - (float)h);
        whiT[(size_t)(n0 + ty + i) * 1024 + k0 + tx] = h;
        wloT[(size_t)(n0 + ty + i) * 1024 + k0 + tx] = l;
    }
}

// ---------------- K1a: x -> split f16 hi/lo planes ----------------
__global__ __launch_bounds__(256) void xsplit_k(const float* __restrict__ x,
                                                _Float16* __restrict__ xhi,
                                                _Float16* __restrict__ xlo) {
    size_t i = ((size_t)blockIdx.x * 256 + threadIdx.x) * 8;
    float4 a = *(const float4*)(x + i);
    float4 b = *(const float4*)(x + i + 4);
    float v[8] = {a.x, a.y, a.z, a.w, b.x, b.y, b.z, b.w};
    f16x8 h, l;
#pragma unroll
    for (int j = 0; j < 8; ++j) {
        _Float16 hv = (_Float16)v[j];
        h[j] = hv;
        l[j] = (_Float16)(v[j] - (float)hv);
    }
    *(f16x8*)(xhi + i) = h;
    *(f16x8*)(xlo + i) = l;
}

// ---------------- K1b: split-fp16 MFMA routing GEMM (pre-split 4-plane) ---------------
__global__ __launch_bounds__(256) void hgemm4_k(const _Float16* __restrict__ Ah,
                                                const _Float16* __restrict__ Al,
                                                const _Float16* __restrict__ Bh,
                                                const _Float16* __restrict__ Bl,
                                                const float* __restrict__ bias1,
                                                const float* __restrict__ bias2,
                                                float* __restrict__ C,
                                                int M, int N, int K) {
    __shared__ __align__(16) _Float16 Ahs[128][32];
    __shared__ __align__(16) _Float16 Als[128][32];
    __shared__ __align__(16) _Float16 Bhs[128][32];
    __shared__ __align__(16) _Float16 Bls[128][32];
    const int tid = threadIdx.x;
    const int wid = tid >> 6;
    const int lane = tid & 63;
    const int swz = xcd_swz(gridDim.x * gridDim.y);
    const int brow = (swz / gridDim.x) * 128;
    const int bcol = (swz % gridDim.x) * 128;
    const int wr = (wid >> 1) * 64;
    const int wc = (wid & 1) * 64;

    const int rb = lane >> 2;
    const int cbk = (lane & 3) * 8;
    const int fr = lane & 15;
    const int fk = (lane >> 4) * 8;

    f32x4 acc[4][4];
#pragma unroll
    for (int m = 0; m < 4; ++m)
#pragma unroll
        for (int n = 0; n < 4; ++n)
            acc[m][n] = f32x4{0.f, 0.f, 0.f, 0.f};

    for (int k0 = 0; k0 < K; k0 += 32) {
#pragma unroll
        for (int i = 0; i < 2; ++i) {
            int r0 = wid * 32 + i * 16;
            const _Float16* gah = Ah + (size_t)(brow + r0 + rb) * K + k0 + cbk;
            __builtin_amdgcn_global_load_lds(
                (const __attribute__((address_space(1))) void*)gah,
                (__attribute__((address_space(3))) void*)&Ahs[r0][0], 16, 0, 0);
            const _Float16* gal = Al + (size_t)(brow + r0 + rb) * K + k0 + cbk;
            __builtin_amdgcn_global_load_lds(
                (const __attribute__((address_space(1))) void*)gal,
                (__attribute__((address_space(3))) void*)&Als[r0][0], 16, 0, 0);
            const _Float16* gbh = Bh + (size_t)(bcol + r0 + rb) * K + k0 + cbk;
            __builtin_amdgcn_global_load_lds(
                (const __attribute__((address_space(1))) void*)gbh,
                (__attribute__((address_space(3))) void*)&Bhs[r0][0], 16, 0, 0);
            const _Float16* gbl = Bl + (size_t)(bcol + r0 + rb) * K + k0 + cbk;
            __builtin_amdgcn_global_load_lds(
                (const __attribute__((address_space(1))) void*)gbl,
                (__attribute__((address_space(3))) void*)&Bls[r0][0], 16, 0, 0);
        }
        __syncthreads();

        f16x8 afh[4], afl[4], bfh[4], bfl[4];
#pragma unroll
        for (int m = 0; m < 4; ++m) {
            afh[m] = *(const f16x8*)&Ahs[wr + m * 16 + fr][fk];
            afl[m] = *(const f16x8*)&Als[wr + m * 16 + fr][fk];
        }
#pragma unroll
        for (int n = 0; n < 4; ++n) {
            bfh[n] = *(const f16x8*)&Bhs[wc + n * 16 + fr][fk];
            bfl[n] = *(const f16x8*)&Bls[wc + n * 16 + fr][fk];
        }
#pragma unroll
        for (int m = 0; m < 4; ++m)
#pragma unroll
            for (int n = 0; n < 4; ++n) {
                acc[m][n] = __builtin_amdgcn_mfma_f32_16x16x32_f16(afl[m], bfh[n], acc[m][n], 0, 0, 0);
                acc[m][n] = __builtin_amdgcn_mfma_f32_16x16x32_f16(afh[m], bfl[n], acc[m][n], 0, 0, 0);
                acc[m][n] = __builtin_amdgcn_mfma_f32_16x16x32_f16(afh[m], bfh[n], acc[m][n], 0, 0, 0);
            }
        __syncthreads();
    }

    const int crow = (lane >> 4) * 4;
#pragma unroll
    for (int m = 0; m < 4; ++m) {
        int row0 = brow + wr + m * 16 + crow;
#pragma unroll
        for (int n = 0; n < 4; ++n) {
            int col = bcol + wc + n * 16 + fr;
            float bv = bias1[col] + bias2[col];
#pragma unroll
            for (int r = 0; r < 4; ++r) {
                float v = acc[m][n][r] + bv;
                C[(size_t)(row0 + r) * N + col] = gelu_f(v);
            }
        }
    }
}

// ---------------- K2: route logits (fp32, register-blocked; bit-identical k-order) ----
// grid M/64 blocks, 256 threads; thread = 4 rows x 4 cols; A transposed in LDS.
__global__ __launch_bounds__(256) void logits2_k(const float* __restrict__ A,
                                                 const float* __restrict__ Bw,
                                                 const float* __restrict__ rb2,
                                                 const float* __restrict__ taup,
                                                 float* __restrict__ Cl) {
    __shared__ float At[16][68];   // [k][row], pad 68 (16B-aligned rows, 2-way banks)
    __shared__ float Bs[16][64];
    const int tid = threadIdx.x;
    const int m0 = blockIdx.x * 64;
    const int rg = tid >> 4;          // 0..15
    const int cg = tid & 15;          // 0..15
    const int srow = tid >> 2;        // 0..63
    const int skk  = (tid & 3) * 4;   // 0,4,8,12
    const int bk = tid >> 4;          // 0..15
    const int bc = (tid & 15) * 4;

    float acc[4][4] = {};

    for (int k0 = 0; k0 < 1024; k0 += 16) {
        float4 av = *(const float4*)(A + (size_t)(m0 + srow) * 1024 + k0 + skk);
        float4 bv = *(const float4*)(Bw + (size_t)(k0 + bk) * 64 + bc);
        __syncthreads();
        At[skk + 0][srow] = av.x;
        At[skk + 1][srow] = av.y;
        At[skk + 2][srow] = av.z;
        At[skk + 3][srow] = av.w;
        *(float4*)&Bs[bk][bc] = bv;
        __syncthreads();
#pragma unroll
        for (int k = 0; k < 16; ++k) {
            float4 a4 = *(const float4*)&At[k][rg * 4];
            float4 b4 = *(const float4*)&Bs[k][cg * 4];
            float a[4] = {a4.x, a4.y, a4.z, a4.w};
            float b[4] = {b4.x, b4.y, b4.z, b4.w};
#pragma unroll
            for (int i = 0; i < 4; ++i)
#pragma unroll
                for (int j = 0; j < 4; ++j)
                    acc[i][j] = fmaf(a[i], b[j], acc[i][j]);
        }
    }
    float inv = 1.0f / (fabsf(taup[0]) + 0.1f);
#pragma unroll
    for (int i = 0; i < 4; ++i)
#pragma unroll
        for (int j = 0; j < 4; ++j)
            Cl[(size_t)(m0 + rg * 4 + i) * 64 + cg * 4 + j] =
                (acc[i][j] + rb2[cg * 4 + j]) * inv;
}

// ---------------- K3: top-32-of-64 + softmax -> dense alpha ----------------
__global__ __launch_bounds__(256) void topk_k(const float* __restrict__ logits,
                                              float* __restrict__ alpha,
                                              _Float16* __restrict__ alpha16) {
    int wave = threadIdx.x >> 6;
    int lane = threadIdx.x & 63;
    int t = blockIdx.x * 4 + wave;
    float li = logits[(size_t)t * 64 + lane];
    float m = li;
#pragma unroll
    for (int off = 32; off; off >>= 1) m = fmaxf(m, __shfl_xor(m, off, 64));
    int cnt = 0;
    for (int off = 1; off < 64; ++off) {
        int j = (lane + off) & 63;
        float lj = __shfl(li, j, 64);
        cnt += (lj > li) || (lj == li && j < lane);
    }
    float e = (cnt < 32) ? expf(li - m) : 0.0f;
    float s = e;
#pragma unroll
    for (int off = 32; off; off >>= 1) s += __shfl_xor(s, off, 64);
    float a = e / s;
    alpha[(size_t)t * 64 + lane] = a;
    alpha16[(size_t)t * 64 + lane] = (_Float16)a;
}

// ---------------- K4: slot pooling ----------------
__global__ __launch_bounds__(256) void pool_part_k(const float* __restrict__ x,
                                                   const float* __restrict__ alpha,
                                                   float* __restrict__ part,
                                                   float* __restrict__ partw) {
    int bh = blockIdx.x;
    int c = blockIdx.y;
    int b = bh >> 4, h = bh & 15;
    int tid = threadIdx.x;
    int s = tid >> 6, d = tid & 63;
    __shared__ float lx[16][64];
    __shared__ float la[16][4];
    float acc = 0.f, wacc = 0.f;
    const int tchunk = Tt / 8;
    const int t0base = c * tchunk;
    for (int t0 = 0; t0 < tchunk; t0 += 16) {
        int ttr = tid >> 4;
        int ddr = (tid & 15) * 4;
        size_t trow = (size_t)b * Tt + t0base + t0 + ttr;
        float4 xv = *(const float4*)(x + trow * Dd + h * 64 + ddr);
        *(float4*)&lx[ttr][ddr] = xv;
        if (tid < 64) {
            int tt2 = tid >> 2, ss = tid & 3;
            la[tt2][ss] = alpha[((size_t)b * Tt + t0base + t0 + tt2) * 64 + h * 4 + ss];
        }
        __syncthreads();
#pragma unroll
        for (int q = 0; q < 16; ++q) {
            float av = la[q][s];
            acc = fmaf(av, lx[q][d], acc);
            wacc += av;
        }
        __syncthreads();
    }
    part[(((size_t)c * 64 + bh) * 4 + s) * 64 + d] = acc;
    if (d == 0) partw[((size_t)c * 64 + bh) * 4 + s] = wacc;
}

__global__ __launch_bounds__(256) void pool_comb_k(const float* __restrict__ part,
                                                   const float* __restrict__ partw,
                                                   float* __restrict__ slot_in) {
    int bh = blockIdx.x;
    int tid = threadIdx.x;
    int s = tid >> 6, d = tid & 63;
    float acc = 0.f, w = 0.f;
    for (int c = 0; c < 8; ++c) {
        acc += part[(((size_t)c * 64 + bh) * 4 + s) * 64 + d];
        w   += partw[((size_t)c * 64 + bh) * 4 + s];
    }
    slot_in[((size_t)bh * 4 + s) * 64 + d] = acc / (w + 1e-8f);
}

// ---------------- K5: GRU + slot MLP ----------------
__global__ __launch_bounds__(64) void gru_k(const float* __restrict__ slot_in,
                                            const float* __restrict__ slot_init,
                                            const float* __restrict__ gwi,
                                            const float* __restrict__ gwh,
                                            const float* __restrict__ gbi,
                                            const float* __restrict__ gbh,
                                            const float* __restrict__ hpw,
                                            const float* __restrict__ hpb,
                                            const float* __restrict__ ohw,
                                            const float* __restrict__ ohb,
                                            float* __restrict__ S_new) {
    int slot = blockIdx.x;
    int hs = slot & 63;
    int d = threadIdx.x;
    __shared__ float si[64], hp[64], hn[64], g[256];
    si[d] = slot_in[(size_t)slot * 64 + d];
    hp[d] = slot_init[(size_t)hs * 64 + d];
    __syncthreads();
    float gi_r = gbi[d], gi_z = gbi[64 + d], gi_n = gbi[128 + d];
    float gh_r = gbh[d], gh_z = gbh[64 + d], gh_n = gbh[128 + d];
    for (int k = 0; k < 64; ++k) {
        float sv = si[k], hv = hp[k];
        gi_r = fmaf(sv, gwi[(size_t)(d) * 64 + k], gi_r);
        gi_z = fmaf(sv, gwi[(size_t)(64 + d) * 64 + k], gi_z);
        gi_n = fmaf(sv, gwi[(size_t)(128 + d) * 64 + k], gi_n);
        gh_r = fmaf(hv, gwh[(size_t)(d) * 64 + k], gh_r);
        gh_z = fmaf(hv, gwh[(size_t)(64 + d) * 64 + k], gh_z);
        gh_n = fmaf(hv, gwh[(size_t)(128 + d) * 64 + k], gh_n);
    }
    float r = 1.0f / (1.0f + expf(-(gi_r + gh_r)));
    float z = 1.0f / (1.0f + expf(-(gi_z + gh_z)));
    float n = tanhf(gi_n + r * gh_n);
    float hnew = (1.0f - z) * n + z * hp[d];
    hn[d] = hnew;
    __syncthreads();
    float p0 = hpb[d], p1 = hpb[64 + d], p2 = hpb[128 + d], p3 = hpb[192 + d];
    for (int k = 0; k < 64; ++k) {
        float hv = hn[k];
        p0 = fmaf(hv, hpw[(size_t)k * 256 + d], p0);
        p1 = fmaf(hv, hpw[(size_t)k * 256 + 64 + d], p1);
        p2 = fmaf(hv, hpw[(size_t)k * 256 + 128 + d], p2);
        p3 = fmaf(hv, hpw[(size_t)k * 256 + 192 + d], p3);
    }
    g[d] = gelu_f(p0); g[64 + d] = gelu_f(p1); g[128 + d] = gelu_f(p2); g[192 + d] = gelu_f(p3);
    __syncthreads();
    float o = ohb[d];
    for (int j = 0; j < 256; ++j) o = fmaf(g[j], ohw[(size_t)j * 64 + d], o);
    S_new[(size_t)slot * 64 + d] = o;
}

// ---------------- K6: PT[b][j][hs] = sum_d Snew[b,hs,d] * vpw[h*64+d, j]  (f16) -------
__global__ __launch_bounds__(256) void pmat_k(const float* __restrict__ Snew,
                                              const float* __restrict__ vpw,
                                              _Float16* __restrict__ PT) {
    const int h = blockIdx.y;
    const int tid = threadIdx.x;
    const int j = blockIdx.x * 256 + tid;
    __shared__ float S[16][64];
    for (int i = tid; i < 1024; i += 256) {
        int row = i >> 6, d = i & 63;
        int b = row >> 2, s = row & 3;
        S[row][d] = Snew[((size_t)b * 64 + h * 4 + s) * 64 + d];
    }
    __syncthreads();
    float acc[16];
#pragma unroll
    for (int r = 0; r < 16; ++r) acc[r] = 0.f;
    const float* wp = vpw + (size_t)h * 64 * HMm + j;
#pragma unroll 4
    for (int d = 0; d < 64; ++d) {
        float w = wp[(size_t)d * HMm];
#pragma unroll
        for (int r = 0; r < 16; ++r) acc[r] = fmaf(S[r][d], w, acc[r]);
    }
#pragma unroll
    for (int b = 0; b < 4; ++b) {
        f16x4 o;
#pragma unroll
        for (int s = 0; s < 4; ++s) o[s] = (_Float16)acc[b * 4 + s];
        *(f16x4*)&PT[((size_t)b * HMm + j) * 64 + h * 4] = o;
    }
}

// ---------------- K7: transpose + fp32->fp16 convert ----------------
__global__ __launch_bounds__(256) void transp_f16_k(const float* __restrict__ in,
                                                    _Float16* __restrict__ out,
                                                    int K, int N) {
    __shared__ float t[32][33];
    int n0 = blockIdx.x * 32, k0 = blockIdx.y * 32;
    int tx = threadIdx.x & 31, ty = threadIdx.x >> 5;
#pragma unroll
    for (int i = 0; i < 32; i += 8)
        t[ty + i][tx] = in[(size_t)(k0 + ty + i) * N + n0 + tx];
    __syncthreads();
#pragma unroll
    for (int i = 0; i < 32; i += 8)
        out[(size_t)(n0 + ty + i) * K + k0 + tx] = (_Float16)t[tx][ty + i];
}

// ---------------- K8: generic fp16 MFMA GEMM (m97 structure + XCD swizzle) ------------
template <int DO_GELU, int OUT_F16>
__global__ __launch_bounds__(256) void hgemm_k(const _Float16* __restrict__ A,
                                               const _Float16* __restrict__ Bt,
                                               const float* __restrict__ bias,
                                               void* __restrict__ Cv,
                                               int M, int N, int K) {
    __shared__ __align__(16) _Float16 As[128][64];
    __shared__ __align__(16) _Float16 Bs[128][64];
    const int tid = threadIdx.x;
    const int wid = tid >> 6;
    const int lane = tid & 63;
    const int swz = xcd_swz(gridDim.x * gridDim.y);
    const int brow = (swz / gridDim.x) * 128;
    const int bcol = (swz % gridDim.x) * 128;
    const int wr = (wid >> 1) * 64;
    const int wc = (wid & 1) * 64;

    f32x4 acc[4][4];
#pragma unroll
    for (int m = 0; m < 4; ++m)
#pragma unroll
        for (int n = 0; n < 4; ++n)
            acc[m][n] = f32x4{0.f, 0.f, 0.f, 0.f};

    const int lrow = lane >> 3;
    const int lcol = (lane & 7) * 8;
    const int fr = lane & 15;
    const int fk = (lane >> 4) * 8;

    for (int k0 = 0; k0 < K; k0 += 64) {
#pragma unroll
        for (int i = 0; i < 4; ++i) {
            int seg = wid * 4 + i;
            const _Float16* g = A + (size_t)(brow + seg * 8 + lrow) * K + k0 + lcol;
            __builtin_amdgcn_global_load_lds(
                (const __attribute__((address_space(1))) void*)g,
                (__attribute__((address_space(3))) void*)&As[seg * 8][0], 16, 0, 0);
        }
#pragma unroll
        for (int i = 0; i < 4; ++i) {
            int seg = wid * 4 + i;
            const _Float16* g = Bt + (size_t)(bcol + seg * 8 + lrow) * K + k0 + lcol;
            __builtin_amdgcn_global_load_lds(
                (const __attribute__((address_space(1))) void*)g,
                (__attribute__((address_space(3))) void*)&Bs[seg * 8][0], 16, 0, 0);
        }
        __syncthreads();
#pragma unroll
        for (int kb = 0; kb < 2; ++kb) {
            f16x8 af[4], bf[4];
#pragma unroll
            for (int m = 0; m < 4; ++m)
                af[m] = *(const f16x8*)&As[wr + m * 16 + fr][kb * 32 + fk];
#pragma unroll
            for (int n = 0; n < 4; ++n)
                bf[n] = *(const f16x8*)&Bs[wc + n * 16 + fr][kb * 32 + fk];
#pragma unroll
            for (int m = 0; m < 4; ++m)
#pragma unroll
                for (int n = 0; n < 4; ++n)
                    acc[m][n] = __builtin_amdgcn_mfma_f32_16x16x32_f16(af[m], bf[n], acc[m][n], 0, 0, 0);
        }
        __syncthreads();
    }

    const int crow = (lane >> 4) * 4;
#pragma unroll
    for (int m = 0; m < 4; ++m) {
        int row0 = brow + wr + m * 16 + crow;
#pragma unroll
        for (int n = 0; n < 4; ++n) {
            int col = bcol + wc + n * 16 + fr;
            float bv = bias ? bias[col] : 0.f;
#pragma unroll
            for (int r = 0; r < 4; ++r) {
                float v = acc[m][n][r] + bv;
                if (DO_GELU) v = gelu_f(v);
                size_t idx = (size_t)(row0 + r) * N + col;
                if (OUT_F16) ((_Float16*)Cv)[idx] = (_Float16)v;
                else ((float*)Cv)[idx] = v;
            }
        }
    }
}

// ---------------- K9: vgen = gelu(alpha16 @ PT[b]^T + vpb), single launch, K=64 -------
// v1 rows 0..8191 -> v1a (old h1), rows 8192.. -> v1b (old xhi/xlo in d_out).
__global__ __launch_bounds__(256) void vgen_k(const _Float16* __restrict__ alpha16,
                                              const _Float16* __restrict__ PT,
                                              const float* __restrict__ vpb,
                                              _Float16* __restrict__ v1a,
                                              _Float16* __restrict__ v1b) {
    __shared__ __align__(16) _Float16 As[128][64];
    __shared__ __align__(16) _Float16 Bs[128][64];
    const int tid = threadIdx.x;
    const int wid = tid >> 6;
    const int lane = tid & 63;
    const int swz = xcd_swz(gridDim.x * gridDim.y);
    const int brow = (swz / gridDim.x) * 128;      // token rows
    const int bcol = (swz % gridDim.x) * 128;      // HM cols
    const int b = brow >> 12;                      // batch
    const _Float16* Bt = PT + (size_t)b * HMm * 64;
    _Float16* Cb = (brow < 8192) ? v1a : v1b;
    const int rowoff = (brow < 8192) ? brow : brow - 8192;
    const int wr = (wid >> 1) * 64;
    const int wc = (wid & 1) * 64;

    f32x4 acc[4][4];
#pragma unroll
    for (int m = 0; m < 4; ++m)
#pragma unroll
        for (int n = 0; n < 4; ++n)
            acc[m][n] = f32x4{0.f, 0.f, 0.f, 0.f};

    const int lrow = lane >> 3;
    const int lcol = (lane & 7) * 8;
    const int fr = lane & 15;
    const int fk = (lane >> 4) * 8;

#pragma unroll
    for (int i = 0; i < 4; ++i) {
        int seg = wid * 4 + i;
        const _Float16* g = alpha16 + (size_t)(brow + seg * 8 + lrow) * 64 + lcol;
        __builtin_amdgcn_global_load_lds(
            (const __attribute__((address_space(1))) void*)g,
            (__attribute__((address_space(3))) void*)&As[seg * 8][0], 16, 0, 0);
    }
#pragma unroll
    for (int i = 0; i < 4; ++i) {
        int seg = wid * 4 + i;
        const _Float16* g = Bt + (size_t)(bcol + seg * 8 + lrow) * 64 + lcol;
        __builtin_amdgcn_global_load_lds(
            (const __attribute__((address_space(1))) void*)g,
            (__attribute__((address_space(3))) void*)&Bs[seg * 8][0], 16, 0, 0);
    }
    __syncthreads();
#pragma unroll
    for (int kb = 0; kb < 2; ++kb) {
        f16x8 af[4], bf[4];
#pragma unroll
        for (int m = 0; m < 4; ++m)
            af[m] = *(const f16x8*)&As[wr + m * 16 + fr][kb * 32 + fk];
#pragma unroll
        for (int n = 0; n < 4; ++n)
            bf[n] = *(const f16x8*)&Bs[wc + n * 16 + fr][kb * 32 + fk];
#pragma unroll
        for (int m = 0; m < 4; ++m)
#pragma unroll
            for (int n = 0; n < 4; ++n)
                acc[m][n] = __builtin_amdgcn_mfma_f32_16x16x32_f16(af[m], bf[n], acc[m][n], 0, 0, 0);
    }

    const int crow = (lane >> 4) * 4;
#pragma unroll
    for (int m = 0; m < 4; ++m) {
        int row0 = rowoff + wr + m * 16 + crow;
#pragma unroll
        for (int n = 0; n < 4; ++n) {
            int col = bcol + wc + n * 16 + fr;
            float bv = vpb[col];
#pragma unroll
            for (int r = 0; r < 4; ++r) {
                float v = acc[m][n][r] + bv;
                Cb[(size_t)(row0 + r) * HMm + col] = (_Float16)gelu_f(v);
            }
        }
    }
}

// ---------------- K10: GEMM2 single launch, dual A pointer --------------------------
__global__ __launch_bounds__(256) void hgemm2_k(const _Float16* __restrict__ v1a,
                                                const _Float16* __restrict__ v1b,
                                                const _Float16* __restrict__ Bt,
                                                const float* __restrict__ bias,
                                                _Float16* __restrict__ C,
                                                int N, int K) {
    __shared__ __align__(16) _Float16 As[128][64];
    __shared__ __align__(16) _Float16 Bs[128][64];
    const int tid = threadIdx.x;
    const int wid = tid >> 6;
    const int lane = tid & 63;
    const int swz = xcd_swz(gridDim.x * gridDim.y);
    const int brow = (swz / gridDim.x) * 128;
    const int bcol = (swz % gridDim.x) * 128;
    const _Float16* Ab = (brow < 8192) ? v1a : v1b;
    const int arow0 = (brow < 8192) ? brow : brow - 8192;
    const int wr = (wid >> 1) * 64;
    const int wc = (wid & 1) * 64;

    f32x4 acc[4][4];
#pragma unroll
    for (int m = 0; m < 4; ++m)
#pragma unroll
        for (int n = 0; n < 4; ++n)
            acc[m][n] = f32x4{0.f, 0.f, 0.f, 0.f};

    const int lrow = lane >> 3;
    const int lcol = (lane & 7) * 8;
    const int fr = lane & 15;
    const int fk = (lane >> 4) * 8;

    for (int k0 = 0; k0 < K; k0 += 64) {
#pragma unroll
        for (int i = 0; i < 4; ++i) {
            int seg = wid * 4 + i;
            const _Float16* g = Ab + (size_t)(arow0 + seg * 8 + lrow) * K + k0 + lcol;
            __builtin_amdgcn_global_load_lds(
                (const __attribute__((address_space(1))) void*)g,
                (__attribute__((address_space(3))) void*)&As[seg * 8][0], 16, 0, 0);
        }
#pragma unroll
        for (int i = 0; i < 4; ++i) {
            int seg = wid * 4 + i;
            const _Float16* g = Bt + (size_t)(bcol + seg * 8 + lrow) * K + k0 + lcol;
            __builtin_amdgcn_global_load_lds(
                (const __attribute__((address_space(1))) void*)g,
                (__attribute__((address_space(3))) void*)&Bs[seg * 8][0], 16, 0, 0);
        }
        __syncthreads();
#pragma unroll
        for (int kb = 0; kb < 2; ++kb) {
            f16x8 af[4], bf[4];
#pragma unroll
            for (int m = 0; m < 4; ++m)
                af[m] = *(const f16x8*)&As[wr + m * 16 + fr][kb * 32 + fk];
#pragma unroll
            for (int n = 0; n < 4; ++n)
                bf[n] = *(const f16x8*)&Bs[wc + n * 16 + fr][kb * 32 + fk];
#pragma unroll
            for (int m = 0; m < 4; ++m)
#pragma unroll
                for (int n = 0; n < 4; ++n)
                    acc[m][n] = __builtin_amdgcn_mfma_f32_16x16x32_f16(af[m], bf[n], acc[m][n], 0, 0, 0);
        }
        __syncthreads();
    }

    const int crow = (lane >> 4) * 4;
#pragma unroll
    for (int m = 0; m < 4; ++m) {
        int row0 = brow + wr + m * 16 + crow;
#pragma unroll
        for (int n = 0; n < 4; ++n) {
            int col = bcol + wc + n * 16 + fr;
            float bv = bias[col];
#pragma unroll
            for (int r = 0; r < 4; ++r)
                C[(size_t)(row0 + r) * N + col] = (_Float16)(acc[m][n][r] + bv);
        }
    }
}

extern "C" void kernel_launch(void* const* d_in, const int* in_sizes, int n_in,
                              void* d_out, int out_size, void* d_ws, size_t ws_size,
                              hipStream_t stream) {
    const float* x         = (const float*)d_in[0];
    const float* slot_init = (const float*)d_in[1];
    const float* rw1       = (const float*)d_in[2];
    const float* rb1       = (const float*)d_in[3];
    const float* rw2       = (const float*)d_in[4];
    const float* rb2       = (const float*)d_in[5];
    const float* gwi       = (const float*)d_in[6];
    const float* gwh       = (const float*)d_in[7];
    const float* gbi       = (const float*)d_in[8];
    const float* gbh       = (const float*)d_in[9];
    const float* hpw       = (const float*)d_in[10];
    const float* hpb       = (const float*)d_in[11];
    const float* ohw       = (const float*)d_in[12];
    const float* ohb       = (const float*)d_in[13];
    const float* vpw       = (const float*)d_in[14];
    const float* vpb       = (const float*)d_in[15];
    const float* vow       = (const float*)d_in[16];
    const float* vob       = (const float*)d_in[17];
    const float* opw       = (const float*)d_in[18];
    const float* opb       = (const float*)d_in[19];
    const float* tau       = (const float*)d_in[20];
    float* out = (float*)d_out;

    float* ws = (float*)d_ws;
    size_t off = 0;
    auto alloc = [&](size_t nfloats) { float* p = ws + off; off += (nfloats + 63) & ~(size_t)63; return p; };

    float* cb     = alloc(1024);
    float* cbp    = alloc(16 * 1024);
    float* h1     = alloc((size_t)MTOK * 1024);            // fp32; dead after logits:
    _Float16* v1a = (_Float16*)h1;                          //   v1 rows 0..8191 [8192,4096] f16
    float* logits = alloc((size_t)MTOK * 64);
    float* alpha  = alloc((size_t)MTOK * 64);
    _Float16* alpha16 = (_Float16*)alloc((size_t)MTOK * 64 / 2);
    float* slotin = alloc(256 * 64);
    float* part   = alloc((size_t)8 * 64 * 4 * 64);
    float* partw  = alloc(8 * 64 * 4);
    float* Snew   = alloc(256 * 64);
    _Float16* PT   = (_Float16*)alloc((size_t)Bb * HMm * 64 / 2);  // [4,4096,64] f16
    _Float16* vowT = (_Float16*)alloc((size_t)Dd * HMm / 2);       // [1024,4096] f16
    _Float16* opwT = (_Float16*)alloc((size_t)Dd * Dd / 2);        // [1024,1024] f16
    _Float16* v2f16 = (_Float16*)alloc((size_t)MTOK * Dd / 2);     // [16384,1024] f16
    _Float16* w1hiT = (_Float16*)alloc((size_t)Dd * Dd / 2);
    _Float16* w1loT = (_Float16*)alloc((size_t)Dd * Dd / 2);

    // d_out scratch: xhi/xlo before hgemm4; v1 rows 8192..16383 after vgen.
    _Float16* xhi = (_Float16*)d_out;
    _Float16* xlo = xhi + (size_t)MTOK * Dd;
    _Float16* v1b = (_Float16*)d_out;

    // ---- routing: pre-split x + 4-plane split-fp16 MFMA GEMM + fp32 logits ----
    cb_part_k<<<dim3(4, 16), 256, 0, stream>>>(slot_init, rw1, cbp);
    cb_comb_k<<<4, 256, 0, stream>>>(cbp, cb);
    wsplitT_k<<<dim3(Dd / 32, Dd / 32), 256, 0, stream>>>(rw1, w1hiT, w1loT);
    xsplit_k<<<(MTOK * Dd) / (256 * 8), 256, 0, stream>>>(x, xhi, xlo);
    hgemm4_k<<<dim3(Dd / 128, MTOK / 128), 256, 0, stream>>>(
        xhi, xlo, w1hiT, w1loT, rb1, cb, h1, MTOK, Dd, Dd);
    logits2_k<<<MTOK / 64, 256, 0, stream>>>(h1, rw2, rb2, tau, logits);
    topk_k<<<MTOK / 4, 256, 0, stream>>>(logits, alpha, alpha16);

    // ---- weight transposes (fp32 -> fp16 [N,K]) ----
    transp_f16_k<<<dim3(Dd / 32, HMm / 32), 256, 0, stream>>>(vow, vowT, HMm, Dd);
    transp_f16_k<<<dim3(Dd / 32, Dd / 32), 256, 0, stream>>>(opw, opwT, Dd, Dd);

    // ---- slot pooling + GRU + slot MLP ----
    pool_part_k<<<dim3(64, 8), 256, 0, stream>>>(x, alpha, part, partw);
    pool_comb_k<<<64, 256, 0, stream>>>(part, partw, slotin);
    gru_k<<<256, 64, 0, stream>>>(slotin, slot_init, gwi, gwh, gbi, gbh,
                                  hpw, hpb, ohw, ohb, Snew);

    // ---- P[b] = S_emb[b] @ vpw (stored transposed f16 [b][j][hs]) ----
    pmat_k<<<dim3(HMm / 256, Hh), 256, 0, stream>>>(Snew, vpw, PT);

    // ---- value MLP: vgen (K=64), GEMM2, GEMM3 — each a single launch ----
    vgen_k<<<dim3(HMm / 128, MTOK / 128), 256, 0, stream>>>(
        alpha16, PT, vpb, v1a, v1b);
    hgemm2_k<<<dim3(Dd / 128, MTOK / 128), 256, 0, stream>>>(
        v1a, v1b, vowT, vob, v2f16, Dd, HMm);
    hgemm_k<0, 0><<<dim3(Dd / 128, MTOK / 128), 256, 0, stream>>>(
        v2f16, opwT, opb, out, MTOK, Dd, Dd);

    (void)in_sizes; (void)n_in; (void)out_size; (void)ws_size;
}

// Round 8
// 578.613 us; speedup vs baseline: 1.4717x; 1.0728x over previous
//
#include <hip/hip_runtime.h>
#include <cstddef>
#include <cstdint>

// Problem constants
#define Bb 4
#define Tt 4096
#define Dd 1024
#define Hh 16
#define HDd 64
#define NSs 64
#define SPHh 4
#define HMm 4096
#define MTOK (Bb*Tt)   // 16384

typedef _Float16 f16x8 __attribute__((ext_vector_type(8)));
typedef _Float16 f16x4 __attribute__((ext_vector_type(4)));
typedef float f32x4 __attribute__((ext_vector_type(4)));

__device__ __forceinline__ float gelu_f(float x) {
    return 0.5f * x * (1.0f + erff(x * 0.70710678118654752440f));
}

// XCD-chunked bijective block swizzle (requires nwg % 8 == 0; all launches comply)
__device__ __forceinline__ int xcd_swz(int nwg) {
    int orig = blockIdx.y * gridDim.x + blockIdx.x;
    int cpx = nwg >> 3;
    return (orig & 7) * cpx + (orig >> 3);
}

// ---------------- K0: cb partials ----------------
__global__ __launch_bounds__(256) void cb_part_k(const float* __restrict__ slot_init,
                                                 const float* __restrict__ rw1,
                                                 float* __restrict__ cbp) {
    __shared__ float sm[64];
    int tid = threadIdx.x;
    if (tid < 64) {
        float s = 0.f;
        for (int i = 0; i < 64; ++i) s += slot_init[i * 64 + tid];
        sm[tid] = s * (1.0f / 64.0f);
    }
    __syncthreads();
    int j = blockIdx.x * 256 + tid;
    int k0 = blockIdx.y * 64;
    float acc = 0.f;
#pragma unroll 8
    for (int k = 0; k < 64; ++k)
        acc = fmaf(sm[k], rw1[(size_t)(1024 + k0 + k) * 1024 + j], acc);
    cbp[(size_t)blockIdx.y * 1024 + j] = acc;
}

__global__ __launch_bounds__(256) void cb_comb_k(const float* __restrict__ cbp,
                                                 float* __restrict__ cb) {
    int j = blockIdx.x * 256 + threadIdx.x;
    float acc = 0.f;
#pragma unroll
    for (int c = 0; c < 16; ++c) acc += cbp[(size_t)c * 1024 + j];
    cb[j] = acc;
}

// ---------------- K1: rw1[:1024] -> transposed split-f16 planes ----------------
__global__ __launch_bounds__(256) void wsplitT_k(const float* __restrict__ rw1,
                                                 _Float16* __restrict__ whiT,
                                                 _Float16* __restrict__ wloT) {
    __shared__ float t[32][33];
    int n0 = blockIdx.x * 32, k0 = blockIdx.y * 32;
    int tx = threadIdx.x & 31, ty = threadIdx.x >> 5;
#pragma unroll
    for (int i = 0; i < 32; i += 8)
        t[ty + i][tx] = rw1[(size_t)(k0 + ty + i) * 1024 + n0 + tx];
    __syncthreads();
#pragma unroll
    for (int i = 0; i < 32; i += 8) {
        float v = t[tx][ty + i];
        _Float16 h = (_Float16)v;
        _Float16 l = (_Float16)(v - (float)h);
        whiT[(size_t)(n0 + ty + i) * 1024 + k0 + tx] = h;
        wloT[(size_t)(n0 + ty + i) * 1024 + k0 + tx] = l;
    }
}

// ---------------- K1a: x -> split f16 hi/lo planes ----------------
__global__ __launch_bounds__(256) void xsplit_k(const float* __restrict__ x,
                                                _Float16* __restrict__ xhi,
                                                _Float16* __restrict__ xlo) {
    size_t i = ((size_t)blockIdx.x * 256 + threadIdx.x) * 8;
    float4 a = *(const float4*)(x + i);
    float4 b = *(const float4*)(x + i + 4);
    float v[8] = {a.x, a.y, a.z, a.w, b.x, b.y, b.z, b.w};
    f16x8 h, l;
#pragma unroll
    for (int j = 0; j < 8; ++j) {
        _Float16 hv = (_Float16)v[j];
        h[j] = hv;
        l[j] = (_Float16)(v[j] - (float)hv);
    }
    *(f16x8*)(xhi + i) = h;
    *(f16x8*)(xlo + i) = l;
}

// ---------------- K1b: split-fp16 MFMA routing GEMM (pre-split 4-plane) ---------------
__global__ __launch_bounds__(256) void hgemm4_k(const _Float16* __restrict__ Ah,
                                                const _Float16* __restrict__ Al,
                                                const _Float16* __restrict__ Bh,
                                                const _Float16* __restrict__ Bl,
                                                const float* __restrict__ bias1,
                                                const float* __restrict__ bias2,
                                                float* __restrict__ C,
                                                int M, int N, int K) {
    __shared__ __align__(16) _Float16 Ahs[128][32];
    __shared__ __align__(16) _Float16 Als[128][32];
    __shared__ __align__(16) _Float16 Bhs[128][32];
    __shared__ __align__(16) _Float16 Bls[128][32];
    const int tid = threadIdx.x;
    const int wid = tid >> 6;
    const int lane = tid & 63;
    const int swz = xcd_swz(gridDim.x * gridDim.y);
    const int brow = (swz / gridDim.x) * 128;
    const int bcol = (swz % gridDim.x) * 128;
    const int wr = (wid >> 1) * 64;
    const int wc = (wid & 1) * 64;

    const int rb = lane >> 2;
    const int cbk = (lane & 3) * 8;
    const int fr = lane & 15;
    const int fk = (lane >> 4) * 8;

    f32x4 acc[4][4];
#pragma unroll
    for (int m = 0; m < 4; ++m)
#pragma unroll
        for (int n = 0; n < 4; ++n)
            acc[m][n] = f32x4{0.f, 0.f, 0.f, 0.f};

    for (int k0 = 0; k0 < K; k0 += 32) {
#pragma unroll
        for (int i = 0; i < 2; ++i) {
            int r0 = wid * 32 + i * 16;
            const _Float16* gah = Ah + (size_t)(brow + r0 + rb) * K + k0 + cbk;
            __builtin_amdgcn_global_load_lds(
                (const __attribute__((address_space(1))) void*)gah,
                (__attribute__((address_space(3))) void*)&Ahs[r0][0], 16, 0, 0);
            const _Float16* gal = Al + (size_t)(brow + r0 + rb) * K + k0 + cbk;
            __builtin_amdgcn_global_load_lds(
                (const __attribute__((address_space(1))) void*)gal,
                (__attribute__((address_space(3))) void*)&Als[r0][0], 16, 0, 0);
            const _Float16* gbh = Bh + (size_t)(bcol + r0 + rb) * K + k0 + cbk;
            __builtin_amdgcn_global_load_lds(
                (const __attribute__((address_space(1))) void*)gbh,
                (__attribute__((address_space(3))) void*)&Bhs[r0][0], 16, 0, 0);
            const _Float16* gbl = Bl + (size_t)(bcol + r0 + rb) * K + k0 + cbk;
            __builtin_amdgcn_global_load_lds(
                (const __attribute__((address_space(1))) void*)gbl,
                (__attribute__((address_space(3))) void*)&Bls[r0][0], 16, 0, 0);
        }
        __syncthreads();

        f16x8 afh[4], afl[4], bfh[4], bfl[4];
#pragma unroll
        for (int m = 0; m < 4; ++m) {
            afh[m] = *(const f16x8*)&Ahs[wr + m * 16 + fr][fk];
            afl[m] = *(const f16x8*)&Als[wr + m * 16 + fr][fk];
        }
#pragma unroll
        for (int n = 0; n < 4; ++n) {
            bfh[n] = *(const f16x8*)&Bhs[wc + n * 16 + fr][fk];
            bfl[n] = *(const f16x8*)&Bls[wc + n * 16 + fr][fk];
        }
#pragma unroll
        for (int m = 0; m < 4; ++m)
#pragma unroll
            for (int n = 0; n < 4; ++n) {
                acc[m][n] = __builtin_amdgcn_mfma_f32_16x16x32_f16(afl[m], bfh[n], acc[m][n], 0, 0, 0);
                acc[m][n] = __builtin_amdgcn_mfma_f32_16x16x32_f16(afh[m], bfl[n], acc[m][n], 0, 0, 0);
                acc[m][n] = __builtin_amdgcn_mfma_f32_16x16x32_f16(afh[m], bfh[n], acc[m][n], 0, 0, 0);
            }
        __syncthreads();
    }

    const int crow = (lane >> 4) * 4;
#pragma unroll
    for (int m = 0; m < 4; ++m) {
        int row0 = brow + wr + m * 16 + crow;
#pragma unroll
        for (int n = 0; n < 4; ++n) {
            int col = bcol + wc + n * 16 + fr;
            float bv = bias1[col] + bias2[col];
#pragma unroll
            for (int r = 0; r < 4; ++r) {
                float v = acc[m][n][r] + bv;
                C[(size_t)(row0 + r) * N + col] = gelu_f(v);
            }
        }
    }
}

// ---------------- K2: route logits (fp32, register-blocked; bit-identical k-order) ----
__global__ __launch_bounds__(256) void logits2_k(const float* __restrict__ A,
                                                 const float* __restrict__ Bw,
                                                 const float* __restrict__ rb2,
                                                 const float* __restrict__ taup,
                                                 float* __restrict__ Cl) {
    __shared__ float At[16][68];
    __shared__ float Bs[16][64];
    const int tid = threadIdx.x;
    const int m0 = blockIdx.x * 64;
    const int rg = tid >> 4;
    const int cg = tid & 15;
    const int srow = tid >> 2;
    const int skk  = (tid & 3) * 4;
    const int bk = tid >> 4;
    const int bc = (tid & 15) * 4;

    float acc[4][4] = {};

    for (int k0 = 0; k0 < 1024; k0 += 16) {
        float4 av = *(const float4*)(A + (size_t)(m0 + srow) * 1024 + k0 + skk);
        float4 bv = *(const float4*)(Bw + (size_t)(k0 + bk) * 64 + bc);
        __syncthreads();
        At[skk + 0][srow] = av.x;
        At[skk + 1][srow] = av.y;
        At[skk + 2][srow] = av.z;
        At[skk + 3][srow] = av.w;
        *(float4*)&Bs[bk][bc] = bv;
        __syncthreads();
#pragma unroll
        for (int k = 0; k < 16; ++k) {
            float4 a4 = *(const float4*)&At[k][rg * 4];
            float4 b4 = *(const float4*)&Bs[k][cg * 4];
            float a[4] = {a4.x, a4.y, a4.z, a4.w};
            float b[4] = {b4.x, b4.y, b4.z, b4.w};
#pragma unroll
            for (int i = 0; i < 4; ++i)
#pragma unroll
                for (int j = 0; j < 4; ++j)
                    acc[i][j] = fmaf(a[i], b[j], acc[i][j]);
        }
    }
    float inv = 1.0f / (fabsf(taup[0]) + 0.1f);
#pragma unroll
    for (int i = 0; i < 4; ++i)
#pragma unroll
        for (int j = 0; j < 4; ++j)
            Cl[(size_t)(m0 + rg * 4 + i) * 64 + cg * 4 + j] =
                (acc[i][j] + rb2[cg * 4 + j]) * inv;
}

// ---------------- K3: top-32-of-64 + softmax -> dense alpha ----------------
__global__ __launch_bounds__(256) void topk_k(const float* __restrict__ logits,
                                              float* __restrict__ alpha,
                                              _Float16* __restrict__ alpha16) {
    int wave = threadIdx.x >> 6;
    int lane = threadIdx.x & 63;
    int t = blockIdx.x * 4 + wave;
    float li = logits[(size_t)t * 64 + lane];
    float m = li;
#pragma unroll
    for (int off = 32; off; off >>= 1) m = fmaxf(m, __shfl_xor(m, off, 64));
    int cnt = 0;
    for (int off = 1; off < 64; ++off) {
        int j = (lane + off) & 63;
        float lj = __shfl(li, j, 64);
        cnt += (lj > li) || (lj == li && j < lane);
    }
    float e = (cnt < 32) ? expf(li - m) : 0.0f;
    float s = e;
#pragma unroll
    for (int off = 32; off; off >>= 1) s += __shfl_xor(s, off, 64);
    float a = e / s;
    alpha[(size_t)t * 64 + lane] = a;
    alpha16[(size_t)t * 64 + lane] = (_Float16)a;
}

// ---------------- K4: slot pooling ----------------
__global__ __launch_bounds__(256) void pool_part_k(const float* __restrict__ x,
                                                   const float* __restrict__ alpha,
                                                   float* __restrict__ part,
                                                   float* __restrict__ partw) {
    int bh = blockIdx.x;
    int c = blockIdx.y;
    int b = bh >> 4, h = bh & 15;
    int tid = threadIdx.x;
    int s = tid >> 6, d = tid & 63;
    __shared__ float lx[16][64];
    __shared__ float la[16][4];
    float acc = 0.f, wacc = 0.f;
    const int tchunk = Tt / 8;
    const int t0base = c * tchunk;
    for (int t0 = 0; t0 < tchunk; t0 += 16) {
        int ttr = tid >> 4;
        int ddr = (tid & 15) * 4;
        size_t trow = (size_t)b * Tt + t0base + t0 + ttr;
        float4 xv = *(const float4*)(x + trow * Dd + h * 64 + ddr);
        *(float4*)&lx[ttr][ddr] = xv;
        if (tid < 64) {
            int tt2 = tid >> 2, ss = tid & 3;
            la[tt2][ss] = alpha[((size_t)b * Tt + t0base + t0 + tt2) * 64 + h * 4 + ss];
        }
        __syncthreads();
#pragma unroll
        for (int q = 0; q < 16; ++q) {
            float av = la[q][s];
            acc = fmaf(av, lx[q][d], acc);
            wacc += av;
        }
        __syncthreads();
    }
    part[(((size_t)c * 64 + bh) * 4 + s) * 64 + d] = acc;
    if (d == 0) partw[((size_t)c * 64 + bh) * 4 + s] = wacc;
}

__global__ __launch_bounds__(256) void pool_comb_k(const float* __restrict__ part,
                                                   const float* __restrict__ partw,
                                                   float* __restrict__ slot_in) {
    int bh = blockIdx.x;
    int tid = threadIdx.x;
    int s = tid >> 6, d = tid & 63;
    float acc = 0.f, w = 0.f;
    for (int c = 0; c < 8; ++c) {
        acc += part[(((size_t)c * 64 + bh) * 4 + s) * 64 + d];
        w   += partw[((size_t)c * 64 + bh) * 4 + s];
    }
    slot_in[((size_t)bh * 4 + s) * 64 + d] = acc / (w + 1e-8f);
}

// ---------------- K5: GRU + slot MLP ----------------
__global__ __launch_bounds__(64) void gru_k(const float* __restrict__ slot_in,
                                            const float* __restrict__ slot_init,
                                            const float* __restrict__ gwi,
                                            const float* __restrict__ gwh,
                                            const float* __restrict__ gbi,
                                            const float* __restrict__ gbh,
                                            const float* __restrict__ hpw,
                                            const float* __restrict__ hpb,
                                            const float* __restrict__ ohw,
                                            const float* __restrict__ ohb,
                                            float* __restrict__ S_new) {
    int slot = blockIdx.x;
    int hs = slot & 63;
    int d = threadIdx.x;
    __shared__ float si[64], hp[64], hn[64], g[256];
    si[d] = slot_in[(size_t)slot * 64 + d];
    hp[d] = slot_init[(size_t)hs * 64 + d];
    __syncthreads();
    float gi_r = gbi[d], gi_z = gbi[64 + d], gi_n = gbi[128 + d];
    float gh_r = gbh[d], gh_z = gbh[64 + d], gh_n = gbh[128 + d];
    for (int k = 0; k < 64; ++k) {
        float sv = si[k], hv = hp[k];
        gi_r = fmaf(sv, gwi[(size_t)(d) * 64 + k], gi_r);
        gi_z = fmaf(sv, gwi[(size_t)(64 + d) * 64 + k], gi_z);
        gi_n = fmaf(sv, gwi[(size_t)(128 + d) * 64 + k], gi_n);
        gh_r = fmaf(hv, gwh[(size_t)(d) * 64 + k], gh_r);
        gh_z = fmaf(hv, gwh[(size_t)(64 + d) * 64 + k], gh_z);
        gh_n = fmaf(hv, gwh[(size_t)(128 + d) * 64 + k], gh_n);
    }
    float r = 1.0f / (1.0f + expf(-(gi_r + gh_r)));
    float z = 1.0f / (1.0f + expf(-(gi_z + gh_z)));
    float n = tanhf(gi_n + r * gh_n);
    float hnew = (1.0f - z) * n + z * hp[d];
    hn[d] = hnew;
    __syncthreads();
    float p0 = hpb[d], p1 = hpb[64 + d], p2 = hpb[128 + d], p3 = hpb[192 + d];
    for (int k = 0; k < 64; ++k) {
        float hv = hn[k];
        p0 = fmaf(hv, hpw[(size_t)k * 256 + d], p0);
        p1 = fmaf(hv, hpw[(size_t)k * 256 + 64 + d], p1);
        p2 = fmaf(hv, hpw[(size_t)k * 256 + 128 + d], p2);
        p3 = fmaf(hv, hpw[(size_t)k * 256 + 192 + d], p3);
    }
    g[d] = gelu_f(p0); g[64 + d] = gelu_f(p1); g[128 + d] = gelu_f(p2); g[192 + d] = gelu_f(p3);
    __syncthreads();
    float o = ohb[d];
    for (int j = 0; j < 256; ++j) o = fmaf(g[j], ohw[(size_t)j * 64 + d], o);
    S_new[(size_t)slot * 64 + d] = o;
}

// ---------------- K6: PT[b][j][hs] = sum_d Snew[b,hs,d] * vpw[h*64+d, j]  (f16) -------
__global__ __launch_bounds__(256) void pmat_k(const float* __restrict__ Snew,
                                              const float* __restrict__ vpw,
                                              _Float16* __restrict__ PT) {
    const int h = blockIdx.y;
    const int tid = threadIdx.x;
    const int j = blockIdx.x * 256 + tid;
    __shared__ float S[16][64];
    for (int i = tid; i < 1024; i += 256) {
        int row = i >> 6, d = i & 63;
        int b = row >> 2, s = row & 3;
        S[row][d] = Snew[((size_t)b * 64 + h * 4 + s) * 64 + d];
    }
    __syncthreads();
    float acc[16];
#pragma unroll
    for (int r = 0; r < 16; ++r) acc[r] = 0.f;
    const float* wp = vpw + (size_t)h * 64 * HMm + j;
#pragma unroll 4
    for (int d = 0; d < 64; ++d) {
        float w = wp[(size_t)d * HMm];
#pragma unroll
        for (int r = 0; r < 16; ++r) acc[r] = fmaf(S[r][d], w, acc[r]);
    }
#pragma unroll
    for (int b = 0; b < 4; ++b) {
        f16x4 o;
#pragma unroll
        for (int s = 0; s < 4; ++s) o[s] = (_Float16)acc[b * 4 + s];
        *(f16x4*)&PT[((size_t)b * HMm + j) * 64 + h * 4] = o;
    }
}

// ---------------- K7: transpose + fp32->fp16 convert ----------------
__global__ __launch_bounds__(256) void transp_f16_k(const float* __restrict__ in,
                                                    _Float16* __restrict__ out,
                                                    int K, int N) {
    __shared__ float t[32][33];
    int n0 = blockIdx.x * 32, k0 = blockIdx.y * 32;
    int tx = threadIdx.x & 31, ty = threadIdx.x >> 5;
#pragma unroll
    for (int i = 0; i < 32; i += 8)
        t[ty + i][tx] = in[(size_t)(k0 + ty + i) * N + n0 + tx];
    __syncthreads();
#pragma unroll
    for (int i = 0; i < 32; i += 8)
        out[(size_t)(n0 + ty + i) * K + k0 + tx] = (_Float16)t[tx][ty + i];
}

// ---------------- K9: vgen = gelu(alpha16 @ PT[b]^T + vpb), single launch, K=64 -------
__global__ __launch_bounds__(256) void vgen_k(const _Float16* __restrict__ alpha16,
                                              const _Float16* __restrict__ PT,
                                              const float* __restrict__ vpb,
                                              _Float16* __restrict__ v1a,
                                              _Float16* __restrict__ v1b) {
    __shared__ __align__(16) _Float16 As[128][64];
    __shared__ __align__(16) _Float16 Bs[128][64];
    const int tid = threadIdx.x;
    const int wid = tid >> 6;
    const int lane = tid & 63;
    const int swz = xcd_swz(gridDim.x * gridDim.y);
    const int brow = (swz / gridDim.x) * 128;
    const int bcol = (swz % gridDim.x) * 128;
    const int b = brow >> 12;
    const _Float16* Bt = PT + (size_t)b * HMm * 64;
    _Float16* Cb = (brow < 8192) ? v1a : v1b;
    const int rowoff = (brow < 8192) ? brow : brow - 8192;
    const int wr = (wid >> 1) * 64;
    const int wc = (wid & 1) * 64;

    f32x4 acc[4][4];
#pragma unroll
    for (int m = 0; m < 4; ++m)
#pragma unroll
        for (int n = 0; n < 4; ++n)
            acc[m][n] = f32x4{0.f, 0.f, 0.f, 0.f};

    const int lrow = lane >> 3;
    const int lcol = (lane & 7) * 8;
    const int fr = lane & 15;
    const int fk = (lane >> 4) * 8;

#pragma unroll
    for (int i = 0; i < 4; ++i) {
        int seg = wid * 4 + i;
        const _Float16* g = alpha16 + (size_t)(brow + seg * 8 + lrow) * 64 + lcol;
        __builtin_amdgcn_global_load_lds(
            (const __attribute__((address_space(1))) void*)g,
            (__attribute__((address_space(3))) void*)&As[seg * 8][0], 16, 0, 0);
    }
#pragma unroll
    for (int i = 0; i < 4; ++i) {
        int seg = wid * 4 + i;
        const _Float16* g = Bt + (size_t)(bcol + seg * 8 + lrow) * 64 + lcol;
        __builtin_amdgcn_global_load_lds(
            (const __attribute__((address_space(1))) void*)g,
            (__attribute__((address_space(3))) void*)&Bs[seg * 8][0], 16, 0, 0);
    }
    __syncthreads();
#pragma unroll
    for (int kb = 0; kb < 2; ++kb) {
        f16x8 af[4], bf[4];
#pragma unroll
        for (int m = 0; m < 4; ++m)
            af[m] = *(const f16x8*)&As[wr + m * 16 + fr][kb * 32 + fk];
#pragma unroll
        for (int n = 0; n < 4; ++n)
            bf[n] = *(const f16x8*)&Bs[wc + n * 16 + fr][kb * 32 + fk];
#pragma unroll
        for (int m = 0; m < 4; ++m)
#pragma unroll
            for (int n = 0; n < 4; ++n)
                acc[m][n] = __builtin_amdgcn_mfma_f32_16x16x32_f16(af[m], bf[n], acc[m][n], 0, 0, 0);
    }

    const int crow = (lane >> 4) * 4;
#pragma unroll
    for (int m = 0; m < 4; ++m) {
        int row0 = rowoff + wr + m * 16 + crow;
#pragma unroll
        for (int n = 0; n < 4; ++n) {
            int col = bcol + wc + n * 16 + fr;
            float bv = vpb[col];
#pragma unroll
            for (int r = 0; r < 4; ++r) {
                float v = acc[m][n][r] + bv;
                Cb[(size_t)(row0 + r) * HMm + col] = (_Float16)gelu_f(v);
            }
        }
    }
}

// ---------------- K11: 256x256 deep-pipelined GEMM (T3+T4: counted vmcnt, 4-deep ring,
//                  T2 via pre-swizzled per-lane global source, T5 setprio) -------------
// C[M,N] = A[M,K] @ Bt[N,K]^T + bias. A dual-pointer split at splitrow. BK=32, 512 thr.
template <int OUT_F16>
__global__ __launch_bounds__(512, 2) void hgemm8_k(const _Float16* __restrict__ A0,
                                                   const _Float16* __restrict__ A1,
                                                   int splitrow,
                                                   const _Float16* __restrict__ Bt,
                                                   const float* __restrict__ bias,
                                                   void* __restrict__ Cv,
                                                   int M, int N, int K) {
    __shared__ __align__(16) _Float16 As[4][256][32];   // 64 KB
    __shared__ __align__(16) _Float16 Bs[4][256][32];   // 64 KB
    const int tid = threadIdx.x;
    const int wid = tid >> 6;            // 0..7
    const int lane = tid & 63;
    const int swz = xcd_swz(gridDim.x * gridDim.y);
    const int brow = (swz / gridDim.x) * 256;
    const int bcol = (swz % gridDim.x) * 256;
    const _Float16* Ab = (brow < splitrow) ? A0 : A1;
    const int arow0 = brow - ((brow < splitrow) ? 0 : splitrow);
    const int wm = wid >> 2;             // 0..1 -> 128-row half
    const int wn = wid & 3;              // 0..3 -> 64-col quarter

    // staging lane map: 16 rows x 64B per issue; source col-block pre-swizzled (m173)
    const int srow = lane >> 2;
    const int scol = ((lane & 3) ^ ((lane >> 3) & 3)) * 8;
    // fragment read: row = base + fr; phys 16B-block = log ^ ((row>>1)&3) = fixed/lane
    const int fr = lane & 15;
    const int fkp = (((lane >> 4) ^ ((lane >> 1) & 3))) * 8;
    const int crow = (lane >> 4) * 4;

    const int nk = K >> 5;

    f32x4 acc[8][4];
#pragma unroll
    for (int m = 0; m < 8; ++m)
#pragma unroll
        for (int n = 0; n < 4; ++n)
            acc[m][n] = f32x4{0.f, 0.f, 0.f, 0.f};

    auto stage = [&](int t) {
        const int slot = t & 3;
        const size_t kk = (size_t)t << 5;
#pragma unroll
        for (int i = 0; i < 2; ++i) {
            const _Float16* g = Ab + (size_t)(arow0 + wid * 32 + i * 16 + srow) * K + kk + scol;
            __builtin_amdgcn_global_load_lds(
                (const __attribute__((address_space(1))) void*)g,
                (__attribute__((address_space(3))) void*)&As[slot][wid * 32 + i * 16][0], 16, 0, 0);
        }
#pragma unroll
        for (int i = 0; i < 2; ++i) {
            const _Float16* g = Bt + (size_t)(bcol + wid * 32 + i * 16 + srow) * K + kk + scol;
            __builtin_amdgcn_global_load_lds(
                (const __attribute__((address_space(1))) void*)g,
                (__attribute__((address_space(3))) void*)&Bs[slot][wid * 32 + i * 16][0], 16, 0, 0);
        }
    };

    // prologue: 3 tiles in flight
    stage(0);
    if (nk > 1) stage(1);
    if (nk > 2) stage(2);

    for (int t = 0; t < nk; ++t) {
        // counted wait: tiles t+1, t+2 may stay in flight (T4 - never drain to 0 mid-loop)
        if (t + 2 < nk)      asm volatile("s_waitcnt vmcnt(8)" ::: "memory");
        else if (t + 1 < nk) asm volatile("s_waitcnt vmcnt(4)" ::: "memory");
        else                 asm volatile("s_waitcnt vmcnt(0)" ::: "memory");
        __builtin_amdgcn_sched_barrier(0);
        __builtin_amdgcn_s_barrier();     // raw barrier: no vmcnt(0) drain
        __builtin_amdgcn_sched_barrier(0);
        // stage tile t+3 into slot (t-1)&3 (reads of t-1 finished by barrier above)
        if (t + 3 < nk) stage(t + 3);

        const int slot = t & 3;
        f16x8 af[8], bf[4];
#pragma unroll
        for (int m = 0; m < 8; ++m)
            af[m] = *(const f16x8*)&As[slot][wm * 128 + m * 16 + fr][fkp];
#pragma unroll
        for (int n = 0; n < 4; ++n)
            bf[n] = *(const f16x8*)&Bs[slot][wn * 64 + n * 16 + fr][fkp];
        __builtin_amdgcn_s_setprio(1);
#pragma unroll
        for (int m = 0; m < 8; ++m)
#pragma unroll
            for (int n = 0; n < 4; ++n)
                acc[m][n] = __builtin_amdgcn_mfma_f32_16x16x32_f16(af[m], bf[n], acc[m][n], 0, 0, 0);
        __builtin_amdgcn_s_setprio(0);
    }

    // epilogue
#pragma unroll
    for (int m = 0; m < 8; ++m) {
        int row0 = brow + wm * 128 + m * 16 + crow;
#pragma unroll
        for (int n = 0; n < 4; ++n) {
            int col = bcol + wn * 64 + n * 16 + fr;
            float bv = bias[col];
#pragma unroll
            for (int r = 0; r < 4; ++r) {
                float v = acc[m][n][r] + bv;
                size_t idx = (size_t)(row0 + r) * N + col;
                if (OUT_F16) ((_Float16*)Cv)[idx] = (_Float16)v;
                else ((float*)Cv)[idx] = v;
            }
        }
    }
    (void)M;
}

extern "C" void kernel_launch(void* const* d_in, const int* in_sizes, int n_in,
                              void* d_out, int out_size, void* d_ws, size_t ws_size,
                              hipStream_t stream) {
    const float* x         = (const float*)d_in[0];
    const float* slot_init = (const float*)d_in[1];
    const float* rw1       = (const float*)d_in[2];
    const float* rb1       = (const float*)d_in[3];
    const float* rw2       = (const float*)d_in[4];
    const float* rb2       = (const float*)d_in[5];
    const float* gwi       = (const float*)d_in[6];
    const float* gwh       = (const float*)d_in[7];
    const float* gbi       = (const float*)d_in[8];
    const float* gbh       = (const float*)d_in[9];
    const float* hpw       = (const float*)d_in[10];
    const float* hpb       = (const float*)d_in[11];
    const float* ohw       = (const float*)d_in[12];
    const float* ohb       = (const float*)d_in[13];
    const float* vpw       = (const float*)d_in[14];
    const float* vpb       = (const float*)d_in[15];
    const float* vow       = (const float*)d_in[16];
    const float* vob       = (const float*)d_in[17];
    const float* opw       = (const float*)d_in[18];
    const float* opb       = (const float*)d_in[19];
    const float* tau       = (const float*)d_in[20];
    float* out = (float*)d_out;

    float* ws = (float*)d_ws;
    size_t off = 0;
    auto alloc = [&](size_t nfloats) { float* p = ws + off; off += (nfloats + 63) & ~(size_t)63; return p; };

    float* cb     = alloc(1024);
    float* cbp    = alloc(16 * 1024);
    float* h1     = alloc((size_t)MTOK * 1024);            // fp32; dead after logits:
    _Float16* v1a = (_Float16*)h1;                          //   v1 rows 0..8191 [8192,4096] f16
    float* logits = alloc((size_t)MTOK * 64);
    float* alpha  = alloc((size_t)MTOK * 64);
    _Float16* alpha16 = (_Float16*)alloc((size_t)MTOK * 64 / 2);
    float* slotin = alloc(256 * 64);
    float* part   = alloc((size_t)8 * 64 * 4 * 64);
    float* partw  = alloc(8 * 64 * 4);
    float* Snew   = alloc(256 * 64);
    _Float16* PT   = (_Float16*)alloc((size_t)Bb * HMm * 64 / 2);  // [4,4096,64] f16
    _Float16* vowT = (_Float16*)alloc((size_t)Dd * HMm / 2);       // [1024,4096] f16
    _Float16* opwT = (_Float16*)alloc((size_t)Dd * Dd / 2);        // [1024,1024] f16
    _Float16* v2f16 = (_Float16*)alloc((size_t)MTOK * Dd / 2);     // [16384,1024] f16
    _Float16* w1hiT = (_Float16*)alloc((size_t)Dd * Dd / 2);
    _Float16* w1loT = (_Float16*)alloc((size_t)Dd * Dd / 2);

    // d_out scratch: xhi/xlo before hgemm4; v1 rows 8192..16383 after vgen.
    _Float16* xhi = (_Float16*)d_out;
    _Float16* xlo = xhi + (size_t)MTOK * Dd;
    _Float16* v1b = (_Float16*)d_out;

    // ---- routing: pre-split x + 4-plane split-fp16 MFMA GEMM + fp32 logits ----
    cb_part_k<<<dim3(4, 16), 256, 0, stream>>>(slot_init, rw1, cbp);
    cb_comb_k<<<4, 256, 0, stream>>>(cbp, cb);
    wsplitT_k<<<dim3(Dd / 32, Dd / 32), 256, 0, stream>>>(rw1, w1hiT, w1loT);
    xsplit_k<<<(MTOK * Dd) / (256 * 8), 256, 0, stream>>>(x, xhi, xlo);
    hgemm4_k<<<dim3(Dd / 128, MTOK / 128), 256, 0, stream>>>(
        xhi, xlo, w1hiT, w1loT, rb1, cb, h1, MTOK, Dd, Dd);
    logits2_k<<<MTOK / 64, 256, 0, stream>>>(h1, rw2, rb2, tau, logits);
    topk_k<<<MTOK / 4, 256, 0, stream>>>(logits, alpha, alpha16);

    // ---- weight transposes (fp32 -> fp16 [N,K]) ----
    transp_f16_k<<<dim3(Dd / 32, HMm / 32), 256, 0, stream>>>(vow, vowT, HMm, Dd);
    transp_f16_k<<<dim3(Dd / 32, Dd / 32), 256, 0, stream>>>(opw, opwT, Dd, Dd);

    // ---- slot pooling + GRU + slot MLP ----
    pool_part_k<<<dim3(64, 8), 256, 0, stream>>>(x, alpha, part, partw);
    pool_comb_k<<<64, 256, 0, stream>>>(part, partw, slotin);
    gru_k<<<256, 64, 0, stream>>>(slotin, slot_init, gwi, gwh, gbi, gbh,
                                  hpw, hpb, ohw, ohb, Snew);

    // ---- P[b] = S_emb[b] @ vpw (stored transposed f16 [b][j][hs]) ----
    pmat_k<<<dim3(HMm / 256, Hh), 256, 0, stream>>>(Snew, vpw, PT);

    // ---- value MLP: vgen (K=64), then deep-pipelined 256^2 GEMM2 + GEMM3 ----
    vgen_k<<<dim3(HMm / 128, MTOK / 128), 256, 0, stream>>>(
        alpha16, PT, vpb, v1a, v1b);
    hgemm8_k<1><<<dim3(Dd / 256, MTOK / 256), 512, 0, stream>>>(
        v1a, v1b, 8192, vowT, vob, v2f16, MTOK, Dd, HMm);
    hgemm8_k<0><<<dim3(Dd / 256, MTOK / 256), 512, 0, stream>>>(
        v2f16, v2f16, MTOK, opwT, opb, out, MTOK, Dd, Dd);

    (void)in_sizes; (void)n_in; (void)out_size; (void)ws_size;
}

// Round 9
// 563.576 us; speedup vs baseline: 1.5109x; 1.0267x over previous
//
#include <hip/hip_runtime.h>
#include <cstddef>
#include <cstdint>

// Problem constants
#define Bb 4
#define Tt 4096
#define Dd 1024
#define Hh 16
#define HDd 64
#define NSs 64
#define SPHh 4
#define HMm 4096
#define MTOK (Bb*Tt)   // 16384

typedef _Float16 f16x8 __attribute__((ext_vector_type(8)));
typedef _Float16 f16x4 __attribute__((ext_vector_type(4)));
typedef float f32x4 __attribute__((ext_vector_type(4)));

__device__ __forceinline__ float gelu_f(float x) {
    return 0.5f * x * (1.0f + erff(x * 0.70710678118654752440f));
}

// XCD-chunked bijective block swizzle (requires nwg % 8 == 0; all launches comply)
__device__ __forceinline__ int xcd_swz(int nwg) {
    int orig = blockIdx.y * gridDim.x + blockIdx.x;
    int cpx = nwg >> 3;
    return (orig & 7) * cpx + (orig >> 3);
}

// ---------------- K0: cb partials ----------------
__global__ __launch_bounds__(256) void cb_part_k(const float* __restrict__ slot_init,
                                                 const float* __restrict__ rw1,
                                                 float* __restrict__ cbp) {
    __shared__ float sm[64];
    int tid = threadIdx.x;
    if (tid < 64) {
        float s = 0.f;
        for (int i = 0; i < 64; ++i) s += slot_init[i * 64 + tid];
        sm[tid] = s * (1.0f / 64.0f);
    }
    __syncthreads();
    int j = blockIdx.x * 256 + tid;
    int k0 = blockIdx.y * 64;
    float acc = 0.f;
#pragma unroll 8
    for (int k = 0; k < 64; ++k)
        acc = fmaf(sm[k], rw1[(size_t)(1024 + k0 + k) * 1024 + j], acc);
    cbp[(size_t)blockIdx.y * 1024 + j] = acc;
}

__global__ __launch_bounds__(256) void cb_comb_k(const float* __restrict__ cbp,
                                                 float* __restrict__ cb) {
    int j = blockIdx.x * 256 + threadIdx.x;
    float acc = 0.f;
#pragma unroll
    for (int c = 0; c < 16; ++c) acc += cbp[(size_t)c * 1024 + j];
    cb[j] = acc;
}

// ---------------- K1: rw1[:1024] -> transposed split-f16 planes ----------------
__global__ __launch_bounds__(256) void wsplitT_k(const float* __restrict__ rw1,
                                                 _Float16* __restrict__ whiT,
                                                 _Float16* __restrict__ wloT) {
    __shared__ float t[32][33];
    int n0 = blockIdx.x * 32, k0 = blockIdx.y * 32;
    int tx = threadIdx.x & 31, ty = threadIdx.x >> 5;
#pragma unroll
    for (int i = 0; i < 32; i += 8)
        t[ty + i][tx] = rw1[(size_t)(k0 + ty + i) * 1024 + n0 + tx];
    __syncthreads();
#pragma unroll
    for (int i = 0; i < 32; i += 8) {
        float v = t[tx][ty + i];
        _Float16 h = (_Float16)v;
        _Float16 l = (_Float16)(v - (float)h);
        whiT[(size_t)(n0 + ty + i) * 1024 + k0 + tx] = h;
        wloT[(size_t)(n0 + ty + i) * 1024 + k0 + tx] = l;
    }
}

// ---------------- K1a: x -> split f16 hi/lo planes ----------------
__global__ __launch_bounds__(256) void xsplit_k(const float* __restrict__ x,
                                                _Float16* __restrict__ xhi,
                                                _Float16* __restrict__ xlo) {
    size_t i = ((size_t)blockIdx.x * 256 + threadIdx.x) * 8;
    float4 a = *(const float4*)(x + i);
    float4 b = *(const float4*)(x + i + 4);
    float v[8] = {a.x, a.y, a.z, a.w, b.x, b.y, b.z, b.w};
    f16x8 h, l;
#pragma unroll
    for (int j = 0; j < 8; ++j) {
        _Float16 hv = (_Float16)v[j];
        h[j] = hv;
        l[j] = (_Float16)(v[j] - (float)hv);
    }
    *(f16x8*)(xhi + i) = h;
    *(f16x8*)(xlo + i) = l;
}

// ---------------- K1b: split-fp16 MFMA routing GEMM (pre-split 4-plane) ---------------
__global__ __launch_bounds__(256) void hgemm4_k(const _Float16* __restrict__ Ah,
                                                const _Float16* __restrict__ Al,
                                                const _Float16* __restrict__ Bh,
                                                const _Float16* __restrict__ Bl,
                                                const float* __restrict__ bias1,
                                                const float* __restrict__ bias2,
                                                float* __restrict__ C,
                                                int M, int N, int K) {
    __shared__ __align__(16) _Float16 Ahs[128][32];
    __shared__ __align__(16) _Float16 Als[128][32];
    __shared__ __align__(16) _Float16 Bhs[128][32];
    __shared__ __align__(16) _Float16 Bls[128][32];
    const int tid = threadIdx.x;
    const int wid = tid >> 6;
    const int lane = tid & 63;
    const int swz = xcd_swz(gridDim.x * gridDim.y);
    const int brow = (swz / gridDim.x) * 128;
    const int bcol = (swz % gridDim.x) * 128;
    const int wr = (wid >> 1) * 64;
    const int wc = (wid & 1) * 64;

    const int rb = lane >> 2;
    const int cbk = (lane & 3) * 8;
    const int fr = lane & 15;
    const int fk = (lane >> 4) * 8;

    f32x4 acc[4][4];
#pragma unroll
    for (int m = 0; m < 4; ++m)
#pragma unroll
        for (int n = 0; n < 4; ++n)
            acc[m][n] = f32x4{0.f, 0.f, 0.f, 0.f};

    for (int k0 = 0; k0 < K; k0 += 32) {
#pragma unroll
        for (int i = 0; i < 2; ++i) {
            int r0 = wid * 32 + i * 16;
            const _Float16* gah = Ah + (size_t)(brow + r0 + rb) * K + k0 + cbk;
            __builtin_amdgcn_global_load_lds(
                (const __attribute__((address_space(1))) void*)gah,
                (__attribute__((address_space(3))) void*)&Ahs[r0][0], 16, 0, 0);
            const _Float16* gal = Al + (size_t)(brow + r0 + rb) * K + k0 + cbk;
            __builtin_amdgcn_global_load_lds(
                (const __attribute__((address_space(1))) void*)gal,
                (__attribute__((address_space(3))) void*)&Als[r0][0], 16, 0, 0);
            const _Float16* gbh = Bh + (size_t)(bcol + r0 + rb) * K + k0 + cbk;
            __builtin_amdgcn_global_load_lds(
                (const __attribute__((address_space(1))) void*)gbh,
                (__attribute__((address_space(3))) void*)&Bhs[r0][0], 16, 0, 0);
            const _Float16* gbl = Bl + (size_t)(bcol + r0 + rb) * K + k0 + cbk;
            __builtin_amdgcn_global_load_lds(
                (const __attribute__((address_space(1))) void*)gbl,
                (__attribute__((address_space(3))) void*)&Bls[r0][0], 16, 0, 0);
        }
        __syncthreads();

        f16x8 afh[4], afl[4], bfh[4], bfl[4];
#pragma unroll
        for (int m = 0; m < 4; ++m) {
            afh[m] = *(const f16x8*)&Ahs[wr + m * 16 + fr][fk];
            afl[m] = *(const f16x8*)&Als[wr + m * 16 + fr][fk];
        }
#pragma unroll
        for (int n = 0; n < 4; ++n) {
            bfh[n] = *(const f16x8*)&Bhs[wc + n * 16 + fr][fk];
            bfl[n] = *(const f16x8*)&Bls[wc + n * 16 + fr][fk];
        }
#pragma unroll
        for (int m = 0; m < 4; ++m)
#pragma unroll
            for (int n = 0; n < 4; ++n) {
                acc[m][n] = __builtin_amdgcn_mfma_f32_16x16x32_f16(afl[m], bfh[n], acc[m][n], 0, 0, 0);
                acc[m][n] = __builtin_amdgcn_mfma_f32_16x16x32_f16(afh[m], bfl[n], acc[m][n], 0, 0, 0);
                acc[m][n] = __builtin_amdgcn_mfma_f32_16x16x32_f16(afh[m], bfh[n], acc[m][n], 0, 0, 0);
            }
        __syncthreads();
    }

    const int crow = (lane >> 4) * 4;
#pragma unroll
    for (int m = 0; m < 4; ++m) {
        int row0 = brow + wr + m * 16 + crow;
#pragma unroll
        for (int n = 0; n < 4; ++n) {
            int col = bcol + wc + n * 16 + fr;
            float bv = bias1[col] + bias2[col];
#pragma unroll
            for (int r = 0; r < 4; ++r) {
                float v = acc[m][n][r] + bv;
                C[(size_t)(row0 + r) * N + col] = gelu_f(v);
            }
        }
    }
}

// ---------------- K2: route logits (fp32, register-blocked; bit-identical k-order) ----
__global__ __launch_bounds__(256) void logits2_k(const float* __restrict__ A,
                                                 const float* __restrict__ Bw,
                                                 const float* __restrict__ rb2,
                                                 const float* __restrict__ taup,
                                                 float* __restrict__ Cl) {
    __shared__ float At[16][68];
    __shared__ float Bs[16][64];
    const int tid = threadIdx.x;
    const int m0 = blockIdx.x * 64;
    const int rg = tid >> 4;
    const int cg = tid & 15;
    const int srow = tid >> 2;
    const int skk  = (tid & 3) * 4;
    const int bk = tid >> 4;
    const int bc = (tid & 15) * 4;

    float acc[4][4] = {};

    for (int k0 = 0; k0 < 1024; k0 += 16) {
        float4 av = *(const float4*)(A + (size_t)(m0 + srow) * 1024 + k0 + skk);
        float4 bv = *(const float4*)(Bw + (size_t)(k0 + bk) * 64 + bc);
        __syncthreads();
        At[skk + 0][srow] = av.x;
        At[skk + 1][srow] = av.y;
        At[skk + 2][srow] = av.z;
        At[skk + 3][srow] = av.w;
        *(float4*)&Bs[bk][bc] = bv;
        __syncthreads();
#pragma unroll
        for (int k = 0; k < 16; ++k) {
            float4 a4 = *(const float4*)&At[k][rg * 4];
            float4 b4 = *(const float4*)&Bs[k][cg * 4];
            float a[4] = {a4.x, a4.y, a4.z, a4.w};
            float b[4] = {b4.x, b4.y, b4.z, b4.w};
#pragma unroll
            for (int i = 0; i < 4; ++i)
#pragma unroll
                for (int j = 0; j < 4; ++j)
                    acc[i][j] = fmaf(a[i], b[j], acc[i][j]);
        }
    }
    float inv = 1.0f / (fabsf(taup[0]) + 0.1f);
#pragma unroll
    for (int i = 0; i < 4; ++i)
#pragma unroll
        for (int j = 0; j < 4; ++j)
            Cl[(size_t)(m0 + rg * 4 + i) * 64 + cg * 4 + j] =
                (acc[i][j] + rb2[cg * 4 + j]) * inv;
}

// ---------------- K3: top-32-of-64 + softmax -> dense alpha ----------------
__global__ __launch_bounds__(256) void topk_k(const float* __restrict__ logits,
                                              float* __restrict__ alpha,
                                              _Float16* __restrict__ alpha16) {
    int wave = threadIdx.x >> 6;
    int lane = threadIdx.x & 63;
    int t = blockIdx.x * 4 + wave;
    float li = logits[(size_t)t * 64 + lane];
    float m = li;
#pragma unroll
    for (int off = 32; off; off >>= 1) m = fmaxf(m, __shfl_xor(m, off, 64));
    int cnt = 0;
    for (int off = 1; off < 64; ++off) {
        int j = (lane + off) & 63;
        float lj = __shfl(li, j, 64);
        cnt += (lj > li) || (lj == li && j < lane);
    }
    float e = (cnt < 32) ? expf(li - m) : 0.0f;
    float s = e;
#pragma unroll
    for (int off = 32; off; off >>= 1) s += __shfl_xor(s, off, 64);
    float a = e / s;
    alpha[(size_t)t * 64 + lane] = a;
    alpha16[(size_t)t * 64 + lane] = (_Float16)a;
}

// ---------------- K4: slot pooling ----------------
__global__ __launch_bounds__(256) void pool_part_k(const float* __restrict__ x,
                                                   const float* __restrict__ alpha,
                                                   float* __restrict__ part,
                                                   float* __restrict__ partw) {
    int bh = blockIdx.x;
    int c = blockIdx.y;
    int b = bh >> 4, h = bh & 15;
    int tid = threadIdx.x;
    int s = tid >> 6, d = tid & 63;
    __shared__ float lx[16][64];
    __shared__ float la[16][4];
    float acc = 0.f, wacc = 0.f;
    const int tchunk = Tt / 8;
    const int t0base = c * tchunk;
    for (int t0 = 0; t0 < tchunk; t0 += 16) {
        int ttr = tid >> 4;
        int ddr = (tid & 15) * 4;
        size_t trow = (size_t)b * Tt + t0base + t0 + ttr;
        float4 xv = *(const float4*)(x + trow * Dd + h * 64 + ddr);
        *(float4*)&lx[ttr][ddr] = xv;
        if (tid < 64) {
            int tt2 = tid >> 2, ss = tid & 3;
            la[tt2][ss] = alpha[((size_t)b * Tt + t0base + t0 + tt2) * 64 + h * 4 + ss];
        }
        __syncthreads();
#pragma unroll
        for (int q = 0; q < 16; ++q) {
            float av = la[q][s];
            acc = fmaf(av, lx[q][d], acc);
            wacc += av;
        }
        __syncthreads();
    }
    part[(((size_t)c * 64 + bh) * 4 + s) * 64 + d] = acc;
    if (d == 0) partw[((size_t)c * 64 + bh) * 4 + s] = wacc;
}

__global__ __launch_bounds__(256) void pool_comb_k(const float* __restrict__ part,
                                                   const float* __restrict__ partw,
                                                   float* __restrict__ slot_in) {
    int bh = blockIdx.x;
    int tid = threadIdx.x;
    int s = tid >> 6, d = tid & 63;
    float acc = 0.f, w = 0.f;
    for (int c = 0; c < 8; ++c) {
        acc += part[(((size_t)c * 64 + bh) * 4 + s) * 64 + d];
        w   += partw[((size_t)c * 64 + bh) * 4 + s];
    }
    slot_in[((size_t)bh * 4 + s) * 64 + d] = acc / (w + 1e-8f);
}

// ---------------- K5: GRU + slot MLP ----------------
__global__ __launch_bounds__(64) void gru_k(const float* __restrict__ slot_in,
                                            const float* __restrict__ slot_init,
                                            const float* __restrict__ gwi,
                                            const float* __restrict__ gwh,
                                            const float* __restrict__ gbi,
                                            const float* __restrict__ gbh,
                                            const float* __restrict__ hpw,
                                            const float* __restrict__ hpb,
                                            const float* __restrict__ ohw,
                                            const float* __restrict__ ohb,
                                            float* __restrict__ S_new) {
    int slot = blockIdx.x;
    int hs = slot & 63;
    int d = threadIdx.x;
    __shared__ float si[64], hp[64], hn[64], g[256];
    si[d] = slot_in[(size_t)slot * 64 + d];
    hp[d] = slot_init[(size_t)hs * 64 + d];
    __syncthreads();
    float gi_r = gbi[d], gi_z = gbi[64 + d], gi_n = gbi[128 + d];
    float gh_r = gbh[d], gh_z = gbh[64 + d], gh_n = gbh[128 + d];
    for (int k = 0; k < 64; ++k) {
        float sv = si[k], hv = hp[k];
        gi_r = fmaf(sv, gwi[(size_t)(d) * 64 + k], gi_r);
        gi_z = fmaf(sv, gwi[(size_t)(64 + d) * 64 + k], gi_z);
        gi_n = fmaf(sv, gwi[(size_t)(128 + d) * 64 + k], gi_n);
        gh_r = fmaf(hv, gwh[(size_t)(d) * 64 + k], gh_r);
        gh_z = fmaf(hv, gwh[(size_t)(64 + d) * 64 + k], gh_z);
        gh_n = fmaf(hv, gwh[(size_t)(128 + d) * 64 + k], gh_n);
    }
    float r = 1.0f / (1.0f + expf(-(gi_r + gh_r)));
    float z = 1.0f / (1.0f + expf(-(gi_z + gh_z)));
    float n = tanhf(gi_n + r * gh_n);
    float hnew = (1.0f - z) * n + z * hp[d];
    hn[d] = hnew;
    __syncthreads();
    float p0 = hpb[d], p1 = hpb[64 + d], p2 = hpb[128 + d], p3 = hpb[192 + d];
    for (int k = 0; k < 64; ++k) {
        float hv = hn[k];
        p0 = fmaf(hv, hpw[(size_t)k * 256 + d], p0);
        p1 = fmaf(hv, hpw[(size_t)k * 256 + 64 + d], p1);
        p2 = fmaf(hv, hpw[(size_t)k * 256 + 128 + d], p2);
        p3 = fmaf(hv, hpw[(size_t)k * 256 + 192 + d], p3);
    }
    g[d] = gelu_f(p0); g[64 + d] = gelu_f(p1); g[128 + d] = gelu_f(p2); g[192 + d] = gelu_f(p3);
    __syncthreads();
    float o = ohb[d];
    for (int j = 0; j < 256; ++j) o = fmaf(g[j], ohw[(size_t)j * 64 + d], o);
    S_new[(size_t)slot * 64 + d] = o;
}

// ---------------- K6: PT[b][j][hs] = sum_d Snew[b,hs,d] * vpw[h*64+d, j]  (f16) -------
__global__ __launch_bounds__(256) void pmat_k(const float* __restrict__ Snew,
                                              const float* __restrict__ vpw,
                                              _Float16* __restrict__ PT) {
    const int h = blockIdx.y;
    const int tid = threadIdx.x;
    const int j = blockIdx.x * 256 + tid;
    __shared__ float S[16][64];
    for (int i = tid; i < 1024; i += 256) {
        int row = i >> 6, d = i & 63;
        int b = row >> 2, s = row & 3;
        S[row][d] = Snew[((size_t)b * 64 + h * 4 + s) * 64 + d];
    }
    __syncthreads();
    float acc[16];
#pragma unroll
    for (int r = 0; r < 16; ++r) acc[r] = 0.f;
    const float* wp = vpw + (size_t)h * 64 * HMm + j;
#pragma unroll 4
    for (int d = 0; d < 64; ++d) {
        float w = wp[(size_t)d * HMm];
#pragma unroll
        for (int r = 0; r < 16; ++r) acc[r] = fmaf(S[r][d], w, acc[r]);
    }
#pragma unroll
    for (int b = 0; b < 4; ++b) {
        f16x4 o;
#pragma unroll
        for (int s = 0; s < 4; ++s) o[s] = (_Float16)acc[b * 4 + s];
        *(f16x4*)&PT[((size_t)b * HMm + j) * 64 + h * 4] = o;
    }
}

// ---------------- K7: transpose + fp32->fp16 convert ----------------
__global__ __launch_bounds__(256) void transp_f16_k(const float* __restrict__ in,
                                                    _Float16* __restrict__ out,
                                                    int K, int N) {
    __shared__ float t[32][33];
    int n0 = blockIdx.x * 32, k0 = blockIdx.y * 32;
    int tx = threadIdx.x & 31, ty = threadIdx.x >> 5;
#pragma unroll
    for (int i = 0; i < 32; i += 8)
        t[ty + i][tx] = in[(size_t)(k0 + ty + i) * N + n0 + tx];
    __syncthreads();
#pragma unroll
    for (int i = 0; i < 32; i += 8)
        out[(size_t)(n0 + ty + i) * K + k0 + tx] = (_Float16)t[tx][ty + i];
}

// ---------------- K9: vgen = gelu(alpha16 @ PT[b]^T + vpb), single launch, K=64 -------
__global__ __launch_bounds__(256) void vgen_k(const _Float16* __restrict__ alpha16,
                                              const _Float16* __restrict__ PT,
                                              const float* __restrict__ vpb,
                                              _Float16* __restrict__ v1a,
                                              _Float16* __restrict__ v1b) {
    __shared__ __align__(16) _Float16 As[128][64];
    __shared__ __align__(16) _Float16 Bs[128][64];
    const int tid = threadIdx.x;
    const int wid = tid >> 6;
    const int lane = tid & 63;
    const int swz = xcd_swz(gridDim.x * gridDim.y);
    const int brow = (swz / gridDim.x) * 128;
    const int bcol = (swz % gridDim.x) * 128;
    const int b = brow >> 12;
    const _Float16* Bt = PT + (size_t)b * HMm * 64;
    _Float16* Cb = (brow < 8192) ? v1a : v1b;
    const int rowoff = (brow < 8192) ? brow : brow - 8192;
    const int wr = (wid >> 1) * 64;
    const int wc = (wid & 1) * 64;

    f32x4 acc[4][4];
#pragma unroll
    for (int m = 0; m < 4; ++m)
#pragma unroll
        for (int n = 0; n < 4; ++n)
            acc[m][n] = f32x4{0.f, 0.f, 0.f, 0.f};

    const int lrow = lane >> 3;
    const int lcol = (lane & 7) * 8;
    const int fr = lane & 15;
    const int fk = (lane >> 4) * 8;

#pragma unroll
    for (int i = 0; i < 4; ++i) {
        int seg = wid * 4 + i;
        const _Float16* g = alpha16 + (size_t)(brow + seg * 8 + lrow) * 64 + lcol;
        __builtin_amdgcn_global_load_lds(
            (const __attribute__((address_space(1))) void*)g,
            (__attribute__((address_space(3))) void*)&As[seg * 8][0], 16, 0, 0);
    }
#pragma unroll
    for (int i = 0; i < 4; ++i) {
        int seg = wid * 4 + i;
        const _Float16* g = Bt + (size_t)(bcol + seg * 8 + lrow) * 64 + lcol;
        __builtin_amdgcn_global_load_lds(
            (const __attribute__((address_space(1))) void*)g,
            (__attribute__((address_space(3))) void*)&Bs[seg * 8][0], 16, 0, 0);
    }
    __syncthreads();
#pragma unroll
    for (int kb = 0; kb < 2; ++kb) {
        f16x8 af[4], bf[4];
#pragma unroll
        for (int m = 0; m < 4; ++m)
            af[m] = *(const f16x8*)&As[wr + m * 16 + fr][kb * 32 + fk];
#pragma unroll
        for (int n = 0; n < 4; ++n)
            bf[n] = *(const f16x8*)&Bs[wc + n * 16 + fr][kb * 32 + fk];
#pragma unroll
        for (int m = 0; m < 4; ++m)
#pragma unroll
            for (int n = 0; n < 4; ++n)
                acc[m][n] = __builtin_amdgcn_mfma_f32_16x16x32_f16(af[m], bf[n], acc[m][n], 0, 0, 0);
    }

    const int crow = (lane >> 4) * 4;
#pragma unroll
    for (int m = 0; m < 4; ++m) {
        int row0 = rowoff + wr + m * 16 + crow;
#pragma unroll
        for (int n = 0; n < 4; ++n) {
            int col = bcol + wc + n * 16 + fr;
            float bv = vpb[col];
#pragma unroll
            for (int r = 0; r < 4; ++r) {
                float v = acc[m][n][r] + bv;
                Cb[(size_t)(row0 + r) * HMm + col] = (_Float16)gelu_f(v);
            }
        }
    }
}

// ---------------- K11: 256x256 deep-pipelined GEMM, 2-phase interleave per K-32 tile.
// T3 phase-split + T4 counted vmcnt (ring-4) + T2 pre-swizzled source + T5 setprio.
template <int OUT_F16>
__global__ __launch_bounds__(512, 2) void hgemm8_k(const _Float16* __restrict__ A0,
                                                   const _Float16* __restrict__ A1,
                                                   int splitrow,
                                                   const _Float16* __restrict__ Bt,
                                                   const float* __restrict__ bias,
                                                   void* __restrict__ Cv,
                                                   int M, int N, int K) {
    __shared__ __align__(16) _Float16 As[4][256][32];   // 64 KB
    __shared__ __align__(16) _Float16 Bs[4][256][32];   // 64 KB
    const int tid = threadIdx.x;
    const int wid = tid >> 6;            // 0..7
    const int lane = tid & 63;
    const int swz = xcd_swz(gridDim.x * gridDim.y);
    const int brow = (swz / gridDim.x) * 256;
    const int bcol = (swz % gridDim.x) * 256;
    const _Float16* Ab = (brow < splitrow) ? A0 : A1;
    const int arow0 = brow - ((brow < splitrow) ? 0 : splitrow);
    const int wm = wid >> 2;             // 0..1 -> 128-row half
    const int wn = wid & 3;              // 0..3 -> 64-col quarter

    // staging lane map: 16 rows x 64B per issue; source col-block pre-swizzled (m173)
    const int srow = lane >> 2;
    const int scol = ((lane & 3) ^ ((lane >> 3) & 3)) * 8;
    // fragment read: physical 16B-block = logical ^ ((row>>1)&3), fixed per lane
    const int fr = lane & 15;
    const int fkp = (((lane >> 4) ^ ((lane >> 1) & 3))) * 8;
    const int crow = (lane >> 4) * 4;

    const int nk = K >> 5;

    f32x4 acc[8][4];
#pragma unroll
    for (int m = 0; m < 8; ++m)
#pragma unroll
        for (int n = 0; n < 4; ++n)
            acc[m][n] = f32x4{0.f, 0.f, 0.f, 0.f};

    auto stage = [&](int t) {
        const int slot = t & 3;
        const size_t kk = (size_t)t << 5;
#pragma unroll
        for (int i = 0; i < 2; ++i) {
            const _Float16* g = Ab + (size_t)(arow0 + wid * 32 + i * 16 + srow) * K + kk + scol;
            __builtin_amdgcn_global_load_lds(
                (const __attribute__((address_space(1))) void*)g,
                (__attribute__((address_space(3))) void*)&As[slot][wid * 32 + i * 16][0], 16, 0, 0);
        }
#pragma unroll
        for (int i = 0; i < 2; ++i) {
            const _Float16* g = Bt + (size_t)(bcol + wid * 32 + i * 16 + srow) * K + kk + scol;
            __builtin_amdgcn_global_load_lds(
                (const __attribute__((address_space(1))) void*)g,
                (__attribute__((address_space(3))) void*)&Bs[slot][wid * 32 + i * 16][0], 16, 0, 0);
        }
    };

    // prologue: 3 tiles in flight
    stage(0);
    if (nk > 1) stage(1);
    if (nk > 2) stage(2);

    for (int t = 0; t < nk; ++t) {
        // counted wait: tiles t+1, t+2 stay in flight (never drain to 0 mid-loop)
        if (t + 2 < nk)      asm volatile("s_waitcnt vmcnt(8)" ::: "memory");
        else if (t + 1 < nk) asm volatile("s_waitcnt vmcnt(4)" ::: "memory");
        else                 asm volatile("s_waitcnt vmcnt(0)" ::: "memory");
        __builtin_amdgcn_sched_barrier(0);
        __builtin_amdgcn_s_barrier();     // tile t staged for all waves
        __builtin_amdgcn_sched_barrier(0);

        const int slot = t & 3;
        f16x8 af[8], bf[4];
        // ---- phase A: reads for first 16 MFMA + next-tile staging ----
#pragma unroll
        for (int m = 0; m < 4; ++m)
            af[m] = *(const f16x8*)&As[slot][wm * 128 + m * 16 + fr][fkp];
#pragma unroll
        for (int n = 0; n < 4; ++n)
            bf[n] = *(const f16x8*)&Bs[slot][wn * 64 + n * 16 + fr][fkp];
        if (t + 3 < nk) stage(t + 3);     // slot (t-1)&3: reads drained in prior phase B
        __builtin_amdgcn_sched_barrier(0);
        __builtin_amdgcn_s_barrier();     // all waves issued phase-A reads
        asm volatile("s_waitcnt lgkmcnt(0)" ::: "memory");
        __builtin_amdgcn_sched_barrier(0);
        __builtin_amdgcn_s_setprio(1);
#pragma unroll
        for (int m = 0; m < 4; ++m)
#pragma unroll
            for (int n = 0; n < 4; ++n)
                acc[m][n] = __builtin_amdgcn_mfma_f32_16x16x32_f16(af[m], bf[n], acc[m][n], 0, 0, 0);
        __builtin_amdgcn_s_setprio(0);
        __builtin_amdgcn_sched_barrier(0);
        // ---- phase B: remaining reads overlap stragglers' phase-A MFMA ----
#pragma unroll
        for (int m = 4; m < 8; ++m)
            af[m] = *(const f16x8*)&As[slot][wm * 128 + m * 16 + fr][fkp];
        __builtin_amdgcn_sched_barrier(0);
        __builtin_amdgcn_s_barrier();
        asm volatile("s_waitcnt lgkmcnt(0)" ::: "memory");
        __builtin_amdgcn_sched_barrier(0);
        __builtin_amdgcn_s_setprio(1);
#pragma unroll
        for (int m = 4; m < 8; ++m)
#pragma unroll
            for (int n = 0; n < 4; ++n)
                acc[m][n] = __builtin_amdgcn_mfma_f32_16x16x32_f16(af[m], bf[n], acc[m][n], 0, 0, 0);
        __builtin_amdgcn_s_setprio(0);
        __builtin_amdgcn_sched_barrier(0);
    }

    // epilogue
#pragma unroll
    for (int m = 0; m < 8; ++m) {
        int row0 = brow + wm * 128 + m * 16 + crow;
#pragma unroll
        for (int n = 0; n < 4; ++n) {
            int col = bcol + wn * 64 + n * 16 + fr;
            float bv = bias[col];
#pragma unroll
            for (int r = 0; r < 4; ++r) {
                float v = acc[m][n][r] + bv;
                size_t idx = (size_t)(row0 + r) * N + col;
                if (OUT_F16) ((_Float16*)Cv)[idx] = (_Float16)v;
                else ((float*)Cv)[idx] = v;
            }
        }
    }
    (void)M;
}

extern "C" void kernel_launch(void* const* d_in, const int* in_sizes, int n_in,
                              void* d_out, int out_size, void* d_ws, size_t ws_size,
                              hipStream_t stream) {
    const float* x         = (const float*)d_in[0];
    const float* slot_init = (const float*)d_in[1];
    const float* rw1       = (const float*)d_in[2];
    const float* rb1       = (const float*)d_in[3];
    const float* rw2       = (const float*)d_in[4];
    const float* rb2       = (const float*)d_in[5];
    const float* gwi       = (const float*)d_in[6];
    const float* gwh       = (const float*)d_in[7];
    const float* gbi       = (const float*)d_in[8];
    const float* gbh       = (const float*)d_in[9];
    const float* hpw       = (const float*)d_in[10];
    const float* hpb       = (const float*)d_in[11];
    const float* ohw       = (const float*)d_in[12];
    const float* ohb       = (const float*)d_in[13];
    const float* vpw       = (const float*)d_in[14];
    const float* vpb       = (const float*)d_in[15];
    const float* vow       = (const float*)d_in[16];
    const float* vob       = (const float*)d_in[17];
    const float* opw       = (const float*)d_in[18];
    const float* opb       = (const float*)d_in[19];
    const float* tau       = (const float*)d_in[20];
    float* out = (float*)d_out;

    float* ws = (float*)d_ws;
    size_t off = 0;
    auto alloc = [&](size_t nfloats) { float* p = ws + off; off += (nfloats + 63) & ~(size_t)63; return p; };

    float* cb     = alloc(1024);
    float* cbp    = alloc(16 * 1024);
    float* h1     = alloc((size_t)MTOK * 1024);            // fp32; dead after logits:
    _Float16* v1a = (_Float16*)h1;                          //   v1 rows 0..8191 [8192,4096] f16
    float* logits = alloc((size_t)MTOK * 64);
    float* alpha  = alloc((size_t)MTOK * 64);
    _Float16* alpha16 = (_Float16*)alloc((size_t)MTOK * 64 / 2);
    float* slotin = alloc(256 * 64);
    float* part   = alloc((size_t)8 * 64 * 4 * 64);
    float* partw  = alloc(8 * 64 * 4);
    float* Snew   = alloc(256 * 64);
    _Float16* PT   = (_Float16*)alloc((size_t)Bb * HMm * 64 / 2);  // [4,4096,64] f16
    _Float16* vowT = (_Float16*)alloc((size_t)Dd * HMm / 2);       // [1024,4096] f16
    _Float16* opwT = (_Float16*)alloc((size_t)Dd * Dd / 2);        // [1024,1024] f16
    _Float16* v2f16 = (_Float16*)alloc((size_t)MTOK * Dd / 2);     // [16384,1024] f16
    _Float16* w1hiT = (_Float16*)alloc((size_t)Dd * Dd / 2);
    _Float16* w1loT = (_Float16*)alloc((size_t)Dd * Dd / 2);

    // d_out scratch: xhi/xlo before hgemm4; v1 rows 8192..16383 after vgen.
    _Float16* xhi = (_Float16*)d_out;
    _Float16* xlo = xhi + (size_t)MTOK * Dd;
    _Float16* v1b = (_Float16*)d_out;

    // ---- routing: pre-split x + 4-plane split-fp16 MFMA GEMM + fp32 logits ----
    cb_part_k<<<dim3(4, 16), 256, 0, stream>>>(slot_init, rw1, cbp);
    cb_comb_k<<<4, 256, 0, stream>>>(cbp, cb);
    wsplitT_k<<<dim3(Dd / 32, Dd / 32), 256, 0, stream>>>(rw1, w1hiT, w1loT);
    xsplit_k<<<(MTOK * Dd) / (256 * 8), 256, 0, stream>>>(x, xhi, xlo);
    hgemm4_k<<<dim3(Dd / 128, MTOK / 128), 256, 0, stream>>>(
        xhi, xlo, w1hiT, w1loT, rb1, cb, h1, MTOK, Dd, Dd);
    logits2_k<<<MTOK / 64, 256, 0, stream>>>(h1, rw2, rb2, tau, logits);
    topk_k<<<MTOK / 4, 256, 0, stream>>>(logits, alpha, alpha16);

    // ---- weight transposes (fp32 -> fp16 [N,K]) ----
    transp_f16_k<<<dim3(Dd / 32, HMm / 32), 256, 0, stream>>>(vow, vowT, HMm, Dd);
    transp_f16_k<<<dim3(Dd / 32, Dd / 32), 256, 0, stream>>>(opw, opwT, Dd, Dd);

    // ---- slot pooling + GRU + slot MLP ----
    pool_part_k<<<dim3(64, 8), 256, 0, stream>>>(x, alpha, part, partw);
    pool_comb_k<<<64, 256, 0, stream>>>(part, partw, slotin);
    gru_k<<<256, 64, 0, stream>>>(slotin, slot_init, gwi, gwh, gbi, gbh,
                                  hpw, hpb, ohw, ohb, Snew);

    // ---- P[b] = S_emb[b] @ vpw (stored transposed f16 [b][j][hs]) ----
    pmat_k<<<dim3(HMm / 256, Hh), 256, 0, stream>>>(Snew, vpw, PT);

    // ---- value MLP: vgen (K=64), then deep-pipelined 256^2 GEMM2 + GEMM3 ----
    vgen_k<<<dim3(HMm / 128, MTOK / 128), 256, 0, stream>>>(
        alpha16, PT, vpb, v1a, v1b);
    hgemm8_k<1><<<dim3(Dd / 256, MTOK / 256), 512, 0, stream>>>(
        v1a, v1b, 8192, vowT, vob, v2f16, MTOK, Dd, HMm);
    hgemm8_k<0><<<dim3(Dd / 256, MTOK / 256), 512, 0, stream>>>(
        v2f16, v2f16, MTOK, opwT, opb, out, MTOK, Dd, Dd);

    (void)in_sizes; (void)n_in; (void)out_size; (void)ws_size;
}

// Round 10
// 545.752 us; speedup vs baseline: 1.5603x; 1.0327x over previous
//
#include <hip/hip_runtime.h>
#include <cstddef>
#include <cstdint>

// Problem constants
#define Bb 4
#define Tt 4096
#define Dd 1024
#define Hh 16
#define HDd 64
#define NSs 64
#define SPHh 4
#define HMm 4096
#define MTOK (Bb*Tt)   // 16384

typedef _Float16 f16x8 __attribute__((ext_vector_type(8)));
typedef _Float16 f16x4 __attribute__((ext_vector_type(4)));
typedef float f32x4 __attribute__((ext_vector_type(4)));

__device__ __forceinline__ float gelu_f(float x) {
    return 0.5f * x * (1.0f + erff(x * 0.70710678118654752440f));
}

// XCD-chunked bijective block swizzle (requires nwg % 8 == 0; all launches comply)
__device__ __forceinline__ int xcd_swz(int nwg) {
    int orig = blockIdx.y * gridDim.x + blockIdx.x;
    int cpx = nwg >> 3;
    return (orig & 7) * cpx + (orig >> 3);
}

// ---------------- K0: cb partials ----------------
__global__ __launch_bounds__(256) void cb_part_k(const float* __restrict__ slot_init,
                                                 const float* __restrict__ rw1,
                                                 float* __restrict__ cbp) {
    __shared__ float sm[64];
    int tid = threadIdx.x;
    if (tid < 64) {
        float s = 0.f;
        for (int i = 0; i < 64; ++i) s += slot_init[i * 64 + tid];
        sm[tid] = s * (1.0f / 64.0f);
    }
    __syncthreads();
    int j = blockIdx.x * 256 + tid;
    int k0 = blockIdx.y * 64;
    float acc = 0.f;
#pragma unroll 8
    for (int k = 0; k < 64; ++k)
        acc = fmaf(sm[k], rw1[(size_t)(1024 + k0 + k) * 1024 + j], acc);
    cbp[(size_t)blockIdx.y * 1024 + j] = acc;
}

__global__ __launch_bounds__(256) void cb_comb_k(const float* __restrict__ cbp,
                                                 float* __restrict__ cb) {
    int j = blockIdx.x * 256 + threadIdx.x;
    float acc = 0.f;
#pragma unroll
    for (int c = 0; c < 16; ++c) acc += cbp[(size_t)c * 1024 + j];
    cb[j] = acc;
}

// ---------------- K1: rw1[:1024] -> transposed split-f16 planes ----------------
__global__ __launch_bounds__(256) void wsplitT_k(const float* __restrict__ rw1,
                                                 _Float16* __restrict__ whiT,
                                                 _Float16* __restrict__ wloT) {
    __shared__ float t[32][33];
    int n0 = blockIdx.x * 32, k0 = blockIdx.y * 32;
    int tx = threadIdx.x & 31, ty = threadIdx.x >> 5;
#pragma unroll
    for (int i = 0; i < 32; i += 8)
        t[ty + i][tx] = rw1[(size_t)(k0 + ty + i) * 1024 + n0 + tx];
    __syncthreads();
#pragma unroll
    for (int i = 0; i < 32; i += 8) {
        float v = t[tx][ty + i];
        _Float16 h = (_Float16)v;
        _Float16 l = (_Float16)(v - (float)h);
        whiT[(size_t)(n0 + ty + i) * 1024 + k0 + tx] = h;
        wloT[(size_t)(n0 + ty + i) * 1024 + k0 + tx] = l;
    }
}

// ---------------- K1a: x -> split f16 hi/lo planes ----------------
__global__ __launch_bounds__(256) void xsplit_k(const float* __restrict__ x,
                                                _Float16* __restrict__ xhi,
                                                _Float16* __restrict__ xlo) {
    size_t i = ((size_t)blockIdx.x * 256 + threadIdx.x) * 8;
    float4 a = *(const float4*)(x + i);
    float4 b = *(const float4*)(x + i + 4);
    float v[8] = {a.x, a.y, a.z, a.w, b.x, b.y, b.z, b.w};
    f16x8 h, l;
#pragma unroll
    for (int j = 0; j < 8; ++j) {
        _Float16 hv = (_Float16)v[j];
        h[j] = hv;
        l[j] = (_Float16)(v[j] - (float)hv);
    }
    *(f16x8*)(xhi + i) = h;
    *(f16x8*)(xlo + i) = l;
}

// ---------------- K1b: deep-pipelined split-fp16 routing GEMM ----------------
// 256x256 tile, BK=32, ring-2 (4 planes x 2 slots = 128KB), counted vmcnt, 2-phase.
// C = gelu(A@B^T + bias1 + bias2); 3-term Markidis, bit-identical chain to hgemm4.
__global__ __launch_bounds__(512, 2) void hgemm4p_k(const _Float16* __restrict__ Ah,
                                                    const _Float16* __restrict__ Al,
                                                    const _Float16* __restrict__ Bh,
                                                    const _Float16* __restrict__ Bl,
                                                    const float* __restrict__ bias1,
                                                    const float* __restrict__ bias2,
                                                    float* __restrict__ C,
                                                    int M, int N, int K) {
    __shared__ __align__(16) _Float16 Ahs[2][256][32];
    __shared__ __align__(16) _Float16 Als[2][256][32];
    __shared__ __align__(16) _Float16 Bhs[2][256][32];
    __shared__ __align__(16) _Float16 Bls[2][256][32];
    const int tid = threadIdx.x;
    const int wid = tid >> 6;            // 0..7
    const int lane = tid & 63;
    const int swz = xcd_swz(gridDim.x * gridDim.y);
    const int brow = (swz / gridDim.x) * 256;
    const int bcol = (swz % gridDim.x) * 256;
    const int wm = wid >> 2;             // 0..1
    const int wn = wid & 3;              // 0..3

    const int srow = lane >> 2;
    const int scol = ((lane & 3) ^ ((lane >> 3) & 3)) * 8;
    const int fr = lane & 15;
    const int fkp = (((lane >> 4) ^ ((lane >> 1) & 3))) * 8;
    const int crow = (lane >> 4) * 4;

    const int nk = K >> 5;   // 32

    f32x4 acc[8][4];
#pragma unroll
    for (int m = 0; m < 8; ++m)
#pragma unroll
        for (int n = 0; n < 4; ++n)
            acc[m][n] = f32x4{0.f, 0.f, 0.f, 0.f};

    auto stage = [&](int t) {
        const int slot = t & 1;
        const size_t kk = (size_t)t << 5;
#pragma unroll
        for (int i = 0; i < 2; ++i) {
            int r0 = wid * 32 + i * 16;
            const _Float16* gah = Ah + (size_t)(brow + r0 + srow) * K + kk + scol;
            __builtin_amdgcn_global_load_lds(
                (const __attribute__((address_space(1))) void*)gah,
                (__attribute__((address_space(3))) void*)&Ahs[slot][r0][0], 16, 0, 0);
            const _Float16* gal = Al + (size_t)(brow + r0 + srow) * K + kk + scol;
            __builtin_amdgcn_global_load_lds(
                (const __attribute__((address_space(1))) void*)gal,
                (__attribute__((address_space(3))) void*)&Als[slot][r0][0], 16, 0, 0);
            const _Float16* gbh = Bh + (size_t)(bcol + r0 + srow) * K + kk + scol;
            __builtin_amdgcn_global_load_lds(
                (const __attribute__((address_space(1))) void*)gbh,
                (__attribute__((address_space(3))) void*)&Bhs[slot][r0][0], 16, 0, 0);
            const _Float16* gbl = Bl + (size_t)(bcol + r0 + srow) * K + kk + scol;
            __builtin_amdgcn_global_load_lds(
                (const __attribute__((address_space(1))) void*)gbl,
                (__attribute__((address_space(3))) void*)&Bls[slot][r0][0], 16, 0, 0);
        }
    };

    stage(0);
    if (nk > 1) stage(1);

    for (int t = 0; t < nk; ++t) {
        // counted wait: tile t done; tile t+1 (8 issues/wave) may stay in flight
        if (t + 1 < nk) asm volatile("s_waitcnt vmcnt(8)" ::: "memory");
        else            asm volatile("s_waitcnt vmcnt(0)" ::: "memory");
        __builtin_amdgcn_sched_barrier(0);
        __builtin_amdgcn_s_barrier();     // tile t staged by all waves
        __builtin_amdgcn_sched_barrier(0);

        const int slot = t & 1;
        f16x8 afh[8], afl[8], bfh[4], bfl[4];
        // ---- phase A: reads for m0-3 + all B ----
#pragma unroll
        for (int m = 0; m < 4; ++m) {
            afh[m] = *(const f16x8*)&Ahs[slot][wm * 128 + m * 16 + fr][fkp];
            afl[m] = *(const f16x8*)&Als[slot][wm * 128 + m * 16 + fr][fkp];
        }
#pragma unroll
        for (int n = 0; n < 4; ++n) {
            bfh[n] = *(const f16x8*)&Bhs[slot][wn * 64 + n * 16 + fr][fkp];
            bfl[n] = *(const f16x8*)&Bls[slot][wn * 64 + n * 16 + fr][fkp];
        }
        __builtin_amdgcn_sched_barrier(0);
        __builtin_amdgcn_s_barrier();
        asm volatile("s_waitcnt lgkmcnt(0)" ::: "memory");
        __builtin_amdgcn_sched_barrier(0);
        __builtin_amdgcn_s_setprio(1);
#pragma unroll
        for (int m = 0; m < 4; ++m)
#pragma unroll
            for (int n = 0; n < 4; ++n) {
                acc[m][n] = __builtin_amdgcn_mfma_f32_16x16x32_f16(afl[m], bfh[n], acc[m][n], 0, 0, 0);
                acc[m][n] = __builtin_amdgcn_mfma_f32_16x16x32_f16(afh[m], bfl[n], acc[m][n], 0, 0, 0);
                acc[m][n] = __builtin_amdgcn_mfma_f32_16x16x32_f16(afh[m], bfh[n], acc[m][n], 0, 0, 0);
            }
        __builtin_amdgcn_s_setprio(0);
        __builtin_amdgcn_sched_barrier(0);
        // ---- phase B: reads for m4-7; then slot-reuse-safe staging of t+2 ----
#pragma unroll
        for (int m = 4; m < 8; ++m) {
            afh[m] = *(const f16x8*)&Ahs[slot][wm * 128 + m * 16 + fr][fkp];
            afl[m] = *(const f16x8*)&Als[slot][wm * 128 + m * 16 + fr][fkp];
        }
        asm volatile("s_waitcnt lgkmcnt(0)" ::: "memory");   // own slot-t reads complete
        __builtin_amdgcn_sched_barrier(0);
        __builtin_amdgcn_s_barrier();     // ALL waves' slot-t reads complete
        __builtin_amdgcn_sched_barrier(0);
        if (t + 2 < nk) stage(t + 2);     // ring-2: overwrite slot t safely
        __builtin_amdgcn_s_setprio(1);
#pragma unroll
        for (int m = 4; m < 8; ++m)
#pragma unroll
            for (int n = 0; n < 4; ++n) {
                acc[m][n] = __builtin_amdgcn_mfma_f32_16x16x32_f16(afl[m], bfh[n], acc[m][n], 0, 0, 0);
                acc[m][n] = __builtin_amdgcn_mfma_f32_16x16x32_f16(afh[m], bfl[n], acc[m][n], 0, 0, 0);
                acc[m][n] = __builtin_amdgcn_mfma_f32_16x16x32_f16(afh[m], bfh[n], acc[m][n], 0, 0, 0);
            }
        __builtin_amdgcn_s_setprio(0);
        __builtin_amdgcn_sched_barrier(0);
    }

    // epilogue
#pragma unroll
    for (int m = 0; m < 8; ++m) {
        int row0 = brow + wm * 128 + m * 16 + crow;
#pragma unroll
        for (int n = 0; n < 4; ++n) {
            int col = bcol + wn * 64 + n * 16 + fr;
            float bv = bias1[col] + bias2[col];
#pragma unroll
            for (int r = 0; r < 4; ++r) {
                float v = acc[m][n][r] + bv;
                C[(size_t)(row0 + r) * N + col] = gelu_f(v);
            }
        }
    }
    (void)M;
}

// ---------------- K2: route logits (fp32, register-blocked; bit-identical k-order) ----
__global__ __launch_bounds__(256) void logits2_k(const float* __restrict__ A,
                                                 const float* __restrict__ Bw,
                                                 const float* __restrict__ rb2,
                                                 const float* __restrict__ taup,
                                                 float* __restrict__ Cl) {
    __shared__ float At[16][68];
    __shared__ float Bs[16][64];
    const int tid = threadIdx.x;
    const int m0 = blockIdx.x * 64;
    const int rg = tid >> 4;
    const int cg = tid & 15;
    const int srow = tid >> 2;
    const int skk  = (tid & 3) * 4;
    const int bk = tid >> 4;
    const int bc = (tid & 15) * 4;

    float acc[4][4] = {};

    for (int k0 = 0; k0 < 1024; k0 += 16) {
        float4 av = *(const float4*)(A + (size_t)(m0 + srow) * 1024 + k0 + skk);
        float4 bv = *(const float4*)(Bw + (size_t)(k0 + bk) * 64 + bc);
        __syncthreads();
        At[skk + 0][srow] = av.x;
        At[skk + 1][srow] = av.y;
        At[skk + 2][srow] = av.z;
        At[skk + 3][srow] = av.w;
        *(float4*)&Bs[bk][bc] = bv;
        __syncthreads();
#pragma unroll
        for (int k = 0; k < 16; ++k) {
            float4 a4 = *(const float4*)&At[k][rg * 4];
            float4 b4 = *(const float4*)&Bs[k][cg * 4];
            float a[4] = {a4.x, a4.y, a4.z, a4.w};
            float b[4] = {b4.x, b4.y, b4.z, b4.w};
#pragma unroll
            for (int i = 0; i < 4; ++i)
#pragma unroll
                for (int j = 0; j < 4; ++j)
                    acc[i][j] = fmaf(a[i], b[j], acc[i][j]);
        }
    }
    float inv = 1.0f / (fabsf(taup[0]) + 0.1f);
#pragma unroll
    for (int i = 0; i < 4; ++i)
#pragma unroll
        for (int j = 0; j < 4; ++j)
            Cl[(size_t)(m0 + rg * 4 + i) * 64 + cg * 4 + j] =
                (acc[i][j] + rb2[cg * 4 + j]) * inv;
}

// ---------------- K3: top-32-of-64 + softmax -> dense alpha ----------------
__global__ __launch_bounds__(256) void topk_k(const float* __restrict__ logits,
                                              float* __restrict__ alpha,
                                              _Float16* __restrict__ alpha16) {
    int wave = threadIdx.x >> 6;
    int lane = threadIdx.x & 63;
    int t = blockIdx.x * 4 + wave;
    float li = logits[(size_t)t * 64 + lane];
    float m = li;
#pragma unroll
    for (int off = 32; off; off >>= 1) m = fmaxf(m, __shfl_xor(m, off, 64));
    int cnt = 0;
    for (int off = 1; off < 64; ++off) {
        int j = (lane + off) & 63;
        float lj = __shfl(li, j, 64);
        cnt += (lj > li) || (lj == li && j < lane);
    }
    float e = (cnt < 32) ? expf(li - m) : 0.0f;
    float s = e;
#pragma unroll
    for (int off = 32; off; off >>= 1) s += __shfl_xor(s, off, 64);
    float a = e / s;
    alpha[(size_t)t * 64 + lane] = a;
    alpha16[(size_t)t * 64 + lane] = (_Float16)a;
}

// ---------------- K4: slot pooling ----------------
__global__ __launch_bounds__(256) void pool_part_k(const float* __restrict__ x,
                                                   const float* __restrict__ alpha,
                                                   float* __restrict__ part,
                                                   float* __restrict__ partw) {
    int bh = blockIdx.x;
    int c = blockIdx.y;
    int b = bh >> 4, h = bh & 15;
    int tid = threadIdx.x;
    int s = tid >> 6, d = tid & 63;
    __shared__ float lx[16][64];
    __shared__ float la[16][4];
    float acc = 0.f, wacc = 0.f;
    const int tchunk = Tt / 8;
    const int t0base = c * tchunk;
    for (int t0 = 0; t0 < tchunk; t0 += 16) {
        int ttr = tid >> 4;
        int ddr = (tid & 15) * 4;
        size_t trow = (size_t)b * Tt + t0base + t0 + ttr;
        float4 xv = *(const float4*)(x + trow * Dd + h * 64 + ddr);
        *(float4*)&lx[ttr][ddr] = xv;
        if (tid < 64) {
            int tt2 = tid >> 2, ss = tid & 3;
            la[tt2][ss] = alpha[((size_t)b * Tt + t0base + t0 + tt2) * 64 + h * 4 + ss];
        }
        __syncthreads();
#pragma unroll
        for (int q = 0; q < 16; ++q) {
            float av = la[q][s];
            acc = fmaf(av, lx[q][d], acc);
            wacc += av;
        }
        __syncthreads();
    }
    part[(((size_t)c * 64 + bh) * 4 + s) * 64 + d] = acc;
    if (d == 0) partw[((size_t)c * 64 + bh) * 4 + s] = wacc;
}

__global__ __launch_bounds__(256) void pool_comb_k(const float* __restrict__ part,
                                                   const float* __restrict__ partw,
                                                   float* __restrict__ slot_in) {
    int bh = blockIdx.x;
    int tid = threadIdx.x;
    int s = tid >> 6, d = tid & 63;
    float acc = 0.f, w = 0.f;
    for (int c = 0; c < 8; ++c) {
        acc += part[(((size_t)c * 64 + bh) * 4 + s) * 64 + d];
        w   += partw[((size_t)c * 64 + bh) * 4 + s];
    }
    slot_in[((size_t)bh * 4 + s) * 64 + d] = acc / (w + 1e-8f);
}

// ---------------- K5: GRU + slot MLP ----------------
__global__ __launch_bounds__(64) void gru_k(const float* __restrict__ slot_in,
                                            const float* __restrict__ slot_init,
                                            const float* __restrict__ gwi,
                                            const float* __restrict__ gwh,
                                            const float* __restrict__ gbi,
                                            const float* __restrict__ gbh,
                                            const float* __restrict__ hpw,
                                            const float* __restrict__ hpb,
                                            const float* __restrict__ ohw,
                                            const float* __restrict__ ohb,
                                            float* __restrict__ S_new) {
    int slot = blockIdx.x;
    int hs = slot & 63;
    int d = threadIdx.x;
    __shared__ float si[64], hp[64], hn[64], g[256];
    si[d] = slot_in[(size_t)slot * 64 + d];
    hp[d] = slot_init[(size_t)hs * 64 + d];
    __syncthreads();
    float gi_r = gbi[d], gi_z = gbi[64 + d], gi_n = gbi[128 + d];
    float gh_r = gbh[d], gh_z = gbh[64 + d], gh_n = gbh[128 + d];
    for (int k = 0; k < 64; ++k) {
        float sv = si[k], hv = hp[k];
        gi_r = fmaf(sv, gwi[(size_t)(d) * 64 + k], gi_r);
        gi_z = fmaf(sv, gwi[(size_t)(64 + d) * 64 + k], gi_z);
        gi_n = fmaf(sv, gwi[(size_t)(128 + d) * 64 + k], gi_n);
        gh_r = fmaf(hv, gwh[(size_t)(d) * 64 + k], gh_r);
        gh_z = fmaf(hv, gwh[(size_t)(64 + d) * 64 + k], gh_z);
        gh_n = fmaf(hv, gwh[(size_t)(128 + d) * 64 + k], gh_n);
    }
    float r = 1.0f / (1.0f + expf(-(gi_r + gh_r)));
    float z = 1.0f / (1.0f + expf(-(gi_z + gh_z)));
    float n = tanhf(gi_n + r * gh_n);
    float hnew = (1.0f - z) * n + z * hp[d];
    hn[d] = hnew;
    __syncthreads();
    float p0 = hpb[d], p1 = hpb[64 + d], p2 = hpb[128 + d], p3 = hpb[192 + d];
    for (int k = 0; k < 64; ++k) {
        float hv = hn[k];
        p0 = fmaf(hv, hpw[(size_t)k * 256 + d], p0);
        p1 = fmaf(hv, hpw[(size_t)k * 256 + 64 + d], p1);
        p2 = fmaf(hv, hpw[(size_t)k * 256 + 128 + d], p2);
        p3 = fmaf(hv, hpw[(size_t)k * 256 + 192 + d], p3);
    }
    g[d] = gelu_f(p0); g[64 + d] = gelu_f(p1); g[128 + d] = gelu_f(p2); g[192 + d] = gelu_f(p3);
    __syncthreads();
    float o = ohb[d];
    for (int j = 0; j < 256; ++j) o = fmaf(g[j], ohw[(size_t)j * 64 + d], o);
    S_new[(size_t)slot * 64 + d] = o;
}

// ---------------- K6: PT[b][j][hs] = sum_d Snew[b,hs,d] * vpw[h*64+d, j]  (f16) -------
__global__ __launch_bounds__(256) void pmat_k(const float* __restrict__ Snew,
                                              const float* __restrict__ vpw,
                                              _Float16* __restrict__ PT) {
    const int h = blockIdx.y;
    const int tid = threadIdx.x;
    const int j = blockIdx.x * 256 + tid;
    __shared__ float S[16][64];
    for (int i = tid; i < 1024; i += 256) {
        int row = i >> 6, d = i & 63;
        int b = row >> 2, s = row & 3;
        S[row][d] = Snew[((size_t)b * 64 + h * 4 + s) * 64 + d];
    }
    __syncthreads();
    float acc[16];
#pragma unroll
    for (int r = 0; r < 16; ++r) acc[r] = 0.f;
    const float* wp = vpw + (size_t)h * 64 * HMm + j;
#pragma unroll 4
    for (int d = 0; d < 64; ++d) {
        float w = wp[(size_t)d * HMm];
#pragma unroll
        for (int r = 0; r < 16; ++r) acc[r] = fmaf(S[r][d], w, acc[r]);
    }
#pragma unroll
    for (int b = 0; b < 4; ++b) {
        f16x4 o;
#pragma unroll
        for (int s = 0; s < 4; ++s) o[s] = (_Float16)acc[b * 4 + s];
        *(f16x4*)&PT[((size_t)b * HMm + j) * 64 + h * 4] = o;
    }
}

// ---------------- K7: transpose + fp32->fp16 convert ----------------
__global__ __launch_bounds__(256) void transp_f16_k(const float* __restrict__ in,
                                                    _Float16* __restrict__ out,
                                                    int K, int N) {
    __shared__ float t[32][33];
    int n0 = blockIdx.x * 32, k0 = blockIdx.y * 32;
    int tx = threadIdx.x & 31, ty = threadIdx.x >> 5;
#pragma unroll
    for (int i = 0; i < 32; i += 8)
        t[ty + i][tx] = in[(size_t)(k0 + ty + i) * N + n0 + tx];
    __syncthreads();
#pragma unroll
    for (int i = 0; i < 32; i += 8)
        out[(size_t)(n0 + ty + i) * K + k0 + tx] = (_Float16)t[tx][ty + i];
}

// ---------------- K9: vgen = gelu(alpha16 @ PT[b]^T + vpb), single launch, K=64 -------
__global__ __launch_bounds__(256) void vgen_k(const _Float16* __restrict__ alpha16,
                                              const _Float16* __restrict__ PT,
                                              const float* __restrict__ vpb,
                                              _Float16* __restrict__ v1a,
                                              _Float16* __restrict__ v1b) {
    __shared__ __align__(16) _Float16 As[128][64];
    __shared__ __align__(16) _Float16 Bs[128][64];
    const int tid = threadIdx.x;
    const int wid = tid >> 6;
    const int lane = tid & 63;
    const int swz = xcd_swz(gridDim.x * gridDim.y);
    const int brow = (swz / gridDim.x) * 128;
    const int bcol = (swz % gridDim.x) * 128;
    const int b = brow >> 12;
    const _Float16* Bt = PT + (size_t)b * HMm * 64;
    _Float16* Cb = (brow < 8192) ? v1a : v1b;
    const int rowoff = (brow < 8192) ? brow : brow - 8192;
    const int wr = (wid >> 1) * 64;
    const int wc = (wid & 1) * 64;

    f32x4 acc[4][4];
#pragma unroll
    for (int m = 0; m < 4; ++m)
#pragma unroll
        for (int n = 0; n < 4; ++n)
            acc[m][n] = f32x4{0.f, 0.f, 0.f, 0.f};

    const int lrow = lane >> 3;
    const int lcol = (lane & 7) * 8;
    const int fr = lane & 15;
    const int fk = (lane >> 4) * 8;

#pragma unroll
    for (int i = 0; i < 4; ++i) {
        int seg = wid * 4 + i;
        const _Float16* g = alpha16 + (size_t)(brow + seg * 8 + lrow) * 64 + lcol;
        __builtin_amdgcn_global_load_lds(
            (const __attribute__((address_space(1))) void*)g,
            (__attribute__((address_space(3))) void*)&As[seg * 8][0], 16, 0, 0);
    }
#pragma unroll
    for (int i = 0; i < 4; ++i) {
        int seg = wid * 4 + i;
        const _Float16* g = Bt + (size_t)(bcol + seg * 8 + lrow) * 64 + lcol;
        __builtin_amdgcn_global_load_lds(
            (const __attribute__((address_space(1))) void*)g,
            (__attribute__((address_space(3))) void*)&Bs[seg * 8][0], 16, 0, 0);
    }
    __syncthreads();
#pragma unroll
    for (int kb = 0; kb < 2; ++kb) {
        f16x8 af[4], bf[4];
#pragma unroll
        for (int m = 0; m < 4; ++m)
            af[m] = *(const f16x8*)&As[wr + m * 16 + fr][kb * 32 + fk];
#pragma unroll
        for (int n = 0; n < 4; ++n)
            bf[n] = *(const f16x8*)&Bs[wc + n * 16 + fr][kb * 32 + fk];
#pragma unroll
        for (int m = 0; m < 4; ++m)
#pragma unroll
            for (int n = 0; n < 4; ++n)
                acc[m][n] = __builtin_amdgcn_mfma_f32_16x16x32_f16(af[m], bf[n], acc[m][n], 0, 0, 0);
    }

    const int crow = (lane >> 4) * 4;
#pragma unroll
    for (int m = 0; m < 4; ++m) {
        int row0 = rowoff + wr + m * 16 + crow;
#pragma unroll
        for (int n = 0; n < 4; ++n) {
            int col = bcol + wc + n * 16 + fr;
            float bv = vpb[col];
#pragma unroll
            for (int r = 0; r < 4; ++r) {
                float v = acc[m][n][r] + bv;
                Cb[(size_t)(row0 + r) * HMm + col] = (_Float16)gelu_f(v);
            }
        }
    }
}

// ---------------- K11: 256x256 deep-pipelined GEMM, 2-phase interleave per K-32 tile.
template <int OUT_F16>
__global__ __launch_bounds__(512, 2) void hgemm8_k(const _Float16* __restrict__ A0,
                                                   const _Float16* __restrict__ A1,
                                                   int splitrow,
                                                   const _Float16* __restrict__ Bt,
                                                   const float* __restrict__ bias,
                                                   void* __restrict__ Cv,
                                                   int M, int N, int K) {
    __shared__ __align__(16) _Float16 As[4][256][32];   // 64 KB
    __shared__ __align__(16) _Float16 Bs[4][256][32];   // 64 KB
    const int tid = threadIdx.x;
    const int wid = tid >> 6;            // 0..7
    const int lane = tid & 63;
    const int swz = xcd_swz(gridDim.x * gridDim.y);
    const int brow = (swz / gridDim.x) * 256;
    const int bcol = (swz % gridDim.x) * 256;
    const _Float16* Ab = (brow < splitrow) ? A0 : A1;
    const int arow0 = brow - ((brow < splitrow) ? 0 : splitrow);
    const int wm = wid >> 2;
    const int wn = wid & 3;

    const int srow = lane >> 2;
    const int scol = ((lane & 3) ^ ((lane >> 3) & 3)) * 8;
    const int fr = lane & 15;
    const int fkp = (((lane >> 4) ^ ((lane >> 1) & 3))) * 8;
    const int crow = (lane >> 4) * 4;

    const int nk = K >> 5;

    f32x4 acc[8][4];
#pragma unroll
    for (int m = 0; m < 8; ++m)
#pragma unroll
        for (int n = 0; n < 4; ++n)
            acc[m][n] = f32x4{0.f, 0.f, 0.f, 0.f};

    auto stage = [&](int t) {
        const int slot = t & 3;
        const size_t kk = (size_t)t << 5;
#pragma unroll
        for (int i = 0; i < 2; ++i) {
            const _Float16* g = Ab + (size_t)(arow0 + wid * 32 + i * 16 + srow) * K + kk + scol;
            __builtin_amdgcn_global_load_lds(
                (const __attribute__((address_space(1))) void*)g,
                (__attribute__((address_space(3))) void*)&As[slot][wid * 32 + i * 16][0], 16, 0, 0);
        }
#pragma unroll
        for (int i = 0; i < 2; ++i) {
            const _Float16* g = Bt + (size_t)(bcol + wid * 32 + i * 16 + srow) * K + kk + scol;
            __builtin_amdgcn_global_load_lds(
                (const __attribute__((address_space(1))) void*)g,
                (__attribute__((address_space(3))) void*)&Bs[slot][wid * 32 + i * 16][0], 16, 0, 0);
        }
    };

    stage(0);
    if (nk > 1) stage(1);
    if (nk > 2) stage(2);

    for (int t = 0; t < nk; ++t) {
        if (t + 2 < nk)      asm volatile("s_waitcnt vmcnt(8)" ::: "memory");
        else if (t + 1 < nk) asm volatile("s_waitcnt vmcnt(4)" ::: "memory");
        else                 asm volatile("s_waitcnt vmcnt(0)" ::: "memory");
        __builtin_amdgcn_sched_barrier(0);
        __builtin_amdgcn_s_barrier();
        __builtin_amdgcn_sched_barrier(0);

        const int slot = t & 3;
        f16x8 af[8], bf[4];
#pragma unroll
        for (int m = 0; m < 4; ++m)
            af[m] = *(const f16x8*)&As[slot][wm * 128 + m * 16 + fr][fkp];
#pragma unroll
        for (int n = 0; n < 4; ++n)
            bf[n] = *(const f16x8*)&Bs[slot][wn * 64 + n * 16 + fr][fkp];
        if (t + 3 < nk) stage(t + 3);
        __builtin_amdgcn_sched_barrier(0);
        __builtin_amdgcn_s_barrier();
        asm volatile("s_waitcnt lgkmcnt(0)" ::: "memory");
        __builtin_amdgcn_sched_barrier(0);
        __builtin_amdgcn_s_setprio(1);
#pragma unroll
        for (int m = 0; m < 4; ++m)
#pragma unroll
            for (int n = 0; n < 4; ++n)
                acc[m][n] = __builtin_amdgcn_mfma_f32_16x16x32_f16(af[m], bf[n], acc[m][n], 0, 0, 0);
        __builtin_amdgcn_s_setprio(0);
        __builtin_amdgcn_sched_barrier(0);
#pragma unroll
        for (int m = 4; m < 8; ++m)
            af[m] = *(const f16x8*)&As[slot][wm * 128 + m * 16 + fr][fkp];
        __builtin_amdgcn_sched_barrier(0);
        __builtin_amdgcn_s_barrier();
        asm volatile("s_waitcnt lgkmcnt(0)" ::: "memory");
        __builtin_amdgcn_sched_barrier(0);
        __builtin_amdgcn_s_setprio(1);
#pragma unroll
        for (int m = 4; m < 8; ++m)
#pragma unroll
            for (int n = 0; n < 4; ++n)
                acc[m][n] = __builtin_amdgcn_mfma_f32_16x16x32_f16(af[m], bf[n], acc[m][n], 0, 0, 0);
        __builtin_amdgcn_s_setprio(0);
        __builtin_amdgcn_sched_barrier(0);
    }

#pragma unroll
    for (int m = 0; m < 8; ++m) {
        int row0 = brow + wm * 128 + m * 16 + crow;
#pragma unroll
        for (int n = 0; n < 4; ++n) {
            int col = bcol + wn * 64 + n * 16 + fr;
            float bv = bias[col];
#pragma unroll
            for (int r = 0; r < 4; ++r) {
                float v = acc[m][n][r] + bv;
                size_t idx = (size_t)(row0 + r) * N + col;
                if (OUT_F16) ((_Float16*)Cv)[idx] = (_Float16)v;
                else ((float*)Cv)[idx] = v;
            }
        }
    }
    (void)M;
}

extern "C" void kernel_launch(void* const* d_in, const int* in_sizes, int n_in,
                              void* d_out, int out_size, void* d_ws, size_t ws_size,
                              hipStream_t stream) {
    const float* x         = (const float*)d_in[0];
    const float* slot_init = (const float*)d_in[1];
    const float* rw1       = (const float*)d_in[2];
    const float* rb1       = (const float*)d_in[3];
    const float* rw2       = (const float*)d_in[4];
    const float* rb2       = (const float*)d_in[5];
    const float* gwi       = (const float*)d_in[6];
    const float* gwh       = (const float*)d_in[7];
    const float* gbi       = (const float*)d_in[8];
    const float* gbh       = (const float*)d_in[9];
    const float* hpw       = (const float*)d_in[10];
    const float* hpb       = (const float*)d_in[11];
    const float* ohw       = (const float*)d_in[12];
    const float* ohb       = (const float*)d_in[13];
    const float* vpw       = (const float*)d_in[14];
    const float* vpb       = (const float*)d_in[15];
    const float* vow       = (const float*)d_in[16];
    const float* vob       = (const float*)d_in[17];
    const float* opw       = (const float*)d_in[18];
    const float* opb       = (const float*)d_in[19];
    const float* tau       = (const float*)d_in[20];
    float* out = (float*)d_out;

    float* ws = (float*)d_ws;
    size_t off = 0;
    auto alloc = [&](size_t nfloats) { float* p = ws + off; off += (nfloats + 63) & ~(size_t)63; return p; };

    float* cb     = alloc(1024);
    float* cbp    = alloc(16 * 1024);
    float* h1     = alloc((size_t)MTOK * 1024);            // fp32; dead after logits:
    _Float16* v1a = (_Float16*)h1;                          //   v1 rows 0..8191 [8192,4096] f16
    float* logits = alloc((size_t)MTOK * 64);
    float* alpha  = alloc((size_t)MTOK * 64);
    _Float16* alpha16 = (_Float16*)alloc((size_t)MTOK * 64 / 2);
    float* slotin = alloc(256 * 64);
    float* part   = alloc((size_t)8 * 64 * 4 * 64);
    float* partw  = alloc(8 * 64 * 4);
    float* Snew   = alloc(256 * 64);
    _Float16* PT   = (_Float16*)alloc((size_t)Bb * HMm * 64 / 2);  // [4,4096,64] f16
    _Float16* vowT = (_Float16*)alloc((size_t)Dd * HMm / 2);       // [1024,4096] f16
    _Float16* opwT = (_Float16*)alloc((size_t)Dd * Dd / 2);        // [1024,1024] f16
    _Float16* v2f16 = (_Float16*)alloc((size_t)MTOK * Dd / 2);     // [16384,1024] f16
    _Float16* w1hiT = (_Float16*)alloc((size_t)Dd * Dd / 2);
    _Float16* w1loT = (_Float16*)alloc((size_t)Dd * Dd / 2);

    // d_out scratch: xhi/xlo before hgemm4p; v1 rows 8192..16383 after vgen.
    _Float16* xhi = (_Float16*)d_out;
    _Float16* xlo = xhi + (size_t)MTOK * Dd;
    _Float16* v1b = (_Float16*)d_out;

    // ---- routing: pre-split x + deep-pipelined 4-plane split-fp16 GEMM + fp32 logits --
    cb_part_k<<<dim3(4, 16), 256, 0, stream>>>(slot_init, rw1, cbp);
    cb_comb_k<<<4, 256, 0, stream>>>(cbp, cb);
    wsplitT_k<<<dim3(Dd / 32, Dd / 32), 256, 0, stream>>>(rw1, w1hiT, w1loT);
    xsplit_k<<<(MTOK * Dd) / (256 * 8), 256, 0, stream>>>(x, xhi, xlo);
    hgemm4p_k<<<dim3(Dd / 256, MTOK / 256), 512, 0, stream>>>(
        xhi, xlo, w1hiT, w1loT, rb1, cb, h1, MTOK, Dd, Dd);
    logits2_k<<<MTOK / 64, 256, 0, stream>>>(h1, rw2, rb2, tau, logits);
    topk_k<<<MTOK / 4, 256, 0, stream>>>(logits, alpha, alpha16);

    // ---- weight transposes (fp32 -> fp16 [N,K]) ----
    transp_f16_k<<<dim3(Dd / 32, HMm / 32), 256, 0, stream>>>(vow, vowT, HMm, Dd);
    transp_f16_k<<<dim3(Dd / 32, Dd / 32), 256, 0, stream>>>(opw, opwT, Dd, Dd);

    // ---- slot pooling + GRU + slot MLP ----
    pool_part_k<<<dim3(64, 8), 256, 0, stream>>>(x, alpha, part, partw);
    pool_comb_k<<<64, 256, 0, stream>>>(part, partw, slotin);
    gru_k<<<256, 64, 0, stream>>>(slotin, slot_init, gwi, gwh, gbi, gbh,
                                  hpw, hpb, ohw, ohb, Snew);

    // ---- P[b] = S_emb[b] @ vpw (stored transposed f16 [b][j][hs]) ----
    pmat_k<<<dim3(HMm / 256, Hh), 256, 0, stream>>>(Snew, vpw, PT);

    // ---- value MLP: vgen (K=64), then deep-pipelined 256^2 GEMM2 + GEMM3 ----
    vgen_k<<<dim3(HMm / 128, MTOK / 128), 256, 0, stream>>>(
        alpha16, PT, vpb, v1a, v1b);
    hgemm8_k<1><<<dim3(Dd / 256, MTOK / 256), 512, 0, stream>>>(
        v1a, v1b, 8192, vowT, vob, v2f16, MTOK, Dd, HMm);
    hgemm8_k<0><<<dim3(Dd / 256, MTOK / 256), 512, 0, stream>>>(
        v2f16, v2f16, MTOK, opwT, opb, out, MTOK, Dd, Dd);

    (void)in_sizes; (void)n_in; (void)out_size; (void)ws_size;
}

// Round 11
// 521.295 us; speedup vs baseline: 1.6335x; 1.0469x over previous
//
#include <hip/hip_runtime.h>
#include <cstddef>
#include <cstdint>

// Problem constants
#define Bb 4
#define Tt 4096
#define Dd 1024
#define Hh 16
#define HDd 64
#define NSs 64
#define SPHh 4
#define HMm 4096
#define MTOK (Bb*Tt)   // 16384

typedef _Float16 f16x8 __attribute__((ext_vector_type(8)));
typedef _Float16 f16x4 __attribute__((ext_vector_type(4)));
typedef float f32x4 __attribute__((ext_vector_type(4)));

__device__ __forceinline__ float gelu_f(float x) {
    return 0.5f * x * (1.0f + erff(x * 0.70710678118654752440f));
}

// XCD-chunked bijective block swizzle (requires nwg % 8 == 0; all launches comply)
__device__ __forceinline__ int xcd_swz(int nwg) {
    int orig = blockIdx.y * gridDim.x + blockIdx.x;
    int cpx = nwg >> 3;
    return (orig & 7) * cpx + (orig >> 3);
}

// ---------------- K0: cb partials ----------------
__global__ __launch_bounds__(256) void cb_part_k(const float* __restrict__ slot_init,
                                                 const float* __restrict__ rw1,
                                                 float* __restrict__ cbp) {
    __shared__ float sm[64];
    int tid = threadIdx.x;
    if (tid < 64) {
        float s = 0.f;
        for (int i = 0; i < 64; ++i) s += slot_init[i * 64 + tid];
        sm[tid] = s * (1.0f / 64.0f);
    }
    __syncthreads();
    int j = blockIdx.x * 256 + tid;
    int k0 = blockIdx.y * 64;
    float acc = 0.f;
#pragma unroll 8
    for (int k = 0; k < 64; ++k)
        acc = fmaf(sm[k], rw1[(size_t)(1024 + k0 + k) * 1024 + j], acc);
    cbp[(size_t)blockIdx.y * 1024 + j] = acc;
}

__global__ __launch_bounds__(256) void cb_comb_k(const float* __restrict__ cbp,
                                                 float* __restrict__ cb) {
    int j = blockIdx.x * 256 + threadIdx.x;
    float acc = 0.f;
#pragma unroll
    for (int c = 0; c < 16; ++c) acc += cbp[(size_t)c * 1024 + j];
    cb[j] = acc;
}

// ---------------- K1: rw1[:1024] -> transposed split-f16 planes ----------------
__global__ __launch_bounds__(256) void wsplitT_k(const float* __restrict__ rw1,
                                                 _Float16* __restrict__ whiT,
                                                 _Float16* __restrict__ wloT) {
    __shared__ float t[32][33];
    int n0 = blockIdx.x * 32, k0 = blockIdx.y * 32;
    int tx = threadIdx.x & 31, ty = threadIdx.x >> 5;
#pragma unroll
    for (int i = 0; i < 32; i += 8)
        t[ty + i][tx] = rw1[(size_t)(k0 + ty + i) * 1024 + n0 + tx];
    __syncthreads();
#pragma unroll
    for (int i = 0; i < 32; i += 8) {
        float v = t[tx][ty + i];
        _Float16 h = (_Float16)v;
        _Float16 l = (_Float16)(v - (float)h);
        whiT[(size_t)(n0 + ty + i) * 1024 + k0 + tx] = h;
        wloT[(size_t)(n0 + ty + i) * 1024 + k0 + tx] = l;
    }
}

// ---------------- K1a: x -> split f16 hi/lo planes ----------------
__global__ __launch_bounds__(256) void xsplit_k(const float* __restrict__ x,
                                                _Float16* __restrict__ xhi,
                                                _Float16* __restrict__ xlo) {
    size_t i = ((size_t)blockIdx.x * 256 + threadIdx.x) * 8;
    float4 a = *(const float4*)(x + i);
    float4 b = *(const float4*)(x + i + 4);
    float v[8] = {a.x, a.y, a.z, a.w, b.x, b.y, b.z, b.w};
    f16x8 h, l;
#pragma unroll
    for (int j = 0; j < 8; ++j) {
        _Float16 hv = (_Float16)v[j];
        h[j] = hv;
        l[j] = (_Float16)(v[j] - (float)hv);
    }
    *(f16x8*)(xhi + i) = h;
    *(f16x8*)(xlo + i) = l;
}

// ---------------- K1b: deep-pipelined split-fp16 routing GEMM ----------------
// 256x256 tile, BK=32, ring-2 (4 planes x 2 slots = 128KB), counted vmcnt, 2-phase.
__global__ __launch_bounds__(512, 2) void hgemm4p_k(const _Float16* __restrict__ Ah,
                                                    const _Float16* __restrict__ Al,
                                                    const _Float16* __restrict__ Bh,
                                                    const _Float16* __restrict__ Bl,
                                                    const float* __restrict__ bias1,
                                                    const float* __restrict__ bias2,
                                                    float* __restrict__ C,
                                                    int M, int N, int K) {
    __shared__ __align__(16) _Float16 Ahs[2][256][32];
    __shared__ __align__(16) _Float16 Als[2][256][32];
    __shared__ __align__(16) _Float16 Bhs[2][256][32];
    __shared__ __align__(16) _Float16 Bls[2][256][32];
    const int tid = threadIdx.x;
    const int wid = tid >> 6;            // 0..7
    const int lane = tid & 63;
    const int swz = xcd_swz(gridDim.x * gridDim.y);
    const int brow = (swz / gridDim.x) * 256;
    const int bcol = (swz % gridDim.x) * 256;
    const int wm = wid >> 2;             // 0..1
    const int wn = wid & 3;              // 0..3

    const int srow = lane >> 2;
    const int scol = ((lane & 3) ^ ((lane >> 3) & 3)) * 8;
    const int fr = lane & 15;
    const int fkp = (((lane >> 4) ^ ((lane >> 1) & 3))) * 8;
    const int crow = (lane >> 4) * 4;

    const int nk = K >> 5;   // 32

    f32x4 acc[8][4];
#pragma unroll
    for (int m = 0; m < 8; ++m)
#pragma unroll
        for (int n = 0; n < 4; ++n)
            acc[m][n] = f32x4{0.f, 0.f, 0.f, 0.f};

    auto stage = [&](int t) {
        const int slot = t & 1;
        const size_t kk = (size_t)t << 5;
#pragma unroll
        for (int i = 0; i < 2; ++i) {
            int r0 = wid * 32 + i * 16;
            const _Float16* gah = Ah + (size_t)(brow + r0 + srow) * K + kk + scol;
            __builtin_amdgcn_global_load_lds(
                (const __attribute__((address_space(1))) void*)gah,
                (__attribute__((address_space(3))) void*)&Ahs[slot][r0][0], 16, 0, 0);
            const _Float16* gal = Al + (size_t)(brow + r0 + srow) * K + kk + scol;
            __builtin_amdgcn_global_load_lds(
                (const __attribute__((address_space(1))) void*)gal,
                (__attribute__((address_space(3))) void*)&Als[slot][r0][0], 16, 0, 0);
            const _Float16* gbh = Bh + (size_t)(bcol + r0 + srow) * K + kk + scol;
            __builtin_amdgcn_global_load_lds(
                (const __attribute__((address_space(1))) void*)gbh,
                (__attribute__((address_space(3))) void*)&Bhs[slot][r0][0], 16, 0, 0);
            const _Float16* gbl = Bl + (size_t)(bcol + r0 + srow) * K + kk + scol;
            __builtin_amdgcn_global_load_lds(
                (const __attribute__((address_space(1))) void*)gbl,
                (__attribute__((address_space(3))) void*)&Bls[slot][r0][0], 16, 0, 0);
        }
    };

    stage(0);
    if (nk > 1) stage(1);

    for (int t = 0; t < nk; ++t) {
        if (t + 1 < nk) asm volatile("s_waitcnt vmcnt(8)" ::: "memory");
        else            asm volatile("s_waitcnt vmcnt(0)" ::: "memory");
        __builtin_amdgcn_sched_barrier(0);
        __builtin_amdgcn_s_barrier();
        __builtin_amdgcn_sched_barrier(0);

        const int slot = t & 1;
        f16x8 afh[8], afl[8], bfh[4], bfl[4];
#pragma unroll
        for (int m = 0; m < 4; ++m) {
            afh[m] = *(const f16x8*)&Ahs[slot][wm * 128 + m * 16 + fr][fkp];
            afl[m] = *(const f16x8*)&Als[slot][wm * 128 + m * 16 + fr][fkp];
        }
#pragma unroll
        for (int n = 0; n < 4; ++n) {
            bfh[n] = *(const f16x8*)&Bhs[slot][wn * 64 + n * 16 + fr][fkp];
            bfl[n] = *(const f16x8*)&Bls[slot][wn * 64 + n * 16 + fr][fkp];
        }
        __builtin_amdgcn_sched_barrier(0);
        __builtin_amdgcn_s_barrier();
        asm volatile("s_waitcnt lgkmcnt(0)" ::: "memory");
        __builtin_amdgcn_sched_barrier(0);
        __builtin_amdgcn_s_setprio(1);
#pragma unroll
        for (int m = 0; m < 4; ++m)
#pragma unroll
            for (int n = 0; n < 4; ++n) {
                acc[m][n] = __builtin_amdgcn_mfma_f32_16x16x32_f16(afl[m], bfh[n], acc[m][n], 0, 0, 0);
                acc[m][n] = __builtin_amdgcn_mfma_f32_16x16x32_f16(afh[m], bfl[n], acc[m][n], 0, 0, 0);
                acc[m][n] = __builtin_amdgcn_mfma_f32_16x16x32_f16(afh[m], bfh[n], acc[m][n], 0, 0, 0);
            }
        __builtin_amdgcn_s_setprio(0);
        __builtin_amdgcn_sched_barrier(0);
#pragma unroll
        for (int m = 4; m < 8; ++m) {
            afh[m] = *(const f16x8*)&Ahs[slot][wm * 128 + m * 16 + fr][fkp];
            afl[m] = *(const f16x8*)&Als[slot][wm * 128 + m * 16 + fr][fkp];
        }
        asm volatile("s_waitcnt lgkmcnt(0)" ::: "memory");
        __builtin_amdgcn_sched_barrier(0);
        __builtin_amdgcn_s_barrier();
        __builtin_amdgcn_sched_barrier(0);
        if (t + 2 < nk) stage(t + 2);
        __builtin_amdgcn_s_setprio(1);
#pragma unroll
        for (int m = 4; m < 8; ++m)
#pragma unroll
            for (int n = 0; n < 4; ++n) {
                acc[m][n] = __builtin_amdgcn_mfma_f32_16x16x32_f16(afl[m], bfh[n], acc[m][n], 0, 0, 0);
                acc[m][n] = __builtin_amdgcn_mfma_f32_16x16x32_f16(afh[m], bfl[n], acc[m][n], 0, 0, 0);
                acc[m][n] = __builtin_amdgcn_mfma_f32_16x16x32_f16(afh[m], bfh[n], acc[m][n], 0, 0, 0);
            }
        __builtin_amdgcn_s_setprio(0);
        __builtin_amdgcn_sched_barrier(0);
    }

#pragma unroll
    for (int m = 0; m < 8; ++m) {
        int row0 = brow + wm * 128 + m * 16 + crow;
#pragma unroll
        for (int n = 0; n < 4; ++n) {
            int col = bcol + wn * 64 + n * 16 + fr;
            float bv = bias1[col] + bias2[col];
#pragma unroll
            for (int r = 0; r < 4; ++r) {
                float v = acc[m][n][r] + bv;
                C[(size_t)(row0 + r) * N + col] = gelu_f(v);
            }
        }
    }
    (void)M;
}

// ---------------- K2: route logits (fp32, register-blocked; bit-identical k-order) ----
__global__ __launch_bounds__(256) void logits2_k(const float* __restrict__ A,
                                                 const float* __restrict__ Bw,
                                                 const float* __restrict__ rb2,
                                                 const float* __restrict__ taup,
                                                 float* __restrict__ Cl) {
    __shared__ float At[16][68];
    __shared__ float Bs[16][64];
    const int tid = threadIdx.x;
    const int m0 = blockIdx.x * 64;
    const int rg = tid >> 4;
    const int cg = tid & 15;
    const int srow = tid >> 2;
    const int skk  = (tid & 3) * 4;
    const int bk = tid >> 4;
    const int bc = (tid & 15) * 4;

    float acc[4][4] = {};

    for (int k0 = 0; k0 < 1024; k0 += 16) {
        float4 av = *(const float4*)(A + (size_t)(m0 + srow) * 1024 + k0 + skk);
        float4 bv = *(const float4*)(Bw + (size_t)(k0 + bk) * 64 + bc);
        __syncthreads();
        At[skk + 0][srow] = av.x;
        At[skk + 1][srow] = av.y;
        At[skk + 2][srow] = av.z;
        At[skk + 3][srow] = av.w;
        *(float4*)&Bs[bk][bc] = bv;
        __syncthreads();
#pragma unroll
        for (int k = 0; k < 16; ++k) {
            float4 a4 = *(const float4*)&At[k][rg * 4];
            float4 b4 = *(const float4*)&Bs[k][cg * 4];
            float a[4] = {a4.x, a4.y, a4.z, a4.w};
            float b[4] = {b4.x, b4.y, b4.z, b4.w};
#pragma unroll
            for (int i = 0; i < 4; ++i)
#pragma unroll
                for (int j = 0; j < 4; ++j)
                    acc[i][j] = fmaf(a[i], b[j], acc[i][j]);
        }
    }
    float inv = 1.0f / (fabsf(taup[0]) + 0.1f);
#pragma unroll
    for (int i = 0; i < 4; ++i)
#pragma unroll
        for (int j = 0; j < 4; ++j)
            Cl[(size_t)(m0 + rg * 4 + i) * 64 + cg * 4 + j] =
                (acc[i][j] + rb2[cg * 4 + j]) * inv;
}

// ---------------- K3: top-32-of-64 + softmax -> dense alpha ----------------
__global__ __launch_bounds__(256) void topk_k(const float* __restrict__ logits,
                                              float* __restrict__ alpha,
                                              _Float16* __restrict__ alpha16) {
    int wave = threadIdx.x >> 6;
    int lane = threadIdx.x & 63;
    int t = blockIdx.x * 4 + wave;
    float li = logits[(size_t)t * 64 + lane];
    float m = li;
#pragma unroll
    for (int off = 32; off; off >>= 1) m = fmaxf(m, __shfl_xor(m, off, 64));
    int cnt = 0;
    for (int off = 1; off < 64; ++off) {
        int j = (lane + off) & 63;
        float lj = __shfl(li, j, 64);
        cnt += (lj > li) || (lj == li && j < lane);
    }
    float e = (cnt < 32) ? expf(li - m) : 0.0f;
    float s = e;
#pragma unroll
    for (int off = 32; off; off >>= 1) s += __shfl_xor(s, off, 64);
    float a = e / s;
    alpha[(size_t)t * 64 + lane] = a;
    alpha16[(size_t)t * 64 + lane] = (_Float16)a;
}

// ---------------- K4: slot pooling ----------------
__global__ __launch_bounds__(256) void pool_part_k(const float* __restrict__ x,
                                                   const float* __restrict__ alpha,
                                                   float* __restrict__ part,
                                                   float* __restrict__ partw) {
    int bh = blockIdx.x;
    int c = blockIdx.y;
    int b = bh >> 4, h = bh & 15;
    int tid = threadIdx.x;
    int s = tid >> 6, d = tid & 63;
    __shared__ float lx[16][64];
    __shared__ float la[16][4];
    float acc = 0.f, wacc = 0.f;
    const int tchunk = Tt / 8;
    const int t0base = c * tchunk;
    for (int t0 = 0; t0 < tchunk; t0 += 16) {
        int ttr = tid >> 4;
        int ddr = (tid & 15) * 4;
        size_t trow = (size_t)b * Tt + t0base + t0 + ttr;
        float4 xv = *(const float4*)(x + trow * Dd + h * 64 + ddr);
        *(float4*)&lx[ttr][ddr] = xv;
        if (tid < 64) {
            int tt2 = tid >> 2, ss = tid & 3;
            la[tt2][ss] = alpha[((size_t)b * Tt + t0base + t0 + tt2) * 64 + h * 4 + ss];
        }
        __syncthreads();
#pragma unroll
        for (int q = 0; q < 16; ++q) {
            float av = la[q][s];
            acc = fmaf(av, lx[q][d], acc);
            wacc += av;
        }
        __syncthreads();
    }
    part[(((size_t)c * 64 + bh) * 4 + s) * 64 + d] = acc;
    if (d == 0) partw[((size_t)c * 64 + bh) * 4 + s] = wacc;
}

__global__ __launch_bounds__(256) void pool_comb_k(const float* __restrict__ part,
                                                   const float* __restrict__ partw,
                                                   float* __restrict__ slot_in) {
    int bh = blockIdx.x;
    int tid = threadIdx.x;
    int s = tid >> 6, d = tid & 63;
    float acc = 0.f, w = 0.f;
    for (int c = 0; c < 8; ++c) {
        acc += part[(((size_t)c * 64 + bh) * 4 + s) * 64 + d];
        w   += partw[((size_t)c * 64 + bh) * 4 + s];
    }
    slot_in[((size_t)bh * 4 + s) * 64 + d] = acc / (w + 1e-8f);
}

// ---------------- K5: GRU + slot MLP ----------------
__global__ __launch_bounds__(64) void gru_k(const float* __restrict__ slot_in,
                                            const float* __restrict__ slot_init,
                                            const float* __restrict__ gwi,
                                            const float* __restrict__ gwh,
                                            const float* __restrict__ gbi,
                                            const float* __restrict__ gbh,
                                            const float* __restrict__ hpw,
                                            const float* __restrict__ hpb,
                                            const float* __restrict__ ohw,
                                            const float* __restrict__ ohb,
                                            float* __restrict__ S_new) {
    int slot = blockIdx.x;
    int hs = slot & 63;
    int d = threadIdx.x;
    __shared__ float si[64], hp[64], hn[64], g[256];
    si[d] = slot_in[(size_t)slot * 64 + d];
    hp[d] = slot_init[(size_t)hs * 64 + d];
    __syncthreads();
    float gi_r = gbi[d], gi_z = gbi[64 + d], gi_n = gbi[128 + d];
    float gh_r = gbh[d], gh_z = gbh[64 + d], gh_n = gbh[128 + d];
    for (int k = 0; k < 64; ++k) {
        float sv = si[k], hv = hp[k];
        gi_r = fmaf(sv, gwi[(size_t)(d) * 64 + k], gi_r);
        gi_z = fmaf(sv, gwi[(size_t)(64 + d) * 64 + k], gi_z);
        gi_n = fmaf(sv, gwi[(size_t)(128 + d) * 64 + k], gi_n);
        gh_r = fmaf(hv, gwh[(size_t)(d) * 64 + k], gh_r);
        gh_z = fmaf(hv, gwh[(size_t)(64 + d) * 64 + k], gh_z);
        gh_n = fmaf(hv, gwh[(size_t)(128 + d) * 64 + k], gh_n);
    }
    float r = 1.0f / (1.0f + expf(-(gi_r + gh_r)));
    float z = 1.0f / (1.0f + expf(-(gi_z + gh_z)));
    float n = tanhf(gi_n + r * gh_n);
    float hnew = (1.0f - z) * n + z * hp[d];
    hn[d] = hnew;
    __syncthreads();
    float p0 = hpb[d], p1 = hpb[64 + d], p2 = hpb[128 + d], p3 = hpb[192 + d];
    for (int k = 0; k < 64; ++k) {
        float hv = hn[k];
        p0 = fmaf(hv, hpw[(size_t)k * 256 + d], p0);
        p1 = fmaf(hv, hpw[(size_t)k * 256 + 64 + d], p1);
        p2 = fmaf(hv, hpw[(size_t)k * 256 + 128 + d], p2);
        p3 = fmaf(hv, hpw[(size_t)k * 256 + 192 + d], p3);
    }
    g[d] = gelu_f(p0); g[64 + d] = gelu_f(p1); g[128 + d] = gelu_f(p2); g[192 + d] = gelu_f(p3);
    __syncthreads();
    float o = ohb[d];
    for (int j = 0; j < 256; ++j) o = fmaf(g[j], ohw[(size_t)j * 64 + d], o);
    S_new[(size_t)slot * 64 + d] = o;
}

// ---------------- K6: PT[b][j][hs] = sum_d Snew[b,hs,d] * vpw[h*64+d, j]  (f16) -------
__global__ __launch_bounds__(256) void pmat_k(const float* __restrict__ Snew,
                                              const float* __restrict__ vpw,
                                              _Float16* __restrict__ PT) {
    const int h = blockIdx.y;
    const int tid = threadIdx.x;
    const int j = blockIdx.x * 256 + tid;
    __shared__ float S[16][64];
    for (int i = tid; i < 1024; i += 256) {
        int row = i >> 6, d = i & 63;
        int b = row >> 2, s = row & 3;
        S[row][d] = Snew[((size_t)b * 64 + h * 4 + s) * 64 + d];
    }
    __syncthreads();
    float acc[16];
#pragma unroll
    for (int r = 0; r < 16; ++r) acc[r] = 0.f;
    const float* wp = vpw + (size_t)h * 64 * HMm + j;
#pragma unroll 4
    for (int d = 0; d < 64; ++d) {
        float w = wp[(size_t)d * HMm];
#pragma unroll
        for (int r = 0; r < 16; ++r) acc[r] = fmaf(S[r][d], w, acc[r]);
    }
#pragma unroll
    for (int b = 0; b < 4; ++b) {
        f16x4 o;
#pragma unroll
        for (int s = 0; s < 4; ++s) o[s] = (_Float16)acc[b * 4 + s];
        *(f16x4*)&PT[((size_t)b * HMm + j) * 64 + h * 4] = o;
    }
}

// ---------------- K7: transpose + fp32->fp16 convert ----------------
__global__ __launch_bounds__(256) void transp_f16_k(const float* __restrict__ in,
                                                    _Float16* __restrict__ out,
                                                    int K, int N) {
    __shared__ float t[32][33];
    int n0 = blockIdx.x * 32, k0 = blockIdx.y * 32;
    int tx = threadIdx.x & 31, ty = threadIdx.x >> 5;
#pragma unroll
    for (int i = 0; i < 32; i += 8)
        t[ty + i][tx] = in[(size_t)(k0 + ty + i) * N + n0 + tx];
    __syncthreads();
#pragma unroll
    for (int i = 0; i < 32; i += 8)
        out[(size_t)(n0 + ty + i) * K + k0 + tx] = (_Float16)t[tx][ty + i];
}

// ---------------- K9: vgen = gelu(alpha16 @ PT[b]^T + vpb), single launch, K=64 -------
__global__ __launch_bounds__(256) void vgen_k(const _Float16* __restrict__ alpha16,
                                              const _Float16* __restrict__ PT,
                                              const float* __restrict__ vpb,
                                              _Float16* __restrict__ v1a,
                                              _Float16* __restrict__ v1b) {
    __shared__ __align__(16) _Float16 As[128][64];
    __shared__ __align__(16) _Float16 Bs[128][64];
    const int tid = threadIdx.x;
    const int wid = tid >> 6;
    const int lane = tid & 63;
    const int swz = xcd_swz(gridDim.x * gridDim.y);
    const int brow = (swz / gridDim.x) * 128;
    const int bcol = (swz % gridDim.x) * 128;
    const int b = brow >> 12;
    const _Float16* Bt = PT + (size_t)b * HMm * 64;
    _Float16* Cb = (brow < 8192) ? v1a : v1b;
    const int rowoff = (brow < 8192) ? brow : brow - 8192;
    const int wr = (wid >> 1) * 64;
    const int wc = (wid & 1) * 64;

    f32x4 acc[4][4];
#pragma unroll
    for (int m = 0; m < 4; ++m)
#pragma unroll
        for (int n = 0; n < 4; ++n)
            acc[m][n] = f32x4{0.f, 0.f, 0.f, 0.f};

    const int lrow = lane >> 3;
    const int lcol = (lane & 7) * 8;
    const int fr = lane & 15;
    const int fk = (lane >> 4) * 8;

#pragma unroll
    for (int i = 0; i < 4; ++i) {
        int seg = wid * 4 + i;
        const _Float16* g = alpha16 + (size_t)(brow + seg * 8 + lrow) * 64 + lcol;
        __builtin_amdgcn_global_load_lds(
            (const __attribute__((address_space(1))) void*)g,
            (__attribute__((address_space(3))) void*)&As[seg * 8][0], 16, 0, 0);
    }
#pragma unroll
    for (int i = 0; i < 4; ++i) {
        int seg = wid * 4 + i;
        const _Float16* g = Bt + (size_t)(bcol + seg * 8 + lrow) * 64 + lcol;
        __builtin_amdgcn_global_load_lds(
            (const __attribute__((address_space(1))) void*)g,
            (__attribute__((address_space(3))) void*)&Bs[seg * 8][0], 16, 0, 0);
    }
    __syncthreads();
#pragma unroll
    for (int kb = 0; kb < 2; ++kb) {
        f16x8 af[4], bf[4];
#pragma unroll
        for (int m = 0; m < 4; ++m)
            af[m] = *(const f16x8*)&As[wr + m * 16 + fr][kb * 32 + fk];
#pragma unroll
        for (int n = 0; n < 4; ++n)
            bf[n] = *(const f16x8*)&Bs[wc + n * 16 + fr][kb * 32 + fk];
#pragma unroll
        for (int m = 0; m < 4; ++m)
#pragma unroll
            for (int n = 0; n < 4; ++n)
                acc[m][n] = __builtin_amdgcn_mfma_f32_16x16x32_f16(af[m], bf[n], acc[m][n], 0, 0, 0);
    }

    const int crow = (lane >> 4) * 4;
#pragma unroll
    for (int m = 0; m < 4; ++m) {
        int row0 = rowoff + wr + m * 16 + crow;
#pragma unroll
        for (int n = 0; n < 4; ++n) {
            int col = bcol + wc + n * 16 + fr;
            float bv = vpb[col];
#pragma unroll
            for (int r = 0; r < 4; ++r) {
                float v = acc[m][n][r] + bv;
                Cb[(size_t)(row0 + r) * HMm + col] = (_Float16)gelu_f(v);
            }
        }
    }
}

// ---------------- K11: 256x256 GEMM, BK=64 ring-2, 4-phase (m201-class schedule) ------
// Phases: p0{af0-3+bf0-1 reads,16 MFMA} p1{bf2-3,16} p2{af4-7,16} p3{stage(t+2),16}.
// vmcnt(8) at tile top only; bf held full tile; p2-end barrier certifies slot drained.
template <int OUT_F16>
__global__ __launch_bounds__(512, 2) void hgemm8_k(const _Float16* __restrict__ A0,
                                                   const _Float16* __restrict__ A1,
                                                   int splitrow,
                                                   const _Float16* __restrict__ Bt,
                                                   const float* __restrict__ bias,
                                                   void* __restrict__ Cv,
                                                   int M, int N, int K) {
    __shared__ __align__(16) _Float16 As[2][256][64];   // 64 KB
    __shared__ __align__(16) _Float16 Bs[2][256][64];   // 64 KB
    const int tid = threadIdx.x;
    const int wid = tid >> 6;            // 0..7
    const int lane = tid & 63;
    const int swz = xcd_swz(gridDim.x * gridDim.y);
    const int brow = (swz / gridDim.x) * 256;
    const int bcol = (swz % gridDim.x) * 256;
    const _Float16* Ab = (brow < splitrow) ? A0 : A1;
    const int arow0 = brow - ((brow < splitrow) ? 0 : splitrow);
    const int wm = wid >> 2;             // 0..1 -> 128-row half
    const int wn = wid & 3;              // 0..3 -> 64-col quarter

    // staging: per issue, wave covers 8 rows x 128B (full cache lines);
    // source col-block pre-swizzled so linear LDS dest + XOR read match (rule 21)
    const int srow = lane >> 3;                        // 0..7
    const int scol = ((lane & 7) ^ (lane >> 3)) * 8;   // f16 elems
    // fragment read: phys 16B-blk = (kk*4 + (lane>>4)) ^ (row&7), row&7 == lane&7
    const int fr = lane & 15;
    const int fk0 = (((lane >> 4) ^ (lane & 7))) * 8;
    const int fk1 = (((4 + (lane >> 4)) ^ (lane & 7))) * 8;
    const int crow = (lane >> 4) * 4;

    const int nk = K >> 6;

    f32x4 acc[8][4];
#pragma unroll
    for (int m = 0; m < 8; ++m)
#pragma unroll
        for (int n = 0; n < 4; ++n)
            acc[m][n] = f32x4{0.f, 0.f, 0.f, 0.f};

    auto stage = [&](int t) {
        const int slot = t & 1;
        const size_t kk = (size_t)t << 6;
#pragma unroll
        for (int j = 0; j < 4; ++j) {
            const _Float16* ga = Ab + (size_t)(arow0 + j * 64 + wid * 8 + srow) * K + kk + scol;
            __builtin_amdgcn_global_load_lds(
                (const __attribute__((address_space(1))) void*)ga,
                (__attribute__((address_space(3))) void*)&As[slot][j * 64 + wid * 8][0], 16, 0, 0);
        }
#pragma unroll
        for (int j = 0; j < 4; ++j) {
            const _Float16* gb = Bt + (size_t)(bcol + j * 64 + wid * 8 + srow) * K + kk + scol;
            __builtin_amdgcn_global_load_lds(
                (const __attribute__((address_space(1))) void*)gb,
                (__attribute__((address_space(3))) void*)&Bs[slot][j * 64 + wid * 8][0], 16, 0, 0);
        }
    };

    // prologue: 2 tiles in flight (nk >= 2 for all our shapes)
    stage(0);
    stage(1);

    for (int t = 0; t < nk; ++t) {
        // counted wait: tile t done; tile t+1 (8 issues/wave) stays in flight
        if (t + 1 < nk) asm volatile("s_waitcnt vmcnt(8)" ::: "memory");
        else            asm volatile("s_waitcnt vmcnt(0)" ::: "memory");
        __builtin_amdgcn_sched_barrier(0);
        __builtin_amdgcn_s_barrier();     // tile t staged by all waves
        __builtin_amdgcn_sched_barrier(0);

        const int slot = t & 1;
        f16x8 af[4][2], bf[4][2];
        // ---- p0: af m0-3 (both kk) + bf n0-1; MFMA m0-3 x n0-1 ----
#pragma unroll
        for (int m = 0; m < 4; ++m) {
            af[m][0] = *(const f16x8*)&As[slot][wm * 128 + m * 16 + fr][fk0];
            af[m][1] = *(const f16x8*)&As[slot][wm * 128 + m * 16 + fr][fk1];
        }
#pragma unroll
        for (int n = 0; n < 2; ++n) {
            bf[n][0] = *(const f16x8*)&Bs[slot][wn * 64 + n * 16 + fr][fk0];
            bf[n][1] = *(const f16x8*)&Bs[slot][wn * 64 + n * 16 + fr][fk1];
        }
        __builtin_amdgcn_sched_barrier(0);
        __builtin_amdgcn_s_barrier();
        asm volatile("s_waitcnt lgkmcnt(0)" ::: "memory");
        __builtin_amdgcn_sched_barrier(0);
        __builtin_amdgcn_s_setprio(1);
#pragma unroll
        for (int m = 0; m < 4; ++m)
#pragma unroll
            for (int n = 0; n < 2; ++n)
#pragma unroll
                for (int kk = 0; kk < 2; ++kk)
                    acc[m][n] = __builtin_amdgcn_mfma_f32_16x16x32_f16(af[m][kk], bf[n][kk], acc[m][n], 0, 0, 0);
        __builtin_amdgcn_s_setprio(0);
        __builtin_amdgcn_sched_barrier(0);
        // ---- p1: bf n2-3; MFMA m0-3 x n2-3 ----
#pragma unroll
        for (int n = 2; n < 4; ++n) {
            bf[n][0] = *(const f16x8*)&Bs[slot][wn * 64 + n * 16 + fr][fk0];
            bf[n][1] = *(const f16x8*)&Bs[slot][wn * 64 + n * 16 + fr][fk1];
        }
        __builtin_amdgcn_sched_barrier(0);
        __builtin_amdgcn_s_barrier();
        asm volatile("s_waitcnt lgkmcnt(0)" ::: "memory");
        __builtin_amdgcn_sched_barrier(0);
        __builtin_amdgcn_s_setprio(1);
#pragma unroll
        for (int m = 0; m < 4; ++m)
#pragma unroll
            for (int n = 2; n < 4; ++n)
#pragma unroll
                for (int kk = 0; kk < 2; ++kk)
                    acc[m][n] = __builtin_amdgcn_mfma_f32_16x16x32_f16(af[m][kk], bf[n][kk], acc[m][n], 0, 0, 0);
        __builtin_amdgcn_s_setprio(0);
        __builtin_amdgcn_sched_barrier(0);
        // ---- p2: af m4-7 (reuse regs); MFMA m4-7 x n0-1 ----
#pragma unroll
        for (int m = 0; m < 4; ++m) {
            af[m][0] = *(const f16x8*)&As[slot][wm * 128 + (m + 4) * 16 + fr][fk0];
            af[m][1] = *(const f16x8*)&As[slot][wm * 128 + (m + 4) * 16 + fr][fk1];
        }
        __builtin_amdgcn_sched_barrier(0);
        __builtin_amdgcn_s_barrier();
        asm volatile("s_waitcnt lgkmcnt(0)" ::: "memory");
        __builtin_amdgcn_sched_barrier(0);
        __builtin_amdgcn_s_setprio(1);
#pragma unroll
        for (int m = 0; m < 4; ++m)
#pragma unroll
            for (int n = 0; n < 2; ++n)
#pragma unroll
                for (int kk = 0; kk < 2; ++kk)
                    acc[m + 4][n] = __builtin_amdgcn_mfma_f32_16x16x32_f16(af[m][kk], bf[n][kk], acc[m + 4][n], 0, 0, 0);
        __builtin_amdgcn_s_setprio(0);
        __builtin_amdgcn_sched_barrier(0);
        // all waves' slot-t reads are complete past this barrier (each wave's
        // lgkmcnt(0) precedes it in program order) -> safe to overwrite slot
        __builtin_amdgcn_s_barrier();
        __builtin_amdgcn_sched_barrier(0);
        // ---- p3: stage t+2 into slot (ring-2), MFMA m4-7 x n2-3 (reg-only) ----
        if (t + 2 < nk) stage(t + 2);
        __builtin_amdgcn_s_setprio(1);
#pragma unroll
        for (int m = 0; m < 4; ++m)
#pragma unroll
            for (int n = 2; n < 4; ++n)
#pragma unroll
                for (int kk = 0; kk < 2; ++kk)
                    acc[m + 4][n] = __builtin_amdgcn_mfma_f32_16x16x32_f16(af[m][kk], bf[n][kk], acc[m + 4][n], 0, 0, 0);
        __builtin_amdgcn_s_setprio(0);
        __builtin_amdgcn_sched_barrier(0);
    }

    // epilogue
#pragma unroll
    for (int m = 0; m < 8; ++m) {
        int row0 = brow + wm * 128 + m * 16 + crow;
#pragma unroll
        for (int n = 0; n < 4; ++n) {
            int col = bcol + wn * 64 + n * 16 + fr;
            float bv = bias[col];
#pragma unroll
            for (int r = 0; r < 4; ++r) {
                float v = acc[m][n][r] + bv;
                size_t idx = (size_t)(row0 + r) * N + col;
                if (OUT_F16) ((_Float16*)Cv)[idx] = (_Float16)v;
                else ((float*)Cv)[idx] = v;
            }
        }
    }
    (void)M;
}

extern "C" void kernel_launch(void* const* d_in, const int* in_sizes, int n_in,
                              void* d_out, int out_size, void* d_ws, size_t ws_size,
                              hipStream_t stream) {
    const float* x         = (const float*)d_in[0];
    const float* slot_init = (const float*)d_in[1];
    const float* rw1       = (const float*)d_in[2];
    const float* rb1       = (const float*)d_in[3];
    const float* rw2       = (const float*)d_in[4];
    const float* rb2       = (const float*)d_in[5];
    const float* gwi       = (const float*)d_in[6];
    const float* gwh       = (const float*)d_in[7];
    const float* gbi       = (const float*)d_in[8];
    const float* gbh       = (const float*)d_in[9];
    const float* hpw       = (const float*)d_in[10];
    const float* hpb       = (const float*)d_in[11];
    const float* ohw       = (const float*)d_in[12];
    const float* ohb       = (const float*)d_in[13];
    const float* vpw       = (const float*)d_in[14];
    const float* vpb       = (const float*)d_in[15];
    const float* vow       = (const float*)d_in[16];
    const float* vob       = (const float*)d_in[17];
    const float* opw       = (const float*)d_in[18];
    const float* opb       = (const float*)d_in[19];
    const float* tau       = (const float*)d_in[20];
    float* out = (float*)d_out;

    float* ws = (float*)d_ws;
    size_t off = 0;
    auto alloc = [&](size_t nfloats) { float* p = ws + off; off += (nfloats + 63) & ~(size_t)63; return p; };

    float* cb     = alloc(1024);
    float* cbp    = alloc(16 * 1024);
    float* h1     = alloc((size_t)MTOK * 1024);            // fp32; dead after logits:
    _Float16* v1a = (_Float16*)h1;                          //   v1 rows 0..8191 [8192,4096] f16
    float* logits = alloc((size_t)MTOK * 64);
    float* alpha  = alloc((size_t)MTOK * 64);
    _Float16* alpha16 = (_Float16*)alloc((size_t)MTOK * 64 / 2);
    float* slotin = alloc(256 * 64);
    float* part   = alloc((size_t)8 * 64 * 4 * 64);
    float* partw  = alloc(8 * 64 * 4);
    float* Snew   = alloc(256 * 64);
    _Float16* PT   = (_Float16*)alloc((size_t)Bb * HMm * 64 / 2);  // [4,4096,64] f16
    _Float16* vowT = (_Float16*)alloc((size_t)Dd * HMm / 2);       // [1024,4096] f16
    _Float16* opwT = (_Float16*)alloc((size_t)Dd * Dd / 2);        // [1024,1024] f16
    _Float16* v2f16 = (_Float16*)alloc((size_t)MTOK * Dd / 2);     // [16384,1024] f16
    _Float16* w1hiT = (_Float16*)alloc((size_t)Dd * Dd / 2);
    _Float16* w1loT = (_Float16*)alloc((size_t)Dd * Dd / 2);

    // d_out scratch: xhi/xlo before hgemm4p; v1 rows 8192..16383 after vgen.
    _Float16* xhi = (_Float16*)d_out;
    _Float16* xlo = xhi + (size_t)MTOK * Dd;
    _Float16* v1b = (_Float16*)d_out;

    // ---- routing: pre-split x + deep-pipelined 4-plane split-fp16 GEMM + fp32 logits --
    cb_part_k<<<dim3(4, 16), 256, 0, stream>>>(slot_init, rw1, cbp);
    cb_comb_k<<<4, 256, 0, stream>>>(cbp, cb);
    wsplitT_k<<<dim3(Dd / 32, Dd / 32), 256, 0, stream>>>(rw1, w1hiT, w1loT);
    xsplit_k<<<(MTOK * Dd) / (256 * 8), 256, 0, stream>>>(x, xhi, xlo);
    hgemm4p_k<<<dim3(Dd / 256, MTOK / 256), 512, 0, stream>>>(
        xhi, xlo, w1hiT, w1loT, rb1, cb, h1, MTOK, Dd, Dd);
    logits2_k<<<MTOK / 64, 256, 0, stream>>>(h1, rw2, rb2, tau, logits);
    topk_k<<<MTOK / 4, 256, 0, stream>>>(logits, alpha, alpha16);

    // ---- weight transposes (fp32 -> fp16 [N,K]) ----
    transp_f16_k<<<dim3(Dd / 32, HMm / 32), 256, 0, stream>>>(vow, vowT, HMm, Dd);
    transp_f16_k<<<dim3(Dd / 32, Dd / 32), 256, 0, stream>>>(opw, opwT, Dd, Dd);

    // ---- slot pooling + GRU + slot MLP ----
    pool_part_k<<<dim3(64, 8), 256, 0, stream>>>(x, alpha, part, partw);
    pool_comb_k<<<64, 256, 0, stream>>>(part, partw, slotin);
    gru_k<<<256, 64, 0, stream>>>(slotin, slot_init, gwi, gwh, gbi, gbh,
                                  hpw, hpb, ohw, ohb, Snew);

    // ---- P[b] = S_emb[b] @ vpw (stored transposed f16 [b][j][hs]) ----
    pmat_k<<<dim3(HMm / 256, Hh), 256, 0, stream>>>(Snew, vpw, PT);

    // ---- value MLP: vgen (K=64), then BK=64 4-phase 256^2 GEMM2 + GEMM3 ----
    vgen_k<<<dim3(HMm / 128, MTOK / 128), 256, 0, stream>>>(
        alpha16, PT, vpb, v1a, v1b);
    hgemm8_k<1><<<dim3(Dd / 256, MTOK / 256), 512, 0, stream>>>(
        v1a, v1b, 8192, vowT, vob, v2f16, MTOK, Dd, HMm);
    hgemm8_k<0><<<dim3(Dd / 256, MTOK / 256), 512, 0, stream>>>(
        v2f16, v2f16, MTOK, opwT, opb, out, MTOK, Dd, Dd);

    (void)in_sizes; (void)n_in; (void)out_size; (void)ws_size;
}

// Round 12
// 500.724 us; speedup vs baseline: 1.7006x; 1.0411x over previous
//
#include <hip/hip_runtime.h>
#include <cstddef>
#include <cstdint>

// Problem constants
#define Bb 4
#define Tt 4096
#define Dd 1024
#define Hh 16
#define HDd 64
#define NSs 64
#define SPHh 4
#define HMm 4096
#define MTOK (Bb*Tt)   // 16384

typedef _Float16 f16x8 __attribute__((ext_vector_type(8)));
typedef _Float16 f16x4 __attribute__((ext_vector_type(4)));
typedef float f32x4 __attribute__((ext_vector_type(4)));

__device__ __forceinline__ float gelu_f(float x) {
    return 0.5f * x * (1.0f + erff(x * 0.70710678118654752440f));
}

// XCD-chunked bijective block swizzle (requires nwg % 8 == 0; all launches comply)
__device__ __forceinline__ int xcd_swz(int nwg) {
    int orig = blockIdx.y * gridDim.x + blockIdx.x;
    int cpx = nwg >> 3;
    return (orig & 7) * cpx + (orig >> 3);
}

// ---------------- K0: cb partials ----------------
__global__ __launch_bounds__(256) void cb_part_k(const float* __restrict__ slot_init,
                                                 const float* __restrict__ rw1,
                                                 float* __restrict__ cbp) {
    __shared__ float sm[64];
    int tid = threadIdx.x;
    if (tid < 64) {
        float s = 0.f;
        for (int i = 0; i < 64; ++i) s += slot_init[i * 64 + tid];
        sm[tid] = s * (1.0f / 64.0f);
    }
    __syncthreads();
    int j = blockIdx.x * 256 + tid;
    int k0 = blockIdx.y * 64;
    float acc = 0.f;
#pragma unroll 8
    for (int k = 0; k < 64; ++k)
        acc = fmaf(sm[k], rw1[(size_t)(1024 + k0 + k) * 1024 + j], acc);
    cbp[(size_t)blockIdx.y * 1024 + j] = acc;
}

__global__ __launch_bounds__(256) void cb_comb_k(const float* __restrict__ cbp,
                                                 float* __restrict__ cb) {
    int j = blockIdx.x * 256 + threadIdx.x;
    float acc = 0.f;
#pragma unroll
    for (int c = 0; c < 16; ++c) acc += cbp[(size_t)c * 1024 + j];
    cb[j] = acc;
}

// ---------------- K1: rw1[:1024] -> transposed split-f16 planes ----------------
__global__ __launch_bounds__(256) void wsplitT_k(const float* __restrict__ rw1,
                                                 _Float16* __restrict__ whiT,
                                                 _Float16* __restrict__ wloT) {
    __shared__ float t[32][33];
    int n0 = blockIdx.x * 32, k0 = blockIdx.y * 32;
    int tx = threadIdx.x & 31, ty = threadIdx.x >> 5;
#pragma unroll
    for (int i = 0; i < 32; i += 8)
        t[ty + i][tx] = rw1[(size_t)(k0 + ty + i) * 1024 + n0 + tx];
    __syncthreads();
#pragma unroll
    for (int i = 0; i < 32; i += 8) {
        float v = t[tx][ty + i];
        _Float16 h = (_Float16)v;
        _Float16 l = (_Float16)(v - (float)h);
        whiT[(size_t)(n0 + ty + i) * 1024 + k0 + tx] = h;
        wloT[(size_t)(n0 + ty + i) * 1024 + k0 + tx] = l;
    }
}

// ---------------- K1a: x -> split f16 hi/lo planes ----------------
__global__ __launch_bounds__(256) void xsplit_k(const float* __restrict__ x,
                                                _Float16* __restrict__ xhi,
                                                _Float16* __restrict__ xlo) {
    size_t i = ((size_t)blockIdx.x * 256 + threadIdx.x) * 8;
    float4 a = *(const float4*)(x + i);
    float4 b = *(const float4*)(x + i + 4);
    float v[8] = {a.x, a.y, a.z, a.w, b.x, b.y, b.z, b.w};
    f16x8 h, l;
#pragma unroll
    for (int j = 0; j < 8; ++j) {
        _Float16 hv = (_Float16)v[j];
        h[j] = hv;
        l[j] = (_Float16)(v[j] - (float)hv);
    }
    *(f16x8*)(xhi + i) = h;
    *(f16x8*)(xlo + i) = l;
}

// ---------------- K1b: deep-pipelined split-fp16 routing GEMM ----------------
// 256x256 tile, BK=32, ring-2, counted vmcnt, 4-phase (hgemm8-mirror skeleton).
// Per-output 3-term chain (al*bh, ah*bl, ah*bh per ascending k0) unchanged -> bit-identical.
__global__ __launch_bounds__(512, 2) void hgemm4p_k(const _Float16* __restrict__ Ah,
                                                    const _Float16* __restrict__ Al,
                                                    const _Float16* __restrict__ Bh,
                                                    const _Float16* __restrict__ Bl,
                                                    const float* __restrict__ bias1,
                                                    const float* __restrict__ bias2,
                                                    float* __restrict__ C,
                                                    int M, int N, int K) {
    __shared__ __align__(16) _Float16 Ahs[2][256][32];
    __shared__ __align__(16) _Float16 Als[2][256][32];
    __shared__ __align__(16) _Float16 Bhs[2][256][32];
    __shared__ __align__(16) _Float16 Bls[2][256][32];
    const int tid = threadIdx.x;
    const int wid = tid >> 6;            // 0..7
    const int lane = tid & 63;
    const int swz = xcd_swz(gridDim.x * gridDim.y);
    const int brow = (swz / gridDim.x) * 256;
    const int bcol = (swz % gridDim.x) * 256;
    const int wm = wid >> 2;             // 0..1
    const int wn = wid & 3;              // 0..3

    const int srow = lane >> 2;
    const int scol = ((lane & 3) ^ ((lane >> 3) & 3)) * 8;
    const int fr = lane & 15;
    const int fkp = (((lane >> 4) ^ ((lane >> 1) & 3))) * 8;
    const int crow = (lane >> 4) * 4;

    const int nk = K >> 5;   // 32

    f32x4 acc[8][4];
#pragma unroll
    for (int m = 0; m < 8; ++m)
#pragma unroll
        for (int n = 0; n < 4; ++n)
            acc[m][n] = f32x4{0.f, 0.f, 0.f, 0.f};

    auto stage = [&](int t) {
        const int slot = t & 1;
        const size_t kk = (size_t)t << 5;
#pragma unroll
        for (int i = 0; i < 2; ++i) {
            int r0 = wid * 32 + i * 16;
            const _Float16* gah = Ah + (size_t)(brow + r0 + srow) * K + kk + scol;
            __builtin_amdgcn_global_load_lds(
                (const __attribute__((address_space(1))) void*)gah,
                (__attribute__((address_space(3))) void*)&Ahs[slot][r0][0], 16, 0, 0);
            const _Float16* gal = Al + (size_t)(brow + r0 + srow) * K + kk + scol;
            __builtin_amdgcn_global_load_lds(
                (const __attribute__((address_space(1))) void*)gal,
                (__attribute__((address_space(3))) void*)&Als[slot][r0][0], 16, 0, 0);
            const _Float16* gbh = Bh + (size_t)(bcol + r0 + srow) * K + kk + scol;
            __builtin_amdgcn_global_load_lds(
                (const __attribute__((address_space(1))) void*)gbh,
                (__attribute__((address_space(3))) void*)&Bhs[slot][r0][0], 16, 0, 0);
            const _Float16* gbl = Bl + (size_t)(bcol + r0 + srow) * K + kk + scol;
            __builtin_amdgcn_global_load_lds(
                (const __attribute__((address_space(1))) void*)gbl,
                (__attribute__((address_space(3))) void*)&Bls[slot][r0][0], 16, 0, 0);
        }
    };

    stage(0);
    if (nk > 1) stage(1);

    for (int t = 0; t < nk; ++t) {
        if (t + 1 < nk) asm volatile("s_waitcnt vmcnt(8)" ::: "memory");
        else            asm volatile("s_waitcnt vmcnt(0)" ::: "memory");
        __builtin_amdgcn_sched_barrier(0);
        __builtin_amdgcn_s_barrier();     // tile t staged by all waves
        __builtin_amdgcn_sched_barrier(0);

        const int slot = t & 1;
        f16x8 afh[4], afl[4], bfh[4], bfl[4];
        // ---- p0: A m0-3 (hi/lo) + B n0-1 (hi/lo); MFMA m0-3 x n0-1 ----
#pragma unroll
        for (int m = 0; m < 4; ++m) {
            afh[m] = *(const f16x8*)&Ahs[slot][wm * 128 + m * 16 + fr][fkp];
            afl[m] = *(const f16x8*)&Als[slot][wm * 128 + m * 16 + fr][fkp];
        }
#pragma unroll
        for (int n = 0; n < 2; ++n) {
            bfh[n] = *(const f16x8*)&Bhs[slot][wn * 64 + n * 16 + fr][fkp];
            bfl[n] = *(const f16x8*)&Bls[slot][wn * 64 + n * 16 + fr][fkp];
        }
        __builtin_amdgcn_sched_barrier(0);
        __builtin_amdgcn_s_barrier();
        asm volatile("s_waitcnt lgkmcnt(0)" ::: "memory");
        __builtin_amdgcn_sched_barrier(0);
        __builtin_amdgcn_s_setprio(1);
#pragma unroll
        for (int m = 0; m < 4; ++m)
#pragma unroll
            for (int n = 0; n < 2; ++n) {
                acc[m][n] = __builtin_amdgcn_mfma_f32_16x16x32_f16(afl[m], bfh[n], acc[m][n], 0, 0, 0);
                acc[m][n] = __builtin_amdgcn_mfma_f32_16x16x32_f16(afh[m], bfl[n], acc[m][n], 0, 0, 0);
                acc[m][n] = __builtin_amdgcn_mfma_f32_16x16x32_f16(afh[m], bfh[n], acc[m][n], 0, 0, 0);
            }
        __builtin_amdgcn_s_setprio(0);
        __builtin_amdgcn_sched_barrier(0);
        // ---- p1: B n2-3; MFMA m0-3 x n2-3 ----
#pragma unroll
        for (int n = 2; n < 4; ++n) {
            bfh[n] = *(const f16x8*)&Bhs[slot][wn * 64 + n * 16 + fr][fkp];
            bfl[n] = *(const f16x8*)&Bls[slot][wn * 64 + n * 16 + fr][fkp];
        }
        __builtin_amdgcn_sched_barrier(0);
        __builtin_amdgcn_s_barrier();
        asm volatile("s_waitcnt lgkmcnt(0)" ::: "memory");
        __builtin_amdgcn_sched_barrier(0);
        __builtin_amdgcn_s_setprio(1);
#pragma unroll
        for (int m = 0; m < 4; ++m)
#pragma unroll
            for (int n = 2; n < 4; ++n) {
                acc[m][n] = __builtin_amdgcn_mfma_f32_16x16x32_f16(afl[m], bfh[n], acc[m][n], 0, 0, 0);
                acc[m][n] = __builtin_amdgcn_mfma_f32_16x16x32_f16(afh[m], bfl[n], acc[m][n], 0, 0, 0);
                acc[m][n] = __builtin_amdgcn_mfma_f32_16x16x32_f16(afh[m], bfh[n], acc[m][n], 0, 0, 0);
            }
        __builtin_amdgcn_s_setprio(0);
        __builtin_amdgcn_sched_barrier(0);
        // ---- p2: A m4-7 (reuse regs); MFMA m4-7 x n0-1 ----
#pragma unroll
        for (int m = 0; m < 4; ++m) {
            afh[m] = *(const f16x8*)&Ahs[slot][wm * 128 + (m + 4) * 16 + fr][fkp];
            afl[m] = *(const f16x8*)&Als[slot][wm * 128 + (m + 4) * 16 + fr][fkp];
        }
        __builtin_amdgcn_sched_barrier(0);
        __builtin_amdgcn_s_barrier();
        asm volatile("s_waitcnt lgkmcnt(0)" ::: "memory");
        __builtin_amdgcn_sched_barrier(0);
        __builtin_amdgcn_s_setprio(1);
#pragma unroll
        for (int m = 0; m < 4; ++m)
#pragma unroll
            for (int n = 0; n < 2; ++n) {
                acc[m + 4][n] = __builtin_amdgcn_mfma_f32_16x16x32_f16(afl[m], bfh[n], acc[m + 4][n], 0, 0, 0);
                acc[m + 4][n] = __builtin_amdgcn_mfma_f32_16x16x32_f16(afh[m], bfl[n], acc[m + 4][n], 0, 0, 0);
                acc[m + 4][n] = __builtin_amdgcn_mfma_f32_16x16x32_f16(afh[m], bfh[n], acc[m + 4][n], 0, 0, 0);
            }
        __builtin_amdgcn_s_setprio(0);
        __builtin_amdgcn_sched_barrier(0);
        // slot fully read by ALL waves past this barrier -> safe to overwrite
        __builtin_amdgcn_s_barrier();
        __builtin_amdgcn_sched_barrier(0);
        // ---- p3: stage t+2 (ring-2), MFMA m4-7 x n2-3 (reg-only) ----
        if (t + 2 < nk) stage(t + 2);
        __builtin_amdgcn_s_setprio(1);
#pragma unroll
        for (int m = 0; m < 4; ++m)
#pragma unroll
            for (int n = 2; n < 4; ++n) {
                acc[m + 4][n] = __builtin_amdgcn_mfma_f32_16x16x32_f16(afl[m], bfh[n], acc[m + 4][n], 0, 0, 0);
                acc[m + 4][n] = __builtin_amdgcn_mfma_f32_16x16x32_f16(afh[m], bfl[n], acc[m + 4][n], 0, 0, 0);
                acc[m + 4][n] = __builtin_amdgcn_mfma_f32_16x16x32_f16(afh[m], bfh[n], acc[m + 4][n], 0, 0, 0);
            }
        __builtin_amdgcn_s_setprio(0);
        __builtin_amdgcn_sched_barrier(0);
    }

#pragma unroll
    for (int m = 0; m < 8; ++m) {
        int row0 = brow + wm * 128 + m * 16 + crow;
#pragma unroll
        for (int n = 0; n < 4; ++n) {
            int col = bcol + wn * 64 + n * 16 + fr;
            float bv = bias1[col] + bias2[col];
#pragma unroll
            for (int r = 0; r < 4; ++r) {
                float v = acc[m][n][r] + bv;
                C[(size_t)(row0 + r) * N + col] = gelu_f(v);
            }
        }
    }
    (void)M;
}

// ---------------- K2: route logits (fp32, register-prefetch; bit-identical k-order) ---
__global__ __launch_bounds__(256) void logits2_k(const float* __restrict__ A,
                                                 const float* __restrict__ Bw,
                                                 const float* __restrict__ rb2,
                                                 const float* __restrict__ taup,
                                                 float* __restrict__ Cl) {
    __shared__ float At[16][68];
    __shared__ float Bs[16][64];
    const int tid = threadIdx.x;
    const int m0 = blockIdx.x * 64;
    const int rg = tid >> 4;
    const int cg = tid & 15;
    const int srow = tid >> 2;
    const int skk  = (tid & 3) * 4;
    const int bk = tid >> 4;
    const int bc = (tid & 15) * 4;

    float acc[4][4] = {};

    float4 av = *(const float4*)(A + (size_t)(m0 + srow) * 1024 + skk);
    float4 bv = *(const float4*)(Bw + (size_t)bk * 64 + bc);

    for (int k0 = 0; k0 < 1024; k0 += 16) {
        __syncthreads();
        At[skk + 0][srow] = av.x;
        At[skk + 1][srow] = av.y;
        At[skk + 2][srow] = av.z;
        At[skk + 3][srow] = av.w;
        *(float4*)&Bs[bk][bc] = bv;
        __syncthreads();
        if (k0 + 16 < 1024) {
            av = *(const float4*)(A + (size_t)(m0 + srow) * 1024 + k0 + 16 + skk);
            bv = *(const float4*)(Bw + (size_t)(k0 + 16 + bk) * 64 + bc);
        }
#pragma unroll
        for (int k = 0; k < 16; ++k) {
            float4 a4 = *(const float4*)&At[k][rg * 4];
            float4 b4 = *(const float4*)&Bs[k][cg * 4];
            float a[4] = {a4.x, a4.y, a4.z, a4.w};
            float b[4] = {b4.x, b4.y, b4.z, b4.w};
#pragma unroll
            for (int i = 0; i < 4; ++i)
#pragma unroll
                for (int j = 0; j < 4; ++j)
                    acc[i][j] = fmaf(a[i], b[j], acc[i][j]);
        }
    }
    float inv = 1.0f / (fabsf(taup[0]) + 0.1f);
#pragma unroll
    for (int i = 0; i < 4; ++i)
#pragma unroll
        for (int j = 0; j < 4; ++j)
            Cl[(size_t)(m0 + rg * 4 + i) * 64 + cg * 4 + j] =
                (acc[i][j] + rb2[cg * 4 + j]) * inv;
}

// ---------------- K3: top-32-of-64 + softmax -> dense alpha ----------------
__global__ __launch_bounds__(256) void topk_k(const float* __restrict__ logits,
                                              float* __restrict__ alpha,
                                              _Float16* __restrict__ alpha16) {
    int wave = threadIdx.x >> 6;
    int lane = threadIdx.x & 63;
    int t = blockIdx.x * 4 + wave;
    float li = logits[(size_t)t * 64 + lane];
    float m = li;
#pragma unroll
    for (int off = 32; off; off >>= 1) m = fmaxf(m, __shfl_xor(m, off, 64));
    int cnt = 0;
    for (int off = 1; off < 64; ++off) {
        int j = (lane + off) & 63;
        float lj = __shfl(li, j, 64);
        cnt += (lj > li) || (lj == li && j < lane);
    }
    float e = (cnt < 32) ? expf(li - m) : 0.0f;
    float s = e;
#pragma unroll
    for (int off = 32; off; off >>= 1) s += __shfl_xor(s, off, 64);
    float a = e / s;
    alpha[(size_t)t * 64 + lane] = a;
    alpha16[(size_t)t * 64 + lane] = (_Float16)a;
}

// ---------------- K4: slot pooling ----------------
__global__ __launch_bounds__(256) void pool_part_k(const float* __restrict__ x,
                                                   const float* __restrict__ alpha,
                                                   float* __restrict__ part,
                                                   float* __restrict__ partw) {
    int bh = blockIdx.x;
    int c = blockIdx.y;
    int b = bh >> 4, h = bh & 15;
    int tid = threadIdx.x;
    int s = tid >> 6, d = tid & 63;
    __shared__ float lx[16][64];
    __shared__ float la[16][4];
    float acc = 0.f, wacc = 0.f;
    const int tchunk = Tt / 8;
    const int t0base = c * tchunk;
    for (int t0 = 0; t0 < tchunk; t0 += 16) {
        int ttr = tid >> 4;
        int ddr = (tid & 15) * 4;
        size_t trow = (size_t)b * Tt + t0base + t0 + ttr;
        float4 xv = *(const float4*)(x + trow * Dd + h * 64 + ddr);
        *(float4*)&lx[ttr][ddr] = xv;
        if (tid < 64) {
            int tt2 = tid >> 2, ss = tid & 3;
            la[tt2][ss] = alpha[((size_t)b * Tt + t0base + t0 + tt2) * 64 + h * 4 + ss];
        }
        __syncthreads();
#pragma unroll
        for (int q = 0; q < 16; ++q) {
            float av = la[q][s];
            acc = fmaf(av, lx[q][d], acc);
            wacc += av;
        }
        __syncthreads();
    }
    part[(((size_t)c * 64 + bh) * 4 + s) * 64 + d] = acc;
    if (d == 0) partw[((size_t)c * 64 + bh) * 4 + s] = wacc;
}

__global__ __launch_bounds__(256) void pool_comb_k(const float* __restrict__ part,
                                                   const float* __restrict__ partw,
                                                   float* __restrict__ slot_in) {
    int bh = blockIdx.x;
    int tid = threadIdx.x;
    int s = tid >> 6, d = tid & 63;
    float acc = 0.f, w = 0.f;
    for (int c = 0; c < 8; ++c) {
        acc += part[(((size_t)c * 64 + bh) * 4 + s) * 64 + d];
        w   += partw[((size_t)c * 64 + bh) * 4 + s];
    }
    slot_in[((size_t)bh * 4 + s) * 64 + d] = acc / (w + 1e-8f);
}

// ---------------- K5: GRU + slot MLP ----------------
__global__ __launch_bounds__(64) void gru_k(const float* __restrict__ slot_in,
                                            const float* __restrict__ slot_init,
                                            const float* __restrict__ gwi,
                                            const float* __restrict__ gwh,
                                            const float* __restrict__ gbi,
                                            const float* __restrict__ gbh,
                                            const float* __restrict__ hpw,
                                            const float* __restrict__ hpb,
                                            const float* __restrict__ ohw,
                                            const float* __restrict__ ohb,
                                            float* __restrict__ S_new) {
    int slot = blockIdx.x;
    int hs = slot & 63;
    int d = threadIdx.x;
    __shared__ float si[64], hp[64], hn[64], g[256];
    si[d] = slot_in[(size_t)slot * 64 + d];
    hp[d] = slot_init[(size_t)hs * 64 + d];
    __syncthreads();
    float gi_r = gbi[d], gi_z = gbi[64 + d], gi_n = gbi[128 + d];
    float gh_r = gbh[d], gh_z = gbh[64 + d], gh_n = gbh[128 + d];
    for (int k = 0; k < 64; ++k) {
        float sv = si[k], hv = hp[k];
        gi_r = fmaf(sv, gwi[(size_t)(d) * 64 + k], gi_r);
        gi_z = fmaf(sv, gwi[(size_t)(64 + d) * 64 + k], gi_z);
        gi_n = fmaf(sv, gwi[(size_t)(128 + d) * 64 + k], gi_n);
        gh_r = fmaf(hv, gwh[(size_t)(d) * 64 + k], gh_r);
        gh_z = fmaf(hv, gwh[(size_t)(64 + d) * 64 + k], gh_z);
        gh_n = fmaf(hv, gwh[(size_t)(128 + d) * 64 + k], gh_n);
    }
    float r = 1.0f / (1.0f + expf(-(gi_r + gh_r)));
    float z = 1.0f / (1.0f + expf(-(gi_z + gh_z)));
    float n = tanhf(gi_n + r * gh_n);
    float hnew = (1.0f - z) * n + z * hp[d];
    hn[d] = hnew;
    __syncthreads();
    float p0 = hpb[d], p1 = hpb[64 + d], p2 = hpb[128 + d], p3 = hpb[192 + d];
    for (int k = 0; k < 64; ++k) {
        float hv = hn[k];
        p0 = fmaf(hv, hpw[(size_t)k * 256 + d], p0);
        p1 = fmaf(hv, hpw[(size_t)k * 256 + 64 + d], p1);
        p2 = fmaf(hv, hpw[(size_t)k * 256 + 128 + d], p2);
        p3 = fmaf(hv, hpw[(size_t)k * 256 + 192 + d], p3);
    }
    g[d] = gelu_f(p0); g[64 + d] = gelu_f(p1); g[128 + d] = gelu_f(p2); g[192 + d] = gelu_f(p3);
    __syncthreads();
    float o = ohb[d];
    for (int j = 0; j < 256; ++j) o = fmaf(g[j], ohw[(size_t)j * 64 + d], o);
    S_new[(size_t)slot * 64 + d] = o;
}

// ---------------- K6: PT[b][j][hs] = sum_d Snew[b,hs,d] * vpw[h*64+d, j]  (f16) -------
__global__ __launch_bounds__(256) void pmat_k(const float* __restrict__ Snew,
                                              const float* __restrict__ vpw,
                                              _Float16* __restrict__ PT) {
    const int h = blockIdx.y;
    const int tid = threadIdx.x;
    const int j = blockIdx.x * 256 + tid;
    __shared__ float S[16][64];
    for (int i = tid; i < 1024; i += 256) {
        int row = i >> 6, d = i & 63;
        int b = row >> 2, s = row & 3;
        S[row][d] = Snew[((size_t)b * 64 + h * 4 + s) * 64 + d];
    }
    __syncthreads();
    float acc[16];
#pragma unroll
    for (int r = 0; r < 16; ++r) acc[r] = 0.f;
    const float* wp = vpw + (size_t)h * 64 * HMm + j;
#pragma unroll 4
    for (int d = 0; d < 64; ++d) {
        float w = wp[(size_t)d * HMm];
#pragma unroll
        for (int r = 0; r < 16; ++r) acc[r] = fmaf(S[r][d], w, acc[r]);
    }
#pragma unroll
    for (int b = 0; b < 4; ++b) {
        f16x4 o;
#pragma unroll
        for (int s = 0; s < 4; ++s) o[s] = (_Float16)acc[b * 4 + s];
        *(f16x4*)&PT[((size_t)b * HMm + j) * 64 + h * 4] = o;
    }
}

// ---------------- K7: transpose + fp32->fp16 convert ----------------
__global__ __launch_bounds__(256) void transp_f16_k(const float* __restrict__ in,
                                                    _Float16* __restrict__ out,
                                                    int K, int N) {
    __shared__ float t[32][33];
    int n0 = blockIdx.x * 32, k0 = blockIdx.y * 32;
    int tx = threadIdx.x & 31, ty = threadIdx.x >> 5;
#pragma unroll
    for (int i = 0; i < 32; i += 8)
        t[ty + i][tx] = in[(size_t)(k0 + ty + i) * N + n0 + tx];
    __syncthreads();
#pragma unroll
    for (int i = 0; i < 32; i += 8)
        out[(size_t)(n0 + ty + i) * K + k0 + tx] = (_Float16)t[tx][ty + i];
}

// ---------------- K9: vgen = gelu(alpha16 @ PT[b]^T + vpb), single launch, K=64 -------
__global__ __launch_bounds__(256) void vgen_k(const _Float16* __restrict__ alpha16,
                                              const _Float16* __restrict__ PT,
                                              const float* __restrict__ vpb,
                                              _Float16* __restrict__ v1a,
                                              _Float16* __restrict__ v1b) {
    __shared__ __align__(16) _Float16 As[128][64];
    __shared__ __align__(16) _Float16 Bs[128][64];
    const int tid = threadIdx.x;
    const int wid = tid >> 6;
    const int lane = tid & 63;
    const int swz = xcd_swz(gridDim.x * gridDim.y);
    const int brow = (swz / gridDim.x) * 128;
    const int bcol = (swz % gridDim.x) * 128;
    const int b = brow >> 12;
    const _Float16* Bt = PT + (size_t)b * HMm * 64;
    _Float16* Cb = (brow < 8192) ? v1a : v1b;
    const int rowoff = (brow < 8192) ? brow : brow - 8192;
    const int wr = (wid >> 1) * 64;
    const int wc = (wid & 1) * 64;

    f32x4 acc[4][4];
#pragma unroll
    for (int m = 0; m < 4; ++m)
#pragma unroll
        for (int n = 0; n < 4; ++n)
            acc[m][n] = f32x4{0.f, 0.f, 0.f, 0.f};

    const int lrow = lane >> 3;
    const int lcol = (lane & 7) * 8;
    const int fr = lane & 15;
    const int fk = (lane >> 4) * 8;

#pragma unroll
    for (int i = 0; i < 4; ++i) {
        int seg = wid * 4 + i;
        const _Float16* g = alpha16 + (size_t)(brow + seg * 8 + lrow) * 64 + lcol;
        __builtin_amdgcn_global_load_lds(
            (const __attribute__((address_space(1))) void*)g,
            (__attribute__((address_space(3))) void*)&As[seg * 8][0], 16, 0, 0);
    }
#pragma unroll
    for (int i = 0; i < 4; ++i) {
        int seg = wid * 4 + i;
        const _Float16* g = Bt + (size_t)(bcol + seg * 8 + lrow) * 64 + lcol;
        __builtin_amdgcn_global_load_lds(
            (const __attribute__((address_space(1))) void*)g,
            (__attribute__((address_space(3))) void*)&Bs[seg * 8][0], 16, 0, 0);
    }
    __syncthreads();
#pragma unroll
    for (int kb = 0; kb < 2; ++kb) {
        f16x8 af[4], bf[4];
#pragma unroll
        for (int m = 0; m < 4; ++m)
            af[m] = *(const f16x8*)&As[wr + m * 16 + fr][kb * 32 + fk];
#pragma unroll
        for (int n = 0; n < 4; ++n)
            bf[n] = *(const f16x8*)&Bs[wc + n * 16 + fr][kb * 32 + fk];
#pragma unroll
        for (int m = 0; m < 4; ++m)
#pragma unroll
            for (int n = 0; n < 4; ++n)
                acc[m][n] = __builtin_amdgcn_mfma_f32_16x16x32_f16(af[m], bf[n], acc[m][n], 0, 0, 0);
    }

    const int crow = (lane >> 4) * 4;
#pragma unroll
    for (int m = 0; m < 4; ++m) {
        int row0 = rowoff + wr + m * 16 + crow;
#pragma unroll
        for (int n = 0; n < 4; ++n) {
            int col = bcol + wc + n * 16 + fr;
            float bv = vpb[col];
#pragma unroll
            for (int r = 0; r < 4; ++r) {
                float v = acc[m][n][r] + bv;
                Cb[(size_t)(row0 + r) * HMm + col] = (_Float16)gelu_f(v);
            }
        }
    }
}

// ---------------- K11: 256x256 GEMM, BK=64 ring-2, 4-phase (m201-class schedule) ------
template <int OUT_F16>
__global__ __launch_bounds__(512, 2) void hgemm8_k(const _Float16* __restrict__ A0,
                                                   const _Float16* __restrict__ A1,
                                                   int splitrow,
                                                   const _Float16* __restrict__ Bt,
                                                   const float* __restrict__ bias,
                                                   void* __restrict__ Cv,
                                                   int M, int N, int K) {
    __shared__ __align__(16) _Float16 As[2][256][64];   // 64 KB
    __shared__ __align__(16) _Float16 Bs[2][256][64];   // 64 KB
    const int tid = threadIdx.x;
    const int wid = tid >> 6;            // 0..7
    const int lane = tid & 63;
    const int swz = xcd_swz(gridDim.x * gridDim.y);
    const int brow = (swz / gridDim.x) * 256;
    const int bcol = (swz % gridDim.x) * 256;
    const _Float16* Ab = (brow < splitrow) ? A0 : A1;
    const int arow0 = brow - ((brow < splitrow) ? 0 : splitrow);
    const int wm = wid >> 2;             // 0..1 -> 128-row half
    const int wn = wid & 3;              // 0..3 -> 64-col quarter

    const int srow = lane >> 3;                        // 0..7
    const int scol = ((lane & 7) ^ (lane >> 3)) * 8;   // f16 elems
    const int fr = lane & 15;
    const int fk0 = (((lane >> 4) ^ (lane & 7))) * 8;
    const int fk1 = (((4 + (lane >> 4)) ^ (lane & 7))) * 8;
    const int crow = (lane >> 4) * 4;

    const int nk = K >> 6;

    f32x4 acc[8][4];
#pragma unroll
    for (int m = 0; m < 8; ++m)
#pragma unroll
        for (int n = 0; n < 4; ++n)
            acc[m][n] = f32x4{0.f, 0.f, 0.f, 0.f};

    auto stage = [&](int t) {
        const int slot = t & 1;
        const size_t kk = (size_t)t << 6;
#pragma unroll
        for (int j = 0; j < 4; ++j) {
            const _Float16* ga = Ab + (size_t)(arow0 + j * 64 + wid * 8 + srow) * K + kk + scol;
            __builtin_amdgcn_global_load_lds(
                (const __attribute__((address_space(1))) void*)ga,
                (__attribute__((address_space(3))) void*)&As[slot][j * 64 + wid * 8][0], 16, 0, 0);
        }
#pragma unroll
        for (int j = 0; j < 4; ++j) {
            const _Float16* gb = Bt + (size_t)(bcol + j * 64 + wid * 8 + srow) * K + kk + scol;
            __builtin_amdgcn_global_load_lds(
                (const __attribute__((address_space(1))) void*)gb,
                (__attribute__((address_space(3))) void*)&Bs[slot][j * 64 + wid * 8][0], 16, 0, 0);
        }
    };

    stage(0);
    stage(1);

    for (int t = 0; t < nk; ++t) {
        if (t + 1 < nk) asm volatile("s_waitcnt vmcnt(8)" ::: "memory");
        else            asm volatile("s_waitcnt vmcnt(0)" ::: "memory");
        __builtin_amdgcn_sched_barrier(0);
        __builtin_amdgcn_s_barrier();
        __builtin_amdgcn_sched_barrier(0);

        const int slot = t & 1;
        f16x8 af[4][2], bf[4][2];
#pragma unroll
        for (int m = 0; m < 4; ++m) {
            af[m][0] = *(const f16x8*)&As[slot][wm * 128 + m * 16 + fr][fk0];
            af[m][1] = *(const f16x8*)&As[slot][wm * 128 + m * 16 + fr][fk1];
        }
#pragma unroll
        for (int n = 0; n < 2; ++n) {
            bf[n][0] = *(const f16x8*)&Bs[slot][wn * 64 + n * 16 + fr][fk0];
            bf[n][1] = *(const f16x8*)&Bs[slot][wn * 64 + n * 16 + fr][fk1];
        }
        __builtin_amdgcn_sched_barrier(0);
        __builtin_amdgcn_s_barrier();
        asm volatile("s_waitcnt lgkmcnt(0)" ::: "memory");
        __builtin_amdgcn_sched_barrier(0);
        __builtin_amdgcn_s_setprio(1);
#pragma unroll
        for (int m = 0; m < 4; ++m)
#pragma unroll
            for (int n = 0; n < 2; ++n)
#pragma unroll
                for (int kk = 0; kk < 2; ++kk)
                    acc[m][n] = __builtin_amdgcn_mfma_f32_16x16x32_f16(af[m][kk], bf[n][kk], acc[m][n], 0, 0, 0);
        __builtin_amdgcn_s_setprio(0);
        __builtin_amdgcn_sched_barrier(0);
#pragma unroll
        for (int n = 2; n < 4; ++n) {
            bf[n][0] = *(const f16x8*)&Bs[slot][wn * 64 + n * 16 + fr][fk0];
            bf[n][1] = *(const f16x8*)&Bs[slot][wn * 64 + n * 16 + fr][fk1];
        }
        __builtin_amdgcn_sched_barrier(0);
        __builtin_amdgcn_s_barrier();
        asm volatile("s_waitcnt lgkmcnt(0)" ::: "memory");
        __builtin_amdgcn_sched_barrier(0);
        __builtin_amdgcn_s_setprio(1);
#pragma unroll
        for (int m = 0; m < 4; ++m)
#pragma unroll
            for (int n = 2; n < 4; ++n)
#pragma unroll
                for (int kk = 0; kk < 2; ++kk)
                    acc[m][n] = __builtin_amdgcn_mfma_f32_16x16x32_f16(af[m][kk], bf[n][kk], acc[m][n], 0, 0, 0);
        __builtin_amdgcn_s_setprio(0);
        __builtin_amdgcn_sched_barrier(0);
#pragma unroll
        for (int m = 0; m < 4; ++m) {
            af[m][0] = *(const f16x8*)&As[slot][wm * 128 + (m + 4) * 16 + fr][fk0];
            af[m][1] = *(const f16x8*)&As[slot][wm * 128 + (m + 4) * 16 + fr][fk1];
        }
        __builtin_amdgcn_sched_barrier(0);
        __builtin_amdgcn_s_barrier();
        asm volatile("s_waitcnt lgkmcnt(0)" ::: "memory");
        __builtin_amdgcn_sched_barrier(0);
        __builtin_amdgcn_s_setprio(1);
#pragma unroll
        for (int m = 0; m < 4; ++m)
#pragma unroll
            for (int n = 0; n < 2; ++n)
#pragma unroll
                for (int kk = 0; kk < 2; ++kk)
                    acc[m + 4][n] = __builtin_amdgcn_mfma_f32_16x16x32_f16(af[m][kk], bf[n][kk], acc[m + 4][n], 0, 0, 0);
        __builtin_amdgcn_s_setprio(0);
        __builtin_amdgcn_sched_barrier(0);
        __builtin_amdgcn_s_barrier();
        __builtin_amdgcn_sched_barrier(0);
        if (t + 2 < nk) stage(t + 2);
        __builtin_amdgcn_s_setprio(1);
#pragma unroll
        for (int m = 0; m < 4; ++m)
#pragma unroll
            for (int n = 2; n < 4; ++n)
#pragma unroll
                for (int kk = 0; kk < 2; ++kk)
                    acc[m + 4][n] = __builtin_amdgcn_mfma_f32_16x16x32_f16(af[m][kk], bf[n][kk], acc[m + 4][n], 0, 0, 0);
        __builtin_amdgcn_s_setprio(0);
        __builtin_amdgcn_sched_barrier(0);
    }

#pragma unroll
    for (int m = 0; m < 8; ++m) {
        int row0 = brow + wm * 128 + m * 16 + crow;
#pragma unroll
        for (int n = 0; n < 4; ++n) {
            int col = bcol + wn * 64 + n * 16 + fr;
            float bv = bias[col];
#pragma unroll
            for (int r = 0; r < 4; ++r) {
                float v = acc[m][n][r] + bv;
                size_t idx = (size_t)(row0 + r) * N + col;
                if (OUT_F16) ((_Float16*)Cv)[idx] = (_Float16)v;
                else ((float*)Cv)[idx] = v;
            }
        }
    }
    (void)M;
}

extern "C" void kernel_launch(void* const* d_in, const int* in_sizes, int n_in,
                              void* d_out, int out_size, void* d_ws, size_t ws_size,
                              hipStream_t stream) {
    const float* x         = (const float*)d_in[0];
    const float* slot_init = (const float*)d_in[1];
    const float* rw1       = (const float*)d_in[2];
    const float* rb1       = (const float*)d_in[3];
    const float* rw2       = (const float*)d_in[4];
    const float* rb2       = (const float*)d_in[5];
    const float* gwi       = (const float*)d_in[6];
    const float* gwh       = (const float*)d_in[7];
    const float* gbi       = (const float*)d_in[8];
    const float* gbh       = (const float*)d_in[9];
    const float* hpw       = (const float*)d_in[10];
    const float* hpb       = (const float*)d_in[11];
    const float* ohw       = (const float*)d_in[12];
    const float* ohb       = (const float*)d_in[13];
    const float* vpw       = (const float*)d_in[14];
    const float* vpb       = (const float*)d_in[15];
    const float* vow       = (const float*)d_in[16];
    const float* vob       = (const float*)d_in[17];
    const float* opw       = (const float*)d_in[18];
    const float* opb       = (const float*)d_in[19];
    const float* tau       = (const float*)d_in[20];
    float* out = (float*)d_out;

    float* ws = (float*)d_ws;
    size_t off = 0;
    auto alloc = [&](size_t nfloats) { float* p = ws + off; off += (nfloats + 63) & ~(size_t)63; return p; };

    float* cb     = alloc(1024);
    float* cbp    = alloc(16 * 1024);
    float* h1     = alloc((size_t)MTOK * 1024);            // fp32; dead after logits:
    _Float16* v1a = (_Float16*)h1;                          //   v1 rows 0..8191 [8192,4096] f16
    float* logits = alloc((size_t)MTOK * 64);
    float* alpha  = alloc((size_t)MTOK * 64);
    _Float16* alpha16 = (_Float16*)alloc((size_t)MTOK * 64 / 2);
    float* slotin = alloc(256 * 64);
    float* part   = alloc((size_t)8 * 64 * 4 * 64);
    float* partw  = alloc(8 * 64 * 4);
    float* Snew   = alloc(256 * 64);
    _Float16* PT   = (_Float16*)alloc((size_t)Bb * HMm * 64 / 2);  // [4,4096,64] f16
    _Float16* vowT = (_Float16*)alloc((size_t)Dd * HMm / 2);       // [1024,4096] f16
    _Float16* opwT = (_Float16*)alloc((size_t)Dd * Dd / 2);        // [1024,1024] f16
    _Float16* v2f16 = (_Float16*)alloc((size_t)MTOK * Dd / 2);     // [16384,1024] f16
    _Float16* w1hiT = (_Float16*)alloc((size_t)Dd * Dd / 2);
    _Float16* w1loT = (_Float16*)alloc((size_t)Dd * Dd / 2);

    // d_out scratch: xhi/xlo before hgemm4p; v1 rows 8192..16383 after vgen.
    _Float16* xhi = (_Float16*)d_out;
    _Float16* xlo = xhi + (size_t)MTOK * Dd;
    _Float16* v1b = (_Float16*)d_out;

    // ---- routing: pre-split x + deep-pipelined 4-plane split-fp16 GEMM + fp32 logits --
    cb_part_k<<<dim3(4, 16), 256, 0, stream>>>(slot_init, rw1, cbp);
    cb_comb_k<<<4, 256, 0, stream>>>(cbp, cb);
    wsplitT_k<<<dim3(Dd / 32, Dd / 32), 256, 0, stream>>>(rw1, w1hiT, w1loT);
    xsplit_k<<<(MTOK * Dd) / (256 * 8), 256, 0, stream>>>(x, xhi, xlo);
    hgemm4p_k<<<dim3(Dd / 256, MTOK / 256), 512, 0, stream>>>(
        xhi, xlo, w1hiT, w1loT, rb1, cb, h1, MTOK, Dd, Dd);
    logits2_k<<<MTOK / 64, 256, 0, stream>>>(h1, rw2, rb2, tau, logits);
    topk_k<<<MTOK / 4, 256, 0, stream>>>(logits, alpha, alpha16);

    // ---- weight transposes (fp32 -> fp16 [N,K]) ----
    transp_f16_k<<<dim3(Dd / 32, HMm / 32), 256, 0, stream>>>(vow, vowT, HMm, Dd);
    transp_f16_k<<<dim3(Dd / 32, Dd / 32), 256, 0, stream>>>(opw, opwT, Dd, Dd);

    // ---- slot pooling + GRU + slot MLP ----
    pool_part_k<<<dim3(64, 8), 256, 0, stream>>>(x, alpha, part, partw);
    pool_comb_k<<<64, 256, 0, stream>>>(part, partw, slotin);
    gru_k<<<256, 64, 0, stream>>>(slotin, slot_init, gwi, gwh, gbi, gbh,
                                  hpw, hpb, ohw, ohb, Snew);

    // ---- P[b] = S_emb[b] @ vpw (stored transposed f16 [b][j][hs]) ----
    pmat_k<<<dim3(HMm / 256, Hh), 256, 0, stream>>>(Snew, vpw, PT);

    // ---- value MLP: vgen (K=64), then BK=64 4-phase 256^2 GEMM2 + GEMM3 ----
    vgen_k<<<dim3(HMm / 128, MTOK / 128), 256, 0, stream>>>(
        alpha16, PT, vpb, v1a, v1b);
    hgemm8_k<1><<<dim3(Dd / 256, MTOK / 256), 512, 0, stream>>>(
        v1a, v1b, 8192, vowT, vob, v2f16, MTOK, Dd, HMm);
    hgemm8_k<0><<<dim3(Dd / 256, MTOK / 256), 512, 0, stream>>>(
        v2f16, v2f16, MTOK, opwT, opb, out, MTOK, Dd, Dd);

    (void)in_sizes; (void)n_in; (void)out_size; (void)ws_size;
}